// Round 1
// baseline (435.528 us; speedup 1.0000x reference)
//
#include <hip/hip_runtime.h>
#include <hip/hip_bf16.h>
#include <stdint.h>

typedef unsigned short u16;
typedef float f32x4 __attribute__((ext_vector_type(4)));
typedef __bf16 bf16x8 __attribute__((ext_vector_type(8)));
typedef u16 u16x8 __attribute__((ext_vector_type(8)));

// async global->LDS, 16B per lane. LDS dest must be wave-uniform base + lane*16.
#define GL2LDS16(g, l)                                                          \
  __builtin_amdgcn_global_load_lds(                                             \
      (const __attribute__((address_space(1))) unsigned int*)(g),               \
      (__attribute__((address_space(3))) unsigned int*)(l), 16, 0, 0)

__device__ __forceinline__ u16 f2bf(float f) {
  uint32_t u = __builtin_bit_cast(uint32_t, f);
  return (u16)((u + 0x7FFFu + ((u >> 16) & 1u)) >> 16);  // RNE, no NaN inputs
}

// ---------------- fp32 -> bf16 cast (vectorized, 8 elems/thread) -------------
__global__ __launch_bounds__(256) void cast_kernel(const float* __restrict__ s,
                                                   u16* __restrict__ d, int n) {
  int i = (blockIdx.x * 256 + threadIdx.x) * 8;
  if (i >= n) return;
  const float4* p = (const float4*)(s + i);
  float4 a = p[0], b = p[1];
  u16x8 o;
  o[0] = f2bf(a.x); o[1] = f2bf(a.y); o[2] = f2bf(a.z); o[3] = f2bf(a.w);
  o[4] = f2bf(b.x); o[5] = f2bf(b.y); o[6] = f2bf(b.z); o[7] = f2bf(b.w);
  *(u16x8*)(d + i) = o;
}

// ---------------- bf16 GEMM, C = A * B^T  (A[M][K], B[N][K], both K-contig) --
// m97 structure: 128x128 tile, BK=32, 4 waves (2x2 of 64x64), global_load_lds
// width-16 staging with pre-swizzled source (2-way-free LDS banking).
template <typename CT>
__global__ __launch_bounds__(256) void gemm_bt(const u16* __restrict__ A,
                                               const u16* __restrict__ B,
                                               CT* __restrict__ C, int M, int N,
                                               int K) {
  __shared__ u16 As[128 * 32];
  __shared__ u16 Bs[128 * 32];
  const int tid = threadIdx.x;
  const int lane = tid & 63;
  const int l15 = lane & 15, lhi = lane >> 4;
  const int wave = tid >> 6;
  const int wr = (wave >> 1) * 64, wc = (wave & 1) * 64;
  const int m0 = blockIdx.y * 128, n0 = blockIdx.x * 128;

  f32x4 acc[4][4] = {};

  for (int k0 = 0; k0 < K; k0 += 32) {
    __syncthreads();
#pragma unroll
    for (int i = 0; i < 2; ++i) {
      int c = tid + i * 256;           // 16B chunk id, 512 chunks = 128x32 bf16
      int row = c >> 2, slot = c & 3;
      int scol = (slot ^ ((row >> 1) & 3)) * 8;  // inverse-swizzled source col
      GL2LDS16(A + (size_t)(m0 + row) * K + k0 + scol, (char*)As + c * 16);
      GL2LDS16(B + (size_t)(n0 + row) * K + k0 + scol, (char*)Bs + c * 16);
    }
    __syncthreads();
    bf16x8 af[4], bfr[4];
#pragma unroll
    for (int mi = 0; mi < 4; ++mi) {
      int row = wr + mi * 16 + l15;
      int byt = row * 64 + ((lhi ^ ((row >> 1) & 3)) << 4);
      af[mi] = *(const bf16x8*)((const char*)As + byt);
    }
#pragma unroll
    for (int ni = 0; ni < 4; ++ni) {
      int row = wc + ni * 16 + l15;
      int byt = row * 64 + ((lhi ^ ((row >> 1) & 3)) << 4);
      bfr[ni] = *(const bf16x8*)((const char*)Bs + byt);
    }
#pragma unroll
    for (int mi = 0; mi < 4; ++mi)
#pragma unroll
      for (int ni = 0; ni < 4; ++ni)
        acc[mi][ni] = __builtin_amdgcn_mfma_f32_16x16x32_bf16(
            af[mi], bfr[ni], acc[mi][ni], 0, 0, 0);
  }

#pragma unroll
  for (int mi = 0; mi < 4; ++mi) {
    int rbase = m0 + wr + mi * 16 + lhi * 4;
#pragma unroll
    for (int ni = 0; ni < 4; ++ni) {
      int col = n0 + wc + ni * 16 + l15;
#pragma unroll
      for (int r = 0; r < 4; ++r) {
        float v = acc[mi][ni][r];
        if constexpr (sizeof(CT) == 2)
          C[(size_t)(rbase + r) * N + col] = (CT)f2bf(v);
        else
          C[(size_t)(rbase + r) * N + col] = v;
      }
    }
  }
}

// ---------------- causal flash attention --------------------------------------
// qkv: [4096][3072] bf16 (Q | K | V, each [s][h*64+d]). out: [4096][1024] bf16.
// Block = (q-block of 64 rows) x head; 4 waves, 16 q-rows each. KV tile = 64.
__global__ __launch_bounds__(256) void attn_kernel(const u16* __restrict__ qkv,
                                                   u16* __restrict__ out) {
  const int h = blockIdx.y;
  const int qb = 63 - blockIdx.x;  // heavy (long-loop) blocks first
  const int tid = threadIdx.x;
  const int lane = tid & 63, wave = tid >> 6;
  const int l15 = lane & 15, lhi = lane >> 4;

  __shared__ u16 Ks[64 * 64];
  __shared__ u16 Vs[64 * 64];
  __shared__ u16 Ps[4][16 * 64];

  const int q0 = qb * 64 + wave * 16;
  const u16* Qb = qkv + (size_t)(q0 + l15) * 3072 + h * 64;
  bf16x8 qf0 = *(const bf16x8*)(const void*)(Qb + lhi * 8);
  bf16x8 qf1 = *(const bf16x8*)(const void*)(Qb + 32 + lhi * 8);

  f32x4 oa[4] = {};
  float mrow[4] = {-1e30f, -1e30f, -1e30f, -1e30f};
  float lrow[4] = {0.f, 0.f, 0.f, 0.f};
  u16* Pw = Ps[wave];

  for (int kb = 0; kb <= qb; ++kb) {
    __syncthreads();
#pragma unroll
    for (int i = 0; i < 2; ++i) {
      int c = tid + i * 256;           // 512 chunks = 64x64 bf16
      int row = c >> 3, slot = c & 7;
      int scol = (slot ^ (row & 7)) * 8;  // inverse-swizzled source col
      size_t g = (size_t)(kb * 64 + row) * 3072 + 1024 + h * 64 + scol;
      GL2LDS16(qkv + g, (char*)Ks + c * 16);
      GL2LDS16(qkv + g + 1024, (char*)Vs + c * 16);
    }
    __syncthreads();

    // S = Q K^T  (A = Q rows, B = K rows, both d-contiguous)
    f32x4 s[4] = {};
#pragma unroll
    for (int ks = 0; ks < 2; ++ks)
#pragma unroll
      for (int nf = 0; nf < 4; ++nf) {
        int row = nf * 16 + l15;
        int byt = row * 128 + ((lhi * 16 + ks * 64) ^ ((row & 7) << 4));
        bf16x8 kf = *(const bf16x8*)((const char*)Ks + byt);
        s[nf] = __builtin_amdgcn_mfma_f32_16x16x32_bf16(ks ? qf1 : qf0, kf,
                                                        s[nf], 0, 0, 0);
      }

    // scale + causal mask (only the diagonal block needs the mask)
    const bool diag = (kb == qb);
#pragma unroll
    for (int nf = 0; nf < 4; ++nf)
#pragma unroll
      for (int r = 0; r < 4; ++r) {
        float v = s[nf][r] * 0.125f;
        if (diag && (nf * 16 + l15 > wave * 16 + lhi * 4 + r)) v = -1e30f;
        s[nf][r] = v;
      }

    // row max across 16 lanes (cols) x 4 frags
    float pm[4];
#pragma unroll
    for (int r = 0; r < 4; ++r)
      pm[r] = fmaxf(fmaxf(s[0][r], s[1][r]), fmaxf(s[2][r], s[3][r]));
#pragma unroll
    for (int off = 1; off < 16; off <<= 1)
#pragma unroll
      for (int r = 0; r < 4; ++r) pm[r] = fmaxf(pm[r], __shfl_xor(pm[r], off));

    float alpha[4];
#pragma unroll
    for (int r = 0; r < 4; ++r) {
      float mn = fmaxf(mrow[r], pm[r]);
      alpha[r] = __expf(mrow[r] - mn);
      mrow[r] = mn;
    }
#pragma unroll
    for (int nf = 0; nf < 4; ++nf)
#pragma unroll
      for (int r = 0; r < 4; ++r) s[nf][r] = __expf(s[nf][r] - mrow[r]);

    float rs[4];
#pragma unroll
    for (int r = 0; r < 4; ++r) rs[r] = (s[0][r] + s[1][r]) + (s[2][r] + s[3][r]);
#pragma unroll
    for (int off = 1; off < 16; off <<= 1)
#pragma unroll
      for (int r = 0; r < 4; ++r) rs[r] += __shfl_xor(rs[r], off);
#pragma unroll
    for (int r = 0; r < 4; ++r) lrow[r] = lrow[r] * alpha[r] + rs[r];
#pragma unroll
    for (int nf = 0; nf < 4; ++nf)
#pragma unroll
      for (int r = 0; r < 4; ++r) oa[nf][r] *= alpha[r];

    // P (C/D layout) -> per-wave LDS (swizzled), bf16
#pragma unroll
    for (int nf = 0; nf < 4; ++nf)
#pragma unroll
      for (int r = 0; r < 4; ++r) {
        int row = lhi * 4 + r, col = nf * 16 + l15;
        int byt = row * 128 + ((col * 2) ^ ((row & 7) << 4));
        *(u16*)((char*)Pw + byt) = f2bf(s[nf][r]);
      }

    // P A-fragments
    bf16x8 pf[2];
#pragma unroll
    for (int ks = 0; ks < 2; ++ks) {
      int byt = l15 * 128 + (((lhi * 8 + ks * 32) * 2) ^ ((l15 & 7) << 4));
      pf[ks] = *(const bf16x8*)((const char*)Pw + byt);
    }

    // O += P * V   (B-frag = V^T gathered as u16, conflict-free under swizzle)
#pragma unroll
    for (int ks = 0; ks < 2; ++ks)
#pragma unroll
      for (int nf = 0; nf < 4; ++nf) {
        u16x8 tv;
#pragma unroll
        for (int j = 0; j < 8; ++j) {
          int kk = ks * 32 + lhi * 8 + j;
          int d = nf * 16 + l15;
          int byt = kk * 128 + ((d * 2) ^ ((kk & 7) << 4));
          tv[j] = *(const u16*)((const char*)Vs + byt);
        }
        bf16x8 vf = __builtin_bit_cast(bf16x8, tv);
        oa[nf] = __builtin_amdgcn_mfma_f32_16x16x32_bf16(pf[ks], vf, oa[nf],
                                                         0, 0, 0);
      }
  }

  // epilogue: O / l -> bf16
#pragma unroll
  for (int r = 0; r < 4; ++r) {
    float inv = 1.0f / lrow[r];
    int rowg = q0 + lhi * 4 + r;
#pragma unroll
    for (int nf = 0; nf < 4; ++nf)
      out[(size_t)rowg * 1024 + h * 64 + nf * 16 + l15] = f2bf(oa[nf][r] * inv);
  }
}

// -----------------------------------------------------------------------------
extern "C" void kernel_launch(void* const* d_in, const int* in_sizes, int n_in,
                              void* d_out, int out_size, void* d_ws,
                              size_t ws_size, hipStream_t stream) {
  const float* x = (const float*)d_in[0];
  const float* wq = (const float*)d_in[1];
  const float* wk = (const float*)d_in[2];
  const float* wv = (const float*)d_in[3];
  const float* wo = (const float*)d_in[4];

  // workspace layout (bf16), ~48 MB total
  u16* xb = (u16*)d_ws;                      // [4096][1024]
  u16* wqkv = xb + 4096 * 1024;              // [3072][1024] (wq|wk|wv rows)
  u16* wob = wqkv + 3072 * 1024;             // [1024][1024]
  u16* qkv = wob + 1024 * 1024;              // [4096][3072]
  u16* atn = qkv + (size_t)4096 * 3072;      // [4096][1024]

  cast_kernel<<<2048, 256, 0, stream>>>(x, xb, 4096 * 1024);
  cast_kernel<<<512, 256, 0, stream>>>(wq, wqkv, 1024 * 1024);
  cast_kernel<<<512, 256, 0, stream>>>(wk, wqkv + 1024 * 1024, 1024 * 1024);
  cast_kernel<<<512, 256, 0, stream>>>(wv, wqkv + 2 * 1024 * 1024, 1024 * 1024);
  cast_kernel<<<512, 256, 0, stream>>>(wo, wob, 1024 * 1024);

  // QKV projection: [4096][3072] = x_bf16 * wqkv^T
  gemm_bt<u16><<<dim3(24, 32), 256, 0, stream>>>(xb, wqkv, qkv, 4096, 3072, 1024);
  // causal flash attention per head
  attn_kernel<<<dim3(64, 16), 256, 0, stream>>>(qkv, atn);
  // output projection: fp32 out = attn_bf16 * wo^T
  gemm_bt<float><<<dim3(8, 32), 256, 0, stream>>>(atn, wob, (float*)d_out, 4096,
                                                  1024, 1024);
}

// Round 2
// 301.944 us; speedup vs baseline: 1.4424x; 1.4424x over previous
//
#include <hip/hip_runtime.h>
#include <hip/hip_bf16.h>
#include <stdint.h>

typedef unsigned short u16;
typedef float f32x4 __attribute__((ext_vector_type(4)));
typedef __bf16 bf16x8 __attribute__((ext_vector_type(8)));
typedef u16 u16x8 __attribute__((ext_vector_type(8)));

// async global->LDS, 16B per lane. LDS dest must be wave-uniform base + lane*16.
#define GL2LDS16(g, l)                                                          \
  __builtin_amdgcn_global_load_lds(                                             \
      (const __attribute__((address_space(1))) unsigned int*)(g),               \
      (__attribute__((address_space(3))) unsigned int*)(l), 16, 0, 0)

__device__ __forceinline__ u16 f2bf(float f) {
  uint32_t u = __builtin_bit_cast(uint32_t, f);
  return (u16)((u + 0x7FFFu + ((u >> 16) & 1u)) >> 16);  // RNE, no NaN inputs
}

// ---------------- fp32 -> bf16 cast (vectorized, 8 elems/thread) -------------
__global__ __launch_bounds__(256) void cast_kernel(const float* __restrict__ s,
                                                   u16* __restrict__ d, int n) {
  int i = (blockIdx.x * 256 + threadIdx.x) * 8;
  if (i >= n) return;
  const float4* p = (const float4*)(s + i);
  float4 a = p[0], b = p[1];
  u16x8 o;
  o[0] = f2bf(a.x); o[1] = f2bf(a.y); o[2] = f2bf(a.z); o[3] = f2bf(a.w);
  o[4] = f2bf(b.x); o[5] = f2bf(b.y); o[6] = f2bf(b.z); o[7] = f2bf(b.w);
  *(u16x8*)(d + i) = o;
}

// ---------------- bf16 GEMM, C = A * B^T  (A[M][K], B[N][K], both K-contig) --
template <typename CT>
__global__ __launch_bounds__(256) void gemm_bt(const u16* __restrict__ A,
                                               const u16* __restrict__ B,
                                               CT* __restrict__ C, int M, int N,
                                               int K) {
  __shared__ u16 As[128 * 32];
  __shared__ u16 Bs[128 * 32];
  const int tid = threadIdx.x;
  const int lane = tid & 63;
  const int l15 = lane & 15, lhi = lane >> 4;
  const int wave = tid >> 6;
  const int wr = (wave >> 1) * 64, wc = (wave & 1) * 64;
  const int m0 = blockIdx.y * 128, n0 = blockIdx.x * 128;

  f32x4 acc[4][4] = {};

  for (int k0 = 0; k0 < K; k0 += 32) {
    __syncthreads();
#pragma unroll
    for (int i = 0; i < 2; ++i) {
      int c = tid + i * 256;           // 16B chunk id, 512 chunks = 128x32 bf16
      int row = c >> 2, slot = c & 3;
      int scol = (slot ^ ((row >> 1) & 3)) * 8;  // inverse-swizzled source col
      GL2LDS16(A + (size_t)(m0 + row) * K + k0 + scol, (char*)As + c * 16);
      GL2LDS16(B + (size_t)(n0 + row) * K + k0 + scol, (char*)Bs + c * 16);
    }
    __syncthreads();
    bf16x8 af[4], bfr[4];
#pragma unroll
    for (int mi = 0; mi < 4; ++mi) {
      int row = wr + mi * 16 + l15;
      int byt = row * 64 + ((lhi ^ ((row >> 1) & 3)) << 4);
      af[mi] = *(const bf16x8*)((const char*)As + byt);
    }
#pragma unroll
    for (int ni = 0; ni < 4; ++ni) {
      int row = wc + ni * 16 + l15;
      int byt = row * 64 + ((lhi ^ ((row >> 1) & 3)) << 4);
      bfr[ni] = *(const bf16x8*)((const char*)Bs + byt);
    }
#pragma unroll
    for (int mi = 0; mi < 4; ++mi)
#pragma unroll
      for (int ni = 0; ni < 4; ++ni)
        acc[mi][ni] = __builtin_amdgcn_mfma_f32_16x16x32_bf16(
            af[mi], bfr[ni], acc[mi][ni], 0, 0, 0);
  }

#pragma unroll
  for (int mi = 0; mi < 4; ++mi) {
    int rbase = m0 + wr + mi * 16 + lhi * 4;
#pragma unroll
    for (int ni = 0; ni < 4; ++ni) {
      int col = n0 + wc + ni * 16 + l15;
#pragma unroll
      for (int r = 0; r < 4; ++r) {
        float v = acc[mi][ni][r];
        if constexpr (sizeof(CT) == 2)
          C[(size_t)(rbase + r) * N + col] = (CT)f2bf(v);
        else
          C[(size_t)(rbase + r) * N + col] = v;
      }
    }
  }
}

// ---------------- V transpose: qkv[4096][3072] V-cols -> vt[1024][4096] -----
__global__ __launch_bounds__(256) void vtrans_kernel(const u16* __restrict__ qkv,
                                                     u16* __restrict__ vt) {
  __shared__ u16 t[64][72];  // +8 pad breaks bank aliasing on column reads
  const int bs = blockIdx.x * 64;  // s tile
  const int be = blockIdx.y * 64;  // e tile (within 1024 V cols)
  const int tid = threadIdx.x;
#pragma unroll
  for (int i = 0; i < 2; ++i) {
    int c = tid + i * 256, row = c >> 3, col = (c & 7) * 8;
    *(u16x8*)&t[row][col] =
        *(const u16x8*)(qkv + (size_t)(bs + row) * 3072 + 2048 + be + col);
  }
  __syncthreads();
#pragma unroll
  for (int i = 0; i < 2; ++i) {
    int c = tid + i * 256, erow = c >> 3, scol = (c & 7) * 8;
    u16x8 o;
#pragma unroll
    for (int j = 0; j < 8; ++j) o[j] = t[scol + j][erow];
    *(u16x8*)(vt + (size_t)(be + erow) * 4096 + bs + scol) = o;
  }
}

// ---------------- causal flash attention --------------------------------------
// qkv: [4096][3072] bf16 (Q | K | V). vt: [16*64][4096] = V^T per head.
// out: [4096][1024] bf16. Block = two paired q-tiles (bx, 63-bx) x head;
// 4 waves, 16 q-rows each. KV tile = 64. Every block: exactly 65 kv-tiles.
__global__ __launch_bounds__(256) void attn_kernel(const u16* __restrict__ qkv,
                                                   const u16* __restrict__ vt,
                                                   u16* __restrict__ out) {
  const int h = blockIdx.y;
  const int bx = blockIdx.x;  // 0..31
  const int tid = threadIdx.x;
  const int lane = tid & 63, wave = tid >> 6;
  const int l15 = lane & 15, lhi = lane >> 4;

  __shared__ u16 Ks[64 * 64];
  __shared__ u16 Vs[64 * 64];
  __shared__ u16 Ps[4][16 * 64];
  u16* Pw = Ps[wave];

  for (int rep = 0; rep < 2; ++rep) {
    const int qb = rep ? (63 - bx) : bx;
    const int q0 = qb * 64 + wave * 16;
    const u16* Qb = qkv + (size_t)(q0 + l15) * 3072 + h * 64;
    bf16x8 qf0 = *(const bf16x8*)(const void*)(Qb + lhi * 8);
    bf16x8 qf1 = *(const bf16x8*)(const void*)(Qb + 32 + lhi * 8);

    f32x4 oa[4] = {};
    float mrow[4] = {-1e30f, -1e30f, -1e30f, -1e30f};
    float lrow[4] = {0.f, 0.f, 0.f, 0.f};

    for (int kb = 0; kb <= qb; ++kb) {
      __syncthreads();
#pragma unroll
      for (int i = 0; i < 2; ++i) {
        int c = tid + i * 256;           // 512 chunks = 64x64 bf16
        int row = c >> 3, slot = c & 7;
        int scol = (slot ^ (row & 7)) * 8;  // inverse-swizzled source col
        GL2LDS16(qkv + (size_t)(kb * 64 + row) * 3072 + 1024 + h * 64 + scol,
                 (char*)Ks + c * 16);
        GL2LDS16(vt + (size_t)(h * 64 + row) * 4096 + kb * 64 + scol,
                 (char*)Vs + c * 16);
      }
      __syncthreads();

      // S = Q K^T  (A = Q rows in reg, B = K rows from LDS)
      f32x4 s[4] = {};
#pragma unroll
      for (int ks = 0; ks < 2; ++ks)
#pragma unroll
        for (int nf = 0; nf < 4; ++nf) {
          int row = nf * 16 + l15;
          int byt = row * 128 + ((lhi * 16 + ks * 64) ^ ((row & 7) << 4));
          bf16x8 kf = *(const bf16x8*)((const char*)Ks + byt);
          s[nf] = __builtin_amdgcn_mfma_f32_16x16x32_bf16(ks ? qf1 : qf0, kf,
                                                          s[nf], 0, 0, 0);
        }

      // scale + causal mask (diagonal tile only)
      const bool diag = (kb == qb);
#pragma unroll
      for (int nf = 0; nf < 4; ++nf)
#pragma unroll
        for (int r = 0; r < 4; ++r) {
          float v = s[nf][r] * 0.125f;
          if (diag && (nf * 16 + l15 > wave * 16 + lhi * 4 + r)) v = -1e30f;
          s[nf][r] = v;
        }

      // row max across 16 lanes (cols) x 4 frags
      float pm[4];
#pragma unroll
      for (int r = 0; r < 4; ++r)
        pm[r] = fmaxf(fmaxf(s[0][r], s[1][r]), fmaxf(s[2][r], s[3][r]));
#pragma unroll
      for (int off = 1; off < 16; off <<= 1)
#pragma unroll
        for (int r = 0; r < 4; ++r) pm[r] = fmaxf(pm[r], __shfl_xor(pm[r], off));

      float alpha[4];
#pragma unroll
      for (int r = 0; r < 4; ++r) {
        float mn = fmaxf(mrow[r], pm[r]);
        alpha[r] = __expf(mrow[r] - mn);
        mrow[r] = mn;
      }
#pragma unroll
      for (int nf = 0; nf < 4; ++nf)
#pragma unroll
        for (int r = 0; r < 4; ++r) s[nf][r] = __expf(s[nf][r] - mrow[r]);

      float rs[4];
#pragma unroll
      for (int r = 0; r < 4; ++r)
        rs[r] = (s[0][r] + s[1][r]) + (s[2][r] + s[3][r]);
#pragma unroll
      for (int off = 1; off < 16; off <<= 1)
#pragma unroll
        for (int r = 0; r < 4; ++r) rs[r] += __shfl_xor(rs[r], off);
#pragma unroll
      for (int r = 0; r < 4; ++r) lrow[r] = lrow[r] * alpha[r] + rs[r];
#pragma unroll
      for (int nf = 0; nf < 4; ++nf)
#pragma unroll
        for (int r = 0; r < 4; ++r) oa[nf][r] *= alpha[r];

      // P (C/D layout) -> per-wave LDS (swizzled), bf16
#pragma unroll
      for (int nf = 0; nf < 4; ++nf)
#pragma unroll
        for (int r = 0; r < 4; ++r) {
          int row = lhi * 4 + r, col = nf * 16 + l15;
          int byt = row * 128 + ((col * 2) ^ ((row & 7) << 4));
          *(u16*)((char*)Pw + byt) = f2bf(s[nf][r]);
        }

      // P A-fragments
      bf16x8 pf[2];
#pragma unroll
      for (int ks = 0; ks < 2; ++ks) {
        int byt = l15 * 128 + (((lhi * 8 + ks * 32) * 2) ^ ((l15 & 7) << 4));
        pf[ks] = *(const bf16x8*)((const char*)Pw + byt);
      }

      // O += P * V  (B-frag from V^T tile: row = d, contiguous along kv)
#pragma unroll
      for (int ks = 0; ks < 2; ++ks)
#pragma unroll
        for (int nf = 0; nf < 4; ++nf) {
          int row = nf * 16 + l15;
          int byt = row * 128 + ((ks * 64 + lhi * 16) ^ ((row & 7) << 4));
          bf16x8 vf = *(const bf16x8*)((const char*)Vs + byt);
          oa[nf] = __builtin_amdgcn_mfma_f32_16x16x32_bf16(pf[ks], vf, oa[nf],
                                                           0, 0, 0);
        }
    }

    // epilogue: O / l -> bf16
#pragma unroll
    for (int r = 0; r < 4; ++r) {
      float inv = 1.0f / lrow[r];
      int rowg = q0 + lhi * 4 + r;
#pragma unroll
      for (int nf = 0; nf < 4; ++nf)
        out[(size_t)rowg * 1024 + h * 64 + nf * 16 + l15] =
            f2bf(oa[nf][r] * inv);
    }
  }
}

// -----------------------------------------------------------------------------
extern "C" void kernel_launch(void* const* d_in, const int* in_sizes, int n_in,
                              void* d_out, int out_size, void* d_ws,
                              size_t ws_size, hipStream_t stream) {
  const float* x = (const float*)d_in[0];
  const float* wq = (const float*)d_in[1];
  const float* wk = (const float*)d_in[2];
  const float* wv = (const float*)d_in[3];
  const float* wo = (const float*)d_in[4];

  // workspace layout (bf16), ~48 MB total
  u16* xb = (u16*)d_ws;                      // [4096][1024]  (dead after QKV GEMM)
  u16* wqkv = xb + 4096 * 1024;              // [3072][1024] (wq|wk|wv rows)
  u16* wob = wqkv + 3072 * 1024;             // [1024][1024]
  u16* qkv = wob + 1024 * 1024;              // [4096][3072]
  u16* atn = qkv + (size_t)4096 * 3072;      // [4096][1024]
  u16* vt = xb;                              // [1024][4096] V^T, reuses xb

  cast_kernel<<<2048, 256, 0, stream>>>(x, xb, 4096 * 1024);
  cast_kernel<<<512, 256, 0, stream>>>(wq, wqkv, 1024 * 1024);
  cast_kernel<<<512, 256, 0, stream>>>(wk, wqkv + 1024 * 1024, 1024 * 1024);
  cast_kernel<<<512, 256, 0, stream>>>(wv, wqkv + 2 * 1024 * 1024, 1024 * 1024);
  cast_kernel<<<512, 256, 0, stream>>>(wo, wob, 1024 * 1024);

  // QKV projection: [4096][3072] = x_bf16 * wqkv^T
  gemm_bt<u16><<<dim3(24, 32), 256, 0, stream>>>(xb, wqkv, qkv, 4096, 3072, 1024);
  // V transpose (xb no longer needed -> vt aliases it)
  vtrans_kernel<<<dim3(64, 16), 256, 0, stream>>>(qkv, vt);
  // causal flash attention per head (paired q-tiles for load balance)
  attn_kernel<<<dim3(32, 16), 256, 0, stream>>>(qkv, vt, atn);
  // output projection: fp32 out = attn_bf16 * wo^T
  gemm_bt<float><<<dim3(8, 32), 256, 0, stream>>>(atn, wob, (float*)d_out, 4096,
                                                  1024, 1024);
}

// Round 3
// 280.028 us; speedup vs baseline: 1.5553x; 1.0783x over previous
//
#include <hip/hip_runtime.h>
#include <hip/hip_bf16.h>
#include <stdint.h>

typedef unsigned short u16;
typedef float f32x4 __attribute__((ext_vector_type(4)));
typedef __bf16 bf16x8 __attribute__((ext_vector_type(8)));
typedef u16 u16x8 __attribute__((ext_vector_type(8)));

// async global->LDS, 16B per lane. LDS dest must be wave-uniform base + lane*16.
#define GL2LDS16(g, l)                                                          \
  __builtin_amdgcn_global_load_lds(                                             \
      (const __attribute__((address_space(1))) unsigned int*)(g),               \
      (__attribute__((address_space(3))) unsigned int*)(l), 16, 0, 0)

#if __has_builtin(__builtin_amdgcn_exp2f)
#define EXP2(x) __builtin_amdgcn_exp2f(x)
#else
#define EXP2(x) exp2f(x)
#endif

__device__ __forceinline__ u16 f2bf(float f) {
  uint32_t u = __builtin_bit_cast(uint32_t, f);
  return (u16)((u + 0x7FFFu + ((u >> 16) & 1u)) >> 16);  // RNE, no NaN inputs
}

__device__ __forceinline__ uint32_t cvt_pk_bf16(float lo, float hi) {
  uint32_t r;
  asm("v_cvt_pk_bf16_f32 %0, %1, %2" : "=v"(r) : "v"(lo), "v"(hi));
  return r;
}

// ---------------- fp32 -> bf16 cast (vectorized, 8 elems/thread) -------------
__device__ __forceinline__ void cast8(const float* __restrict__ s,
                                      u16* __restrict__ d) {
  const float4* p = (const float4*)s;
  float4 a = p[0], b = p[1];
  uint4 o;
  o.x = cvt_pk_bf16(a.x, a.y);
  o.y = cvt_pk_bf16(a.z, a.w);
  o.z = cvt_pk_bf16(b.x, b.y);
  o.w = cvt_pk_bf16(b.z, b.w);
  *(uint4*)d = o;
}

__global__ __launch_bounds__(256) void cast_kernel(const float* __restrict__ s,
                                                   u16* __restrict__ d, int n) {
  int i = (blockIdx.x * 256 + threadIdx.x) * 8;
  if (i >= n) return;
  cast8(s + i, d + i);
}

// 4 weight matrices (1M elems each) -> contiguous bf16 (wq|wk|wv|wo)
__global__ __launch_bounds__(256) void cast4_kernel(const float* __restrict__ s0,
                                                    const float* __restrict__ s1,
                                                    const float* __restrict__ s2,
                                                    const float* __restrict__ s3,
                                                    u16* __restrict__ d) {
  int b = blockIdx.x >> 9;
  int i = ((blockIdx.x & 511) * 256 + threadIdx.x) * 8;
  const float* s = (b == 0) ? s0 : (b == 1) ? s1 : (b == 2) ? s2 : s3;
  cast8(s + i, d + ((size_t)b << 20) + i);
}

// ---------------- bf16 GEMM, C = A * B^T  (A[M][K], B[N][K], both K-contig) --
template <typename CT>
__global__ __launch_bounds__(256) void gemm_bt(const u16* __restrict__ A,
                                               const u16* __restrict__ B,
                                               CT* __restrict__ C, int M, int N,
                                               int K) {
  __shared__ u16 As[128 * 32];
  __shared__ u16 Bs[128 * 32];
  const int tid = threadIdx.x;
  const int lane = tid & 63;
  const int l15 = lane & 15, lhi = lane >> 4;
  const int wave = tid >> 6;
  const int wr = (wave >> 1) * 64, wc = (wave & 1) * 64;
  const int m0 = blockIdx.y * 128, n0 = blockIdx.x * 128;

  f32x4 acc[4][4] = {};

  for (int k0 = 0; k0 < K; k0 += 32) {
    __syncthreads();
#pragma unroll
    for (int i = 0; i < 2; ++i) {
      int c = tid + i * 256;           // 16B chunk id, 512 chunks = 128x32 bf16
      int row = c >> 2, slot = c & 3;
      int scol = (slot ^ ((row >> 1) & 3)) * 8;  // inverse-swizzled source col
      GL2LDS16(A + (size_t)(m0 + row) * K + k0 + scol, (char*)As + c * 16);
      GL2LDS16(B + (size_t)(n0 + row) * K + k0 + scol, (char*)Bs + c * 16);
    }
    __syncthreads();
    bf16x8 af[4], bfr[4];
#pragma unroll
    for (int mi = 0; mi < 4; ++mi) {
      int row = wr + mi * 16 + l15;
      int byt = row * 64 + ((lhi ^ ((row >> 1) & 3)) << 4);
      af[mi] = *(const bf16x8*)((const char*)As + byt);
    }
#pragma unroll
    for (int ni = 0; ni < 4; ++ni) {
      int row = wc + ni * 16 + l15;
      int byt = row * 64 + ((lhi ^ ((row >> 1) & 3)) << 4);
      bfr[ni] = *(const bf16x8*)((const char*)Bs + byt);
    }
#pragma unroll
    for (int mi = 0; mi < 4; ++mi)
#pragma unroll
      for (int ni = 0; ni < 4; ++ni)
        acc[mi][ni] = __builtin_amdgcn_mfma_f32_16x16x32_bf16(
            af[mi], bfr[ni], acc[mi][ni], 0, 0, 0);
  }

#pragma unroll
  for (int mi = 0; mi < 4; ++mi) {
    int rbase = m0 + wr + mi * 16 + lhi * 4;
#pragma unroll
    for (int ni = 0; ni < 4; ++ni) {
      int col = n0 + wc + ni * 16 + l15;
#pragma unroll
      for (int r = 0; r < 4; ++r) {
        float v = acc[mi][ni][r];
        if constexpr (sizeof(CT) == 2)
          C[(size_t)(rbase + r) * N + col] = (CT)f2bf(v);
        else
          C[(size_t)(rbase + r) * N + col] = v;
      }
    }
  }
}

// ---------------- V transpose: qkv[4096][3072] V-cols -> vt[1024][4096] -----
__global__ __launch_bounds__(256) void vtrans_kernel(const u16* __restrict__ qkv,
                                                     u16* __restrict__ vt) {
  __shared__ u16 t[64][72];  // +8 pad breaks bank aliasing on column reads
  const int bs = blockIdx.x * 64;  // s tile
  const int be = blockIdx.y * 64;  // e tile (within 1024 V cols)
  const int tid = threadIdx.x;
#pragma unroll
  for (int i = 0; i < 2; ++i) {
    int c = tid + i * 256, row = c >> 3, col = (c & 7) * 8;
    *(u16x8*)&t[row][col] =
        *(const u16x8*)(qkv + (size_t)(bs + row) * 3072 + 2048 + be + col);
  }
  __syncthreads();
#pragma unroll
  for (int i = 0; i < 2; ++i) {
    int c = tid + i * 256, erow = c >> 3, scol = (c & 7) * 8;
    u16x8 o;
#pragma unroll
    for (int j = 0; j < 8; ++j) o[j] = t[scol + j][erow];
    *(u16x8*)(vt + (size_t)(be + erow) * 4096 + bs + scol) = o;
  }
}

// ---------------- causal flash attention --------------------------------------
// qkv: [4096][3072] bf16 (Q | K | V). vt: [16*64][4096] = V^T per head.
// out: [4096][1024] bf16. Block = two paired q-tiles (bx, 63-bx) x head;
// 4 waves, 16 q-rows each. KV tile = 64, double-buffered (T3-min 2-phase).
// Softmax in exp2 domain with defer-max (T13, THR=8).
__global__ __launch_bounds__(256) void attn_kernel(const u16* __restrict__ qkv,
                                                   const u16* __restrict__ vt,
                                                   u16* __restrict__ out) {
  const int h = blockIdx.y;
  const int bx = blockIdx.x;  // 0..31
  const int tid = threadIdx.x;
  const int lane = tid & 63, wave = tid >> 6;
  const int l15 = lane & 15, lhi = lane >> 4;

  __shared__ u16 Ks[2][64 * 64];
  __shared__ u16 Vs[2][64 * 64];
  __shared__ u16 Ps[4][16 * 64];
  u16* Pw = Ps[wave];

  const float SC = 0.18033688f;  // 0.125 * log2(e): softmax in exp2 domain

  auto stage = [&](int b, int kb) {
#pragma unroll
    for (int i = 0; i < 2; ++i) {
      int c = tid + i * 256;           // 512 chunks = 64x64 bf16
      int row = c >> 3, slot = c & 7;
      int scol = (slot ^ (row & 7)) * 8;  // inverse-swizzled source col
      GL2LDS16(qkv + (size_t)(kb * 64 + row) * 3072 + 1024 + h * 64 + scol,
               (char*)(Ks[b]) + c * 16);
      GL2LDS16(vt + (size_t)(h * 64 + row) * 4096 + kb * 64 + scol,
               (char*)(Vs[b]) + c * 16);
    }
  };

  int cur = 0;
  for (int rep = 0; rep < 2; ++rep) {
    const int qb = rep ? (63 - bx) : bx;
    const int q0 = qb * 64 + wave * 16;
    const u16* Qb = qkv + (size_t)(q0 + l15) * 3072 + h * 64;
    bf16x8 qf0 = *(const bf16x8*)(const void*)(Qb + lhi * 8);
    bf16x8 qf1 = *(const bf16x8*)(const void*)(Qb + 32 + lhi * 8);

    f32x4 oa[4] = {};
    float mrow[4] = {-1e30f, -1e30f, -1e30f, -1e30f};
    float lrow[4] = {0.f, 0.f, 0.f, 0.f};

    // prologue: stage tile 0 and drain (all waves' chunks must land)
    stage(cur, 0);
    asm volatile("s_waitcnt vmcnt(0)" ::: "memory");
    __builtin_amdgcn_s_barrier();

    for (int kb = 0; kb <= qb; ++kb) {
      // issue next tile's loads early; they fly under this tile's compute
      if (kb < qb) stage(cur ^ 1, kb + 1);

      // S = Q K^T  (A = Q rows in reg, B = K rows from LDS)
      f32x4 s[4] = {};
#pragma unroll
      for (int ks = 0; ks < 2; ++ks)
#pragma unroll
        for (int nf = 0; nf < 4; ++nf) {
          int row = nf * 16 + l15;
          int byt = row * 128 + ((lhi * 16 + ks * 64) ^ ((row & 7) << 4));
          bf16x8 kf = *(const bf16x8*)((const char*)(Ks[cur]) + byt);
          s[nf] = __builtin_amdgcn_mfma_f32_16x16x32_bf16(ks ? qf1 : qf0, kf,
                                                          s[nf], 0, 0, 0);
        }

      // scale into exp2 domain + causal mask (diagonal tile only)
      const bool diag = (kb == qb);
#pragma unroll
      for (int nf = 0; nf < 4; ++nf)
#pragma unroll
        for (int r = 0; r < 4; ++r) {
          float v = s[nf][r] * SC;
          if (diag && (nf * 16 + l15 > wave * 16 + lhi * 4 + r)) v = -1e30f;
          s[nf][r] = v;
        }

      // row max across 16 lanes (cols) x 4 frags
      float pm[4];
#pragma unroll
      for (int r = 0; r < 4; ++r)
        pm[r] = fmaxf(fmaxf(s[0][r], s[1][r]), fmaxf(s[2][r], s[3][r]));
#pragma unroll
      for (int off = 1; off < 16; off <<= 1)
#pragma unroll
        for (int r = 0; r < 4; ++r) pm[r] = fmaxf(pm[r], __shfl_xor(pm[r], off));

      // defer-max: only rescale when the running max grew by > 8 (=2^8 headroom)
      float gm = fmaxf(fmaxf(pm[0] - mrow[0], pm[1] - mrow[1]),
                       fmaxf(pm[2] - mrow[2], pm[3] - mrow[3]));
      if (__any(gm > 8.0f)) {
#pragma unroll
        for (int r = 0; r < 4; ++r) {
          float mn = fmaxf(mrow[r], pm[r]);
          float al = EXP2(mrow[r] - mn);
          mrow[r] = mn;
          lrow[r] *= al;
#pragma unroll
          for (int nf = 0; nf < 4; ++nf) oa[nf][r] *= al;
        }
      }

      // P = exp2(S - m)
#pragma unroll
      for (int nf = 0; nf < 4; ++nf)
#pragma unroll
        for (int r = 0; r < 4; ++r) s[nf][r] = EXP2(s[nf][r] - mrow[r]);

      float rs[4];
#pragma unroll
      for (int r = 0; r < 4; ++r)
        rs[r] = (s[0][r] + s[1][r]) + (s[2][r] + s[3][r]);
#pragma unroll
      for (int off = 1; off < 16; off <<= 1)
#pragma unroll
        for (int r = 0; r < 4; ++r) rs[r] += __shfl_xor(rs[r], off);
#pragma unroll
      for (int r = 0; r < 4; ++r) lrow[r] += rs[r];

      // P (C/D layout) -> per-wave LDS (swizzled), packed bf16 conversion
#pragma unroll
      for (int nf = 0; nf < 4; ++nf) {
        uint32_t pk0 = cvt_pk_bf16(s[nf][0], s[nf][1]);
        uint32_t pk1 = cvt_pk_bf16(s[nf][2], s[nf][3]);
        int col2 = (nf * 16 + l15) * 2;
        int row = lhi * 4;
        *(u16*)((char*)Pw + (row + 0) * 128 + (col2 ^ (((row + 0) & 7) << 4))) =
            (u16)pk0;
        *(u16*)((char*)Pw + (row + 1) * 128 + (col2 ^ (((row + 1) & 7) << 4))) =
            (u16)(pk0 >> 16);
        *(u16*)((char*)Pw + (row + 2) * 128 + (col2 ^ (((row + 2) & 7) << 4))) =
            (u16)pk1;
        *(u16*)((char*)Pw + (row + 3) * 128 + (col2 ^ (((row + 3) & 7) << 4))) =
            (u16)(pk1 >> 16);
      }

      // P A-fragments
      bf16x8 pf[2];
#pragma unroll
      for (int ks = 0; ks < 2; ++ks) {
        int byt = l15 * 128 + (((lhi * 8 + ks * 32) * 2) ^ ((l15 & 7) << 4));
        pf[ks] = *(const bf16x8*)((const char*)Pw + byt);
      }

      // O += P * V  (B-frag from V^T tile: row = d, contiguous along kv)
#pragma unroll
      for (int ks = 0; ks < 2; ++ks)
#pragma unroll
        for (int nf = 0; nf < 4; ++nf) {
          int row = nf * 16 + l15;
          int byt = row * 128 + ((ks * 64 + lhi * 16) ^ ((row & 7) << 4));
          bf16x8 vf = *(const bf16x8*)((const char*)(Vs[cur]) + byt);
          oa[nf] = __builtin_amdgcn_mfma_f32_16x16x32_bf16(pf[ks], vf, oa[nf],
                                                           0, 0, 0);
        }

      // next tile's staged data must be complete before anyone reads it;
      // barrier also fences buffer reuse (no wave still reads cur^1 past here)
      asm volatile("s_waitcnt vmcnt(0)" ::: "memory");
      __builtin_amdgcn_s_barrier();
      cur ^= 1;
    }

    // epilogue: O / l -> bf16
#pragma unroll
    for (int r = 0; r < 4; ++r) {
      float inv = 1.0f / lrow[r];
      int rowg = q0 + lhi * 4 + r;
#pragma unroll
      for (int nf = 0; nf < 4; ++nf)
        out[(size_t)rowg * 1024 + h * 64 + nf * 16 + l15] =
            f2bf(oa[nf][r] * inv);
    }
  }
}

// -----------------------------------------------------------------------------
extern "C" void kernel_launch(void* const* d_in, const int* in_sizes, int n_in,
                              void* d_out, int out_size, void* d_ws,
                              size_t ws_size, hipStream_t stream) {
  const float* x = (const float*)d_in[0];
  const float* wq = (const float*)d_in[1];
  const float* wk = (const float*)d_in[2];
  const float* wv = (const float*)d_in[3];
  const float* wo = (const float*)d_in[4];

  // workspace layout (bf16), ~48 MB total
  u16* xb = (u16*)d_ws;                      // [4096][1024]  (dead after QKV GEMM)
  u16* wqkv = xb + 4096 * 1024;              // [3072][1024] (wq|wk|wv rows)
  u16* wob = wqkv + 3072 * 1024;             // [1024][1024] (contiguous after wqkv)
  u16* qkv = wob + 1024 * 1024;              // [4096][3072]
  u16* atn = qkv + (size_t)4096 * 3072;      // [4096][1024]
  u16* vt = xb;                              // [1024][4096] V^T, reuses xb

  cast_kernel<<<2048, 256, 0, stream>>>(x, xb, 4096 * 1024);
  cast4_kernel<<<2048, 256, 0, stream>>>(wq, wk, wv, wo, wqkv);

  // QKV projection: [4096][3072] = x_bf16 * wqkv^T
  gemm_bt<u16><<<dim3(24, 32), 256, 0, stream>>>(xb, wqkv, qkv, 4096, 3072, 1024);
  // V transpose (xb no longer needed -> vt aliases it)
  vtrans_kernel<<<dim3(64, 16), 256, 0, stream>>>(qkv, vt);
  // causal flash attention per head (paired q-tiles for load balance)
  attn_kernel<<<dim3(32, 16), 256, 0, stream>>>(qkv, vt, atn);
  // output projection: fp32 out = attn_bf16 * wo^T
  gemm_bt<float><<<dim3(8, 32), 256, 0, stream>>>(atn, wob, (float*)d_out, 4096,
                                                  1024, 1024);
}

// Round 4
// 243.832 us; speedup vs baseline: 1.7862x; 1.1484x over previous
//
#include <hip/hip_runtime.h>
#include <hip/hip_bf16.h>
#include <stdint.h>

typedef unsigned short u16;
typedef float f32x4 __attribute__((ext_vector_type(4)));
typedef __bf16 bf16x8 __attribute__((ext_vector_type(8)));
typedef u16 u16x8 __attribute__((ext_vector_type(8)));

// async global->LDS, 16B per lane. LDS dest must be wave-uniform base + lane*16.
#define GL2LDS16(g, l)                                                          \
  __builtin_amdgcn_global_load_lds(                                             \
      (const __attribute__((address_space(1))) unsigned int*)(g),               \
      (__attribute__((address_space(3))) unsigned int*)(l), 16, 0, 0)

#if __has_builtin(__builtin_amdgcn_exp2f)
#define EXP2(x) __builtin_amdgcn_exp2f(x)
#else
#define EXP2(x) exp2f(x)
#endif

__device__ __forceinline__ u16 f2bf(float f) {
  uint32_t u = __builtin_bit_cast(uint32_t, f);
  return (u16)((u + 0x7FFFu + ((u >> 16) & 1u)) >> 16);  // RNE, no NaN inputs
}

__device__ __forceinline__ uint32_t cvt_pk_bf16(float lo, float hi) {
  uint32_t r;
  asm("v_cvt_pk_bf16_f32 %0, %1, %2" : "=v"(r) : "v"(lo), "v"(hi));
  return r;
}

// ---------------- fp32 -> bf16 cast (vectorized, 8 elems/thread) -------------
__device__ __forceinline__ void cast8(const float* __restrict__ s,
                                      u16* __restrict__ d) {
  const float4* p = (const float4*)s;
  float4 a = p[0], b = p[1];
  uint4 o;
  o.x = cvt_pk_bf16(a.x, a.y);
  o.y = cvt_pk_bf16(a.z, a.w);
  o.z = cvt_pk_bf16(b.x, b.y);
  o.w = cvt_pk_bf16(b.z, b.w);
  *(uint4*)d = o;
}

__global__ __launch_bounds__(256) void cast_kernel(const float* __restrict__ s,
                                                   u16* __restrict__ d, int n) {
  int i = (blockIdx.x * 256 + threadIdx.x) * 8;
  if (i >= n) return;
  cast8(s + i, d + i);
}

// 4 weight matrices (1M elems each) -> contiguous bf16 (wq|wk|wv|wo)
__global__ __launch_bounds__(256) void cast4_kernel(const float* __restrict__ s0,
                                                    const float* __restrict__ s1,
                                                    const float* __restrict__ s2,
                                                    const float* __restrict__ s3,
                                                    u16* __restrict__ d) {
  int b = blockIdx.x >> 9;
  int i = ((blockIdx.x & 511) * 256 + threadIdx.x) * 8;
  const float* s = (b == 0) ? s0 : (b == 1) ? s1 : (b == 2) ? s2 : s3;
  cast8(s + i, d + ((size_t)b << 20) + i);
}

// ---------------- bf16 GEMM, C = A * B^T  (A[M][K], B[N][K], both K-contig) --
template <typename CT>
__global__ __launch_bounds__(256) void gemm_bt(const u16* __restrict__ A,
                                               const u16* __restrict__ B,
                                               CT* __restrict__ C, int M, int N,
                                               int K) {
  __shared__ u16 As[128 * 32];
  __shared__ u16 Bs[128 * 32];
  const int tid = threadIdx.x;
  const int lane = tid & 63;
  const int l15 = lane & 15, lhi = lane >> 4;
  const int wave = tid >> 6;
  const int wr = (wave >> 1) * 64, wc = (wave & 1) * 64;
  const int m0 = blockIdx.y * 128, n0 = blockIdx.x * 128;

  f32x4 acc[4][4] = {};

  for (int k0 = 0; k0 < K; k0 += 32) {
    __syncthreads();
#pragma unroll
    for (int i = 0; i < 2; ++i) {
      int c = tid + i * 256;           // 16B chunk id, 512 chunks = 128x32 bf16
      int row = c >> 2, slot = c & 3;
      int scol = (slot ^ ((row >> 1) & 3)) * 8;  // inverse-swizzled source col
      GL2LDS16(A + (size_t)(m0 + row) * K + k0 + scol, (char*)As + c * 16);
      GL2LDS16(B + (size_t)(n0 + row) * K + k0 + scol, (char*)Bs + c * 16);
    }
    __syncthreads();
    bf16x8 af[4], bfr[4];
#pragma unroll
    for (int mi = 0; mi < 4; ++mi) {
      int row = wr + mi * 16 + l15;
      int byt = row * 64 + ((lhi ^ ((row >> 1) & 3)) << 4);
      af[mi] = *(const bf16x8*)((const char*)As + byt);
    }
#pragma unroll
    for (int ni = 0; ni < 4; ++ni) {
      int row = wc + ni * 16 + l15;
      int byt = row * 64 + ((lhi ^ ((row >> 1) & 3)) << 4);
      bfr[ni] = *(const bf16x8*)((const char*)Bs + byt);
    }
#pragma unroll
    for (int mi = 0; mi < 4; ++mi)
#pragma unroll
      for (int ni = 0; ni < 4; ++ni)
        acc[mi][ni] = __builtin_amdgcn_mfma_f32_16x16x32_bf16(
            af[mi], bfr[ni], acc[mi][ni], 0, 0, 0);
  }

#pragma unroll
  for (int mi = 0; mi < 4; ++mi) {
    int rbase = m0 + wr + mi * 16 + lhi * 4;
#pragma unroll
    for (int ni = 0; ni < 4; ++ni) {
      int col = n0 + wc + ni * 16 + l15;
#pragma unroll
      for (int r = 0; r < 4; ++r) {
        float v = acc[mi][ni][r];
        if constexpr (sizeof(CT) == 2)
          C[(size_t)(rbase + r) * N + col] = (CT)f2bf(v);
        else
          C[(size_t)(rbase + r) * N + col] = v;
      }
    }
  }
}

// ---------------- V transpose: qkv[4096][3072] V-cols -> vt[1024][4096] -----
__global__ __launch_bounds__(256) void vtrans_kernel(const u16* __restrict__ qkv,
                                                     u16* __restrict__ vt) {
  __shared__ u16 t[64][72];  // +8 pad breaks bank aliasing on column reads
  const int bs = blockIdx.x * 64;  // s tile
  const int be = blockIdx.y * 64;  // e tile (within 1024 V cols)
  const int tid = threadIdx.x;
#pragma unroll
  for (int i = 0; i < 2; ++i) {
    int c = tid + i * 256, row = c >> 3, col = (c & 7) * 8;
    *(u16x8*)&t[row][col] =
        *(const u16x8*)(qkv + (size_t)(bs + row) * 3072 + 2048 + be + col);
  }
  __syncthreads();
#pragma unroll
  for (int i = 0; i < 2; ++i) {
    int c = tid + i * 256, erow = c >> 3, scol = (c & 7) * 8;
    u16x8 o;
#pragma unroll
    for (int j = 0; j < 8; ++j) o[j] = t[scol + j][erow];
    *(u16x8*)(vt + (size_t)(be + erow) * 4096 + bs + scol) = o;
  }
}

// ---------------- causal flash attention --------------------------------------
// Swapped-QK^T structure: S fragment = mfma(K_frag, Q_frag) so each lane owns
// ONE q-row (q = l15) and 16 kv values -> in-lane softmax, 2 shfls per reduce.
// qkv: [4096][3072] bf16 (Q | K | V). vt: [16*64][4096] = V^T per head.
// Block = two paired q-tiles (bx, 63-bx) x head; 4 waves, 16 q-rows each.
// KV tile = 64, double-buffered. exp2-domain softmax + defer-max (THR=8).
__global__ __launch_bounds__(256) void attn_kernel(const u16* __restrict__ qkv,
                                                   const u16* __restrict__ vt,
                                                   u16* __restrict__ out) {
  const int h = blockIdx.y;
  const int bx = blockIdx.x;  // 0..31
  const int tid = threadIdx.x;
  const int lane = tid & 63, wave = tid >> 6;
  const int l15 = lane & 15, lhi = lane >> 4;

  __shared__ u16 Ks[2][64 * 64];
  __shared__ u16 Vs[2][64 * 64];
  __shared__ u16 Ps[4][16 * 64];
  u16* Pw = Ps[wave];

  const float SC = 0.18033688f;  // 0.125 * log2(e): softmax in exp2 domain

  // hoisted XOR-swizzled LDS offsets (kb-invariant)
  int koff[2][4];  // [ks][nf]: row = nf*16+l15, 16B col = lhi*16 + ks*64
#pragma unroll
  for (int ks = 0; ks < 2; ++ks)
#pragma unroll
    for (int nf = 0; nf < 4; ++nf) {
      int row = nf * 16 + l15;
      koff[ks][nf] = row * 128 + ((lhi * 16 + ks * 64) ^ ((row & 7) << 4));
    }
  int poff[4];  // P write: row = q = l15, 8B col = nf*32 + lhi*8
#pragma unroll
  for (int nf = 0; nf < 4; ++nf)
    poff[nf] = l15 * 128 + ((nf * 32 + lhi * 8) ^ ((l15 & 7) << 4));
  // P read reuses koff[ks][0] (row = l15, 16B col = lhi*16 + ks*64)

  auto stage = [&](int b, int kb) {
#pragma unroll
    for (int i = 0; i < 2; ++i) {
      int c = tid + i * 256;           // 512 chunks = 64x64 bf16
      int row = c >> 3, slot = c & 7;
      int scol = (slot ^ (row & 7)) * 8;  // inverse-swizzled source col
      GL2LDS16(qkv + (size_t)(kb * 64 + row) * 3072 + 1024 + h * 64 + scol,
               (char*)(Ks[b]) + c * 16);
      GL2LDS16(vt + (size_t)(h * 64 + row) * 4096 + kb * 64 + scol,
               (char*)(Vs[b]) + c * 16);
    }
  };

  int cur = 0;
  for (int rep = 0; rep < 2; ++rep) {
    const int qb = rep ? (63 - bx) : bx;
    const int q0 = qb * 64 + wave * 16;
    const u16* Qb = qkv + (size_t)(q0 + l15) * 3072 + h * 64;
    bf16x8 qf0 = *(const bf16x8*)(const void*)(Qb + lhi * 8);
    bf16x8 qf1 = *(const bf16x8*)(const void*)(Qb + 32 + lhi * 8);

    f32x4 oa[4] = {};
    float mrow = -1e30f, lrow = 0.f;  // scalars: this lane's q-row = l15

    // prologue: stage tile 0 and drain (all waves' chunks must land)
    stage(cur, 0);
    asm volatile("s_waitcnt vmcnt(0)" ::: "memory");
    __builtin_amdgcn_s_barrier();

    for (int kb = 0; kb <= qb; ++kb) {
      // issue next tile's loads early; they fly under this tile's compute
      if (kb < qb) stage(cur ^ 1, kb + 1);

      // S^T = K Q^T: s[nf][r] = S[kv = nf*16+lhi*4+r][q = l15]
      f32x4 s[4] = {};
#pragma unroll
      for (int ks = 0; ks < 2; ++ks)
#pragma unroll
        for (int nf = 0; nf < 4; ++nf) {
          bf16x8 kf =
              *(const bf16x8*)((const char*)(Ks[cur]) + koff[ks][nf]);
          s[nf] = __builtin_amdgcn_mfma_f32_16x16x32_bf16(kf, ks ? qf1 : qf0,
                                                          s[nf], 0, 0, 0);
        }

      // scale into exp2 domain + causal mask (diagonal tile only)
      if (kb == qb) {
        const int qloc = wave * 16 + l15;
#pragma unroll
        for (int nf = 0; nf < 4; ++nf)
#pragma unroll
          for (int r = 0; r < 4; ++r) {
            float v = s[nf][r] * SC;
            if (nf * 16 + lhi * 4 + r > qloc) v = -1e30f;
            s[nf][r] = v;
          }
      } else {
#pragma unroll
        for (int nf = 0; nf < 4; ++nf)
#pragma unroll
          for (int r = 0; r < 4; ++r) s[nf][r] *= SC;
      }

      // row max: in-lane over 16 kv + 2 shfls across lhi groups
      float pm0 = fmaxf(fmaxf(s[0][0], s[0][1]), fmaxf(s[0][2], s[0][3]));
      float pm1 = fmaxf(fmaxf(s[1][0], s[1][1]), fmaxf(s[1][2], s[1][3]));
      float pm2 = fmaxf(fmaxf(s[2][0], s[2][1]), fmaxf(s[2][2], s[2][3]));
      float pm3 = fmaxf(fmaxf(s[3][0], s[3][1]), fmaxf(s[3][2], s[3][3]));
      float pm = fmaxf(fmaxf(pm0, pm1), fmaxf(pm2, pm3));
      pm = fmaxf(pm, __shfl_xor(pm, 16));
      pm = fmaxf(pm, __shfl_xor(pm, 32));

      // defer-max: rescale only when running max grew by > 8 (2^8 headroom)
      if (__any(pm - mrow > 8.0f)) {
        float mn = fmaxf(mrow, pm);
        float al = EXP2(mrow - mn);
        mrow = mn;
        lrow *= al;
        float alq[4];
#pragma unroll
        for (int r = 0; r < 4; ++r) alq[r] = __shfl(al, lhi * 4 + r, 16);
#pragma unroll
        for (int nf = 0; nf < 4; ++nf)
#pragma unroll
          for (int r = 0; r < 4; ++r) oa[nf][r] *= alq[r];
      }

      // P = exp2(S - m); row sum in-lane + 2 shfls
#pragma unroll
      for (int nf = 0; nf < 4; ++nf)
#pragma unroll
        for (int r = 0; r < 4; ++r) s[nf][r] = EXP2(s[nf][r] - mrow);
      float rs = ((s[0][0] + s[0][1]) + (s[0][2] + s[0][3])) +
                 ((s[1][0] + s[1][1]) + (s[1][2] + s[1][3])) +
                 ((s[2][0] + s[2][1]) + (s[2][2] + s[2][3])) +
                 ((s[3][0] + s[3][1]) + (s[3][2] + s[3][3]));
      rs += __shfl_xor(rs, 16);
      rs += __shfl_xor(rs, 32);
      lrow += rs;

      // P -> LDS: lane's 4 kv values are contiguous -> one b64 write per frag
#pragma unroll
      for (int nf = 0; nf < 4; ++nf) {
        uint2 pk;
        pk.x = cvt_pk_bf16(s[nf][0], s[nf][1]);
        pk.y = cvt_pk_bf16(s[nf][2], s[nf][3]);
        *(uint2*)((char*)Pw + poff[nf]) = pk;
      }

      // P A-fragments (row = q = l15, contiguous kv)
      bf16x8 pf[2];
#pragma unroll
      for (int ks = 0; ks < 2; ++ks)
        pf[ks] = *(const bf16x8*)((const char*)Pw + koff[ks][0]);

      // O += P * V  (B-frag from V^T tile: row = d, contiguous along kv)
#pragma unroll
      for (int ks = 0; ks < 2; ++ks)
#pragma unroll
        for (int nf = 0; nf < 4; ++nf) {
          bf16x8 vf =
              *(const bf16x8*)((const char*)(Vs[cur]) + koff[ks][nf]);
          oa[nf] = __builtin_amdgcn_mfma_f32_16x16x32_bf16(pf[ks], vf, oa[nf],
                                                           0, 0, 0);
        }

      // staged next tile must be complete; barrier also fences buffer reuse
      asm volatile("s_waitcnt vmcnt(0)" ::: "memory");
      __builtin_amdgcn_s_barrier();
      cur ^= 1;
    }

    // epilogue: O / l -> bf16 (l lives in lane l15 = q; broadcast to rows)
    float linv[4];
#pragma unroll
    for (int r = 0; r < 4; ++r)
      linv[r] = 1.0f / __shfl(lrow, lhi * 4 + r, 16);
#pragma unroll
    for (int r = 0; r < 4; ++r) {
      int rowg = q0 + lhi * 4 + r;
#pragma unroll
      for (int nf = 0; nf < 4; ++nf)
        out[(size_t)rowg * 1024 + h * 64 + nf * 16 + l15] =
            f2bf(oa[nf][r] * linv[r]);
    }
  }
}

// -----------------------------------------------------------------------------
extern "C" void kernel_launch(void* const* d_in, const int* in_sizes, int n_in,
                              void* d_out, int out_size, void* d_ws,
                              size_t ws_size, hipStream_t stream) {
  const float* x = (const float*)d_in[0];
  const float* wq = (const float*)d_in[1];
  const float* wk = (const float*)d_in[2];
  const float* wv = (const float*)d_in[3];
  const float* wo = (const float*)d_in[4];

  // workspace layout (bf16), ~48 MB total
  u16* xb = (u16*)d_ws;                      // [4096][1024]  (dead after QKV GEMM)
  u16* wqkv = xb + 4096 * 1024;              // [3072][1024] (wq|wk|wv rows)
  u16* wob = wqkv + 3072 * 1024;             // [1024][1024] (contiguous after wqkv)
  u16* qkv = wob + 1024 * 1024;              // [4096][3072]
  u16* atn = qkv + (size_t)4096 * 3072;      // [4096][1024]
  u16* vt = xb;                              // [1024][4096] V^T, reuses xb

  cast_kernel<<<2048, 256, 0, stream>>>(x, xb, 4096 * 1024);
  cast4_kernel<<<2048, 256, 0, stream>>>(wq, wk, wv, wo, wqkv);

  // QKV projection: [4096][3072] = x_bf16 * wqkv^T
  gemm_bt<u16><<<dim3(24, 32), 256, 0, stream>>>(xb, wqkv, qkv, 4096, 3072, 1024);
  // V transpose (xb no longer needed -> vt aliases it)
  vtrans_kernel<<<dim3(64, 16), 256, 0, stream>>>(qkv, vt);
  // causal flash attention per head (paired q-tiles for load balance)
  attn_kernel<<<dim3(32, 16), 256, 0, stream>>>(qkv, vt, atn);
  // output projection: fp32 out = attn_bf16 * wo^T
  gemm_bt<float><<<dim3(8, 32), 256, 0, stream>>>(atn, wob, (float*)d_out, 4096,
                                                  1024, 1024);
}

// Round 5
// 242.551 us; speedup vs baseline: 1.7956x; 1.0053x over previous
//
#include <hip/hip_runtime.h>
#include <hip/hip_bf16.h>
#include <stdint.h>

typedef unsigned short u16;
typedef float f32x4 __attribute__((ext_vector_type(4)));
typedef __bf16 bf16x8 __attribute__((ext_vector_type(8)));
typedef u16 u16x8 __attribute__((ext_vector_type(8)));

// async global->LDS, 16B per lane. LDS dest must be wave-uniform base + lane*16.
#define GL2LDS16(g, l)                                                          \
  __builtin_amdgcn_global_load_lds(                                             \
      (const __attribute__((address_space(1))) unsigned int*)(g),               \
      (__attribute__((address_space(3))) unsigned int*)(l), 16, 0, 0)

#if __has_builtin(__builtin_amdgcn_exp2f)
#define EXP2(x) __builtin_amdgcn_exp2f(x)
#else
#define EXP2(x) exp2f(x)
#endif

#define SOFTMAX_SC 0.18033688f  // 0.125 * log2(e)

__device__ __forceinline__ u16 f2bf(float f) {
  uint32_t u = __builtin_bit_cast(uint32_t, f);
  return (u16)((u + 0x7FFFu + ((u >> 16) & 1u)) >> 16);  // RNE, no NaN inputs
}

__device__ __forceinline__ uint32_t cvt_pk_bf16(float lo, float hi) {
  uint32_t r;
  asm("v_cvt_pk_bf16_f32 %0, %1, %2" : "=v"(r) : "v"(lo), "v"(hi));
  return r;
}

// ---------------- fp32 -> bf16 cast (vectorized, 8 elems/thread) -------------
__device__ __forceinline__ void cast8(const float* __restrict__ s,
                                      u16* __restrict__ d) {
  const float4* p = (const float4*)s;
  float4 a = p[0], b = p[1];
  uint4 o;
  o.x = cvt_pk_bf16(a.x, a.y);
  o.y = cvt_pk_bf16(a.z, a.w);
  o.z = cvt_pk_bf16(b.x, b.y);
  o.w = cvt_pk_bf16(b.z, b.w);
  *(uint4*)d = o;
}

__global__ __launch_bounds__(256) void cast_kernel(const float* __restrict__ s,
                                                   u16* __restrict__ d, int n) {
  int i = (blockIdx.x * 256 + threadIdx.x) * 8;
  if (i >= n) return;
  cast8(s + i, d + i);
}

// 4 weight matrices (1M elems each) -> contiguous bf16 (wq|wk|wv|wo)
__global__ __launch_bounds__(256) void cast4_kernel(const float* __restrict__ s0,
                                                    const float* __restrict__ s1,
                                                    const float* __restrict__ s2,
                                                    const float* __restrict__ s3,
                                                    u16* __restrict__ d) {
  int b = blockIdx.x >> 9;
  int i = ((blockIdx.x & 511) * 256 + threadIdx.x) * 8;
  const float* s = (b == 0) ? s0 : (b == 1) ? s1 : (b == 2) ? s2 : s3;
  cast8(s + i, d + ((size_t)b << 20) + i);
}

// ---------------- 8-phase 256x256 bf16 GEMM, C = A * B^T ---------------------
// T3+T4 structure (m248-verified regime: K=1024). 512 thr = 8 waves (2Mx4N),
// BK=64, LDS 128KB double-buffered, per-phase barrier pair + lgkmcnt(0) +
// setprio MFMA cluster; next-tile global_load_lds front-loaded in phases 0-1.
// scaleq: multiply C cols < 1024 by SOFTMAX_SC (Q pre-scaling for attention).
__global__ __launch_bounds__(512, 2) void gemm8(const u16* __restrict__ A,
                                                const u16* __restrict__ B,
                                                u16* __restrict__ C, int M,
                                                int N, int K, int scaleq) {
  __shared__ u16 As[2][256 * 64];
  __shared__ u16 Bs[2][256 * 64];
  const int tid = threadIdx.x;
  const int lane = tid & 63;
  const int l15 = lane & 15, lhi = lane >> 4;
  const int wave = tid >> 6;
  const int wm = wave >> 2, wn = wave & 3;  // 2 x 4 waves
  const int m0 = blockIdx.y * 256, n0 = blockIdx.x * 256;
  const int nt = K >> 6;  // K-tiles of 64

  // hoisted swizzled LDS read offsets: row*128 + ((ks*4+lhi)^(l15&7))*16
  int aoff[2][8], boff[2][4];
#pragma unroll
  for (int ks = 0; ks < 2; ++ks) {
    int sl = ((ks * 4 + lhi) ^ (l15 & 7)) << 4;
#pragma unroll
    for (int m = 0; m < 8; ++m)
      aoff[ks][m] = (wm * 128 + m * 16 + l15) * 128 + sl;
#pragma unroll
    for (int n = 0; n < 4; ++n)
      boff[ks][n] = (wn * 64 + n * 16 + l15) * 128 + sl;
  }

  // stage unit u of K-tile t into buf b. u: 0/1 = A half, 2/3 = B half.
  // 1024 chunks of 16B per unit -> 2 gload_lds per thread.
  auto unit = [&](int b, int t, int u) {
    const u16* src = (u < 2) ? A : B;
    const int base = ((u < 2) ? m0 : n0) + (u & 1) * 128;
    u16* lb = ((u < 2) ? As[b] : Bs[b]) + (u & 1) * 128 * 64;
#pragma unroll
    for (int i = 0; i < 2; ++i) {
      int c = tid + i * 512;
      int row = c >> 3, slot = c & 7;
      int scol = (slot ^ (row & 7)) * 8;  // inverse swizzle on source
      GL2LDS16(src + (size_t)(base + row) * K + t * 64 + scol,
               (char*)lb + c * 16);
    }
  };

  f32x4 acc[8][4] = {};

  // prologue: stage tile 0, drain, barrier
#pragma unroll
  for (int u = 0; u < 4; ++u) unit(0, 0, u);
  asm volatile("s_waitcnt vmcnt(0)" ::: "memory");
  __builtin_amdgcn_s_barrier();

  int cur = 0;
  for (int t = 0; t < nt; ++t) {
    const bool pre = (t + 1) < nt;
    const char* Ab = (const char*)As[cur];
    const char* Bb = (const char*)Bs[cur];
    bf16x8 af[4], bfr[4];

#pragma unroll
    for (int p = 0; p < 4; ++p) {
      const int ks = p >> 1, mh = p & 1;
      // ds-read this phase's register subtile
#pragma unroll
      for (int j = 0; j < 4; ++j)
        af[j] = *(const bf16x8*)(Ab + aoff[ks][mh * 4 + j]);
      if (mh == 0) {
#pragma unroll
        for (int n = 0; n < 4; ++n)
          bfr[n] = *(const bf16x8*)(Bb + boff[ks][n]);
      }
      // front-load next tile's staging into phases 0 and 1
      if (p < 2 && pre) {
        unit(cur ^ 1, t + 1, p * 2);
        unit(cur ^ 1, t + 1, p * 2 + 1);
      }
      __builtin_amdgcn_s_barrier();
      asm volatile("s_waitcnt lgkmcnt(0)" ::: "memory");
      __builtin_amdgcn_sched_barrier(0);
      __builtin_amdgcn_s_setprio(1);
#pragma unroll
      for (int j = 0; j < 4; ++j)
#pragma unroll
        for (int n = 0; n < 4; ++n)
          acc[mh * 4 + j][n] = __builtin_amdgcn_mfma_f32_16x16x32_bf16(
              af[j], bfr[n], acc[mh * 4 + j][n], 0, 0, 0);
      __builtin_amdgcn_s_setprio(0);
      if (p == 3) asm volatile("s_waitcnt vmcnt(0)" ::: "memory");
      __builtin_amdgcn_s_barrier();
    }
    cur ^= 1;
  }

  // epilogue: C rows = m0+wm*128+m*16+lhi*4+r, cols = n0+wn*64+n*16+l15
#pragma unroll
  for (int m = 0; m < 8; ++m) {
    int rbase = m0 + wm * 128 + m * 16 + lhi * 4;
#pragma unroll
    for (int n = 0; n < 4; ++n) {
      int col = n0 + wn * 64 + n * 16 + l15;
      float sc = (scaleq && col < 1024) ? SOFTMAX_SC : 1.0f;
#pragma unroll
      for (int r = 0; r < 4; ++r)
        C[(size_t)(rbase + r) * N + col] = f2bf(acc[m][n][r] * sc);
    }
  }
}

// ---------------- bf16 GEMM, C = A * B^T (m97 128^2 structure, fp32 out) ----
template <typename CT>
__global__ __launch_bounds__(256) void gemm_bt(const u16* __restrict__ A,
                                               const u16* __restrict__ B,
                                               CT* __restrict__ C, int M, int N,
                                               int K) {
  __shared__ u16 As[128 * 32];
  __shared__ u16 Bs[128 * 32];
  const int tid = threadIdx.x;
  const int lane = tid & 63;
  const int l15 = lane & 15, lhi = lane >> 4;
  const int wave = tid >> 6;
  const int wr = (wave >> 1) * 64, wc = (wave & 1) * 64;
  const int m0 = blockIdx.y * 128, n0 = blockIdx.x * 128;

  f32x4 acc[4][4] = {};

  for (int k0 = 0; k0 < K; k0 += 32) {
    __syncthreads();
#pragma unroll
    for (int i = 0; i < 2; ++i) {
      int c = tid + i * 256;           // 16B chunk id, 512 chunks = 128x32 bf16
      int row = c >> 2, slot = c & 3;
      int scol = (slot ^ ((row >> 1) & 3)) * 8;  // inverse-swizzled source col
      GL2LDS16(A + (size_t)(m0 + row) * K + k0 + scol, (char*)As + c * 16);
      GL2LDS16(B + (size_t)(n0 + row) * K + k0 + scol, (char*)Bs + c * 16);
    }
    __syncthreads();
    bf16x8 af[4], bfr[4];
#pragma unroll
    for (int mi = 0; mi < 4; ++mi) {
      int row = wr + mi * 16 + l15;
      int byt = row * 64 + ((lhi ^ ((row >> 1) & 3)) << 4);
      af[mi] = *(const bf16x8*)((const char*)As + byt);
    }
#pragma unroll
    for (int ni = 0; ni < 4; ++ni) {
      int row = wc + ni * 16 + l15;
      int byt = row * 64 + ((lhi ^ ((row >> 1) & 3)) << 4);
      bfr[ni] = *(const bf16x8*)((const char*)Bs + byt);
    }
#pragma unroll
    for (int mi = 0; mi < 4; ++mi)
#pragma unroll
      for (int ni = 0; ni < 4; ++ni)
        acc[mi][ni] = __builtin_amdgcn_mfma_f32_16x16x32_bf16(
            af[mi], bfr[ni], acc[mi][ni], 0, 0, 0);
  }

#pragma unroll
  for (int mi = 0; mi < 4; ++mi) {
    int rbase = m0 + wr + mi * 16 + lhi * 4;
#pragma unroll
    for (int ni = 0; ni < 4; ++ni) {
      int col = n0 + wc + ni * 16 + l15;
#pragma unroll
      for (int r = 0; r < 4; ++r) {
        float v = acc[mi][ni][r];
        if constexpr (sizeof(CT) == 2)
          C[(size_t)(rbase + r) * N + col] = (CT)f2bf(v);
        else
          C[(size_t)(rbase + r) * N + col] = v;
      }
    }
  }
}

// ---------------- V transpose: qkv[4096][3072] V-cols -> vt[1024][4096] -----
__global__ __launch_bounds__(256) void vtrans_kernel(const u16* __restrict__ qkv,
                                                     u16* __restrict__ vt) {
  __shared__ u16 t[64][72];  // +8 pad breaks bank aliasing on column reads
  const int bs = blockIdx.x * 64;  // s tile
  const int be = blockIdx.y * 64;  // e tile (within 1024 V cols)
  const int tid = threadIdx.x;
#pragma unroll
  for (int i = 0; i < 2; ++i) {
    int c = tid + i * 256, row = c >> 3, col = (c & 7) * 8;
    *(u16x8*)&t[row][col] =
        *(const u16x8*)(qkv + (size_t)(bs + row) * 3072 + 2048 + be + col);
  }
  __syncthreads();
#pragma unroll
  for (int i = 0; i < 2; ++i) {
    int c = tid + i * 256, erow = c >> 3, scol = (c & 7) * 8;
    u16x8 o;
#pragma unroll
    for (int j = 0; j < 8; ++j) o[j] = t[scol + j][erow];
    *(u16x8*)(vt + (size_t)(be + erow) * 4096 + bs + scol) = o;
  }
}

// ---------------- causal flash attention --------------------------------------
// Swapped-QK^T: lane owns ONE q-row (= l15) x 16 kv -> in-lane softmax.
// Q is pre-scaled by SOFTMAX_SC in the gemm8 epilogue (exp2-domain softmax).
__global__ __launch_bounds__(256) void attn_kernel(const u16* __restrict__ qkv,
                                                   const u16* __restrict__ vt,
                                                   u16* __restrict__ out) {
  const int h = blockIdx.y;
  const int bx = blockIdx.x;  // 0..31
  const int tid = threadIdx.x;
  const int lane = tid & 63, wave = tid >> 6;
  const int l15 = lane & 15, lhi = lane >> 4;

  __shared__ u16 Ks[2][64 * 64];
  __shared__ u16 Vs[2][64 * 64];
  __shared__ u16 Ps[4][16 * 64];
  u16* Pw = Ps[wave];

  // hoisted XOR-swizzled LDS offsets (kb-invariant)
  int koff[2][4];  // [ks][nf]: row = nf*16+l15, 16B col = lhi*16 + ks*64
#pragma unroll
  for (int ks = 0; ks < 2; ++ks)
#pragma unroll
    for (int nf = 0; nf < 4; ++nf) {
      int row = nf * 16 + l15;
      koff[ks][nf] = row * 128 + ((lhi * 16 + ks * 64) ^ ((row & 7) << 4));
    }
  int poff[4];  // P write: row = q = l15, 8B col = nf*32 + lhi*8
#pragma unroll
  for (int nf = 0; nf < 4; ++nf)
    poff[nf] = l15 * 128 + ((nf * 32 + lhi * 8) ^ ((l15 & 7) << 4));

  auto stage = [&](int b, int kb) {
#pragma unroll
    for (int i = 0; i < 2; ++i) {
      int c = tid + i * 256;           // 512 chunks = 64x64 bf16
      int row = c >> 3, slot = c & 7;
      int scol = (slot ^ (row & 7)) * 8;  // inverse-swizzled source col
      GL2LDS16(qkv + (size_t)(kb * 64 + row) * 3072 + 1024 + h * 64 + scol,
               (char*)(Ks[b]) + c * 16);
      GL2LDS16(vt + (size_t)(h * 64 + row) * 4096 + kb * 64 + scol,
               (char*)(Vs[b]) + c * 16);
    }
  };

  int cur = 0;
  for (int rep = 0; rep < 2; ++rep) {
    const int qb = rep ? (63 - bx) : bx;
    const int q0 = qb * 64 + wave * 16;
    const u16* Qb = qkv + (size_t)(q0 + l15) * 3072 + h * 64;
    bf16x8 qf0 = *(const bf16x8*)(const void*)(Qb + lhi * 8);
    bf16x8 qf1 = *(const bf16x8*)(const void*)(Qb + 32 + lhi * 8);

    f32x4 oa[4] = {};
    float mrow = -1e30f, lrow = 0.f;  // scalars: this lane's q-row = l15

    // prologue: stage tile 0 and drain (all waves' chunks must land)
    stage(cur, 0);
    asm volatile("s_waitcnt vmcnt(0)" ::: "memory");
    __builtin_amdgcn_s_barrier();

    for (int kb = 0; kb <= qb; ++kb) {
      // issue next tile's loads early; they fly under this tile's compute
      if (kb < qb) stage(cur ^ 1, kb + 1);

      // S^T = K Q^T: s[nf][r] = S[kv = nf*16+lhi*4+r][q = l15] (pre-scaled)
      f32x4 s[4] = {};
#pragma unroll
      for (int ks = 0; ks < 2; ++ks)
#pragma unroll
        for (int nf = 0; nf < 4; ++nf) {
          bf16x8 kf =
              *(const bf16x8*)((const char*)(Ks[cur]) + koff[ks][nf]);
          s[nf] = __builtin_amdgcn_mfma_f32_16x16x32_bf16(kf, ks ? qf1 : qf0,
                                                          s[nf], 0, 0, 0);
        }

      // causal mask (diagonal tile only)
      if (kb == qb) {
        const int qloc = wave * 16 + l15;
#pragma unroll
        for (int nf = 0; nf < 4; ++nf)
#pragma unroll
          for (int r = 0; r < 4; ++r)
            if (nf * 16 + lhi * 4 + r > qloc) s[nf][r] = -1e30f;
      }

      // row max: in-lane over 16 kv + 2 shfls across lhi groups
      float pm0 = fmaxf(fmaxf(s[0][0], s[0][1]), fmaxf(s[0][2], s[0][3]));
      float pm1 = fmaxf(fmaxf(s[1][0], s[1][1]), fmaxf(s[1][2], s[1][3]));
      float pm2 = fmaxf(fmaxf(s[2][0], s[2][1]), fmaxf(s[2][2], s[2][3]));
      float pm3 = fmaxf(fmaxf(s[3][0], s[3][1]), fmaxf(s[3][2], s[3][3]));
      float pm = fmaxf(fmaxf(pm0, pm1), fmaxf(pm2, pm3));
      pm = fmaxf(pm, __shfl_xor(pm, 16));
      pm = fmaxf(pm, __shfl_xor(pm, 32));

      // defer-max: rescale only when running max grew by > 8 (2^8 headroom)
      if (__any(pm - mrow > 8.0f)) {
        float mn = fmaxf(mrow, pm);
        float al = EXP2(mrow - mn);
        mrow = mn;
        lrow *= al;
        float alq[4];
#pragma unroll
        for (int r = 0; r < 4; ++r) alq[r] = __shfl(al, lhi * 4 + r, 16);
#pragma unroll
        for (int nf = 0; nf < 4; ++nf)
#pragma unroll
          for (int r = 0; r < 4; ++r) oa[nf][r] *= alq[r];
      }

      // P = exp2(S - m); row sum in-lane + 2 shfls
#pragma unroll
      for (int nf = 0; nf < 4; ++nf)
#pragma unroll
        for (int r = 0; r < 4; ++r) s[nf][r] = EXP2(s[nf][r] - mrow);
      float rs = ((s[0][0] + s[0][1]) + (s[0][2] + s[0][3])) +
                 ((s[1][0] + s[1][1]) + (s[1][2] + s[1][3])) +
                 ((s[2][0] + s[2][1]) + (s[2][2] + s[2][3])) +
                 ((s[3][0] + s[3][1]) + (s[3][2] + s[3][3]));
      rs += __shfl_xor(rs, 16);
      rs += __shfl_xor(rs, 32);
      lrow += rs;

      // P -> LDS: lane's 4 kv values are contiguous -> one b64 write per frag
#pragma unroll
      for (int nf = 0; nf < 4; ++nf) {
        uint2 pk;
        pk.x = cvt_pk_bf16(s[nf][0], s[nf][1]);
        pk.y = cvt_pk_bf16(s[nf][2], s[nf][3]);
        *(uint2*)((char*)Pw + poff[nf]) = pk;
      }

      // P A-fragments (row = q = l15, contiguous kv)
      bf16x8 pf[2];
#pragma unroll
      for (int ks = 0; ks < 2; ++ks)
        pf[ks] = *(const bf16x8*)((const char*)Pw + koff[ks][0]);

      // O += P * V  (B-frag from V^T tile: row = d, contiguous along kv)
#pragma unroll
      for (int ks = 0; ks < 2; ++ks)
#pragma unroll
        for (int nf = 0; nf < 4; ++nf) {
          bf16x8 vf =
              *(const bf16x8*)((const char*)(Vs[cur]) + koff[ks][nf]);
          oa[nf] = __builtin_amdgcn_mfma_f32_16x16x32_bf16(pf[ks], vf, oa[nf],
                                                           0, 0, 0);
        }

      // staged next tile must be complete; barrier also fences buffer reuse
      asm volatile("s_waitcnt vmcnt(0)" ::: "memory");
      __builtin_amdgcn_s_barrier();
      cur ^= 1;
    }

    // epilogue: O / l -> bf16 (l lives in lane l15 = q; broadcast to rows)
    float linv[4];
#pragma unroll
    for (int r = 0; r < 4; ++r)
      linv[r] = 1.0f / __shfl(lrow, lhi * 4 + r, 16);
#pragma unroll
    for (int r = 0; r < 4; ++r) {
      int rowg = q0 + lhi * 4 + r;
#pragma unroll
      for (int nf = 0; nf < 4; ++nf)
        out[(size_t)rowg * 1024 + h * 64 + nf * 16 + l15] =
            f2bf(oa[nf][r] * linv[r]);
    }
  }
}

// -----------------------------------------------------------------------------
extern "C" void kernel_launch(void* const* d_in, const int* in_sizes, int n_in,
                              void* d_out, int out_size, void* d_ws,
                              size_t ws_size, hipStream_t stream) {
  const float* x = (const float*)d_in[0];
  const float* wq = (const float*)d_in[1];
  const float* wk = (const float*)d_in[2];
  const float* wv = (const float*)d_in[3];
  const float* wo = (const float*)d_in[4];

  // workspace layout (bf16), ~48 MB total
  u16* xb = (u16*)d_ws;                      // [4096][1024]  (dead after QKV GEMM)
  u16* wqkv = xb + 4096 * 1024;              // [3072][1024] (wq|wk|wv rows)
  u16* wob = wqkv + 3072 * 1024;             // [1024][1024] (contiguous after wqkv)
  u16* qkv = wob + 1024 * 1024;              // [4096][3072]
  u16* atn = qkv + (size_t)4096 * 3072;      // [4096][1024]
  u16* vt = xb;                              // [1024][4096] V^T, reuses xb

  cast_kernel<<<2048, 256, 0, stream>>>(x, xb, 4096 * 1024);
  cast4_kernel<<<2048, 256, 0, stream>>>(wq, wk, wv, wo, wqkv);

  // QKV projection: [4096][3072] = x_bf16 * wqkv^T (8-phase 256^2; Q pre-scaled)
  gemm8<<<dim3(12, 16), 512, 0, stream>>>(xb, wqkv, qkv, 4096, 3072, 1024, 1);
  // V transpose (xb no longer needed -> vt aliases it)
  vtrans_kernel<<<dim3(64, 16), 256, 0, stream>>>(qkv, vt);
  // causal flash attention per head (paired q-tiles for load balance)
  attn_kernel<<<dim3(32, 16), 256, 0, stream>>>(qkv, vt, atn);
  // output projection: fp32 out = attn_bf16 * wo^T
  gemm_bt<float><<<dim3(8, 32), 256, 0, stream>>>(atn, wob, (float*)d_out, 4096,
                                                  1024, 1024);
}

// Round 6
// 238.718 us; speedup vs baseline: 1.8244x; 1.0161x over previous
//
#include <hip/hip_runtime.h>
#include <hip/hip_bf16.h>
#include <stdint.h>

typedef unsigned short u16;
typedef float f32x4 __attribute__((ext_vector_type(4)));
typedef __bf16 bf16x8 __attribute__((ext_vector_type(8)));
typedef u16 u16x8 __attribute__((ext_vector_type(8)));

// async global->LDS, 16B per lane. LDS dest must be wave-uniform base + lane*16.
#define GL2LDS16(g, l)                                                          \
  __builtin_amdgcn_global_load_lds(                                             \
      (const __attribute__((address_space(1))) unsigned int*)(g),               \
      (__attribute__((address_space(3))) unsigned int*)(l), 16, 0, 0)

#if __has_builtin(__builtin_amdgcn_exp2f)
#define EXP2(x) __builtin_amdgcn_exp2f(x)
#else
#define EXP2(x) exp2f(x)
#endif

#define SOFTMAX_SC 0.18033688f  // 0.125 * log2(e)

__device__ __forceinline__ u16 f2bf(float f) {
  uint32_t u = __builtin_bit_cast(uint32_t, f);
  return (u16)((u + 0x7FFFu + ((u >> 16) & 1u)) >> 16);  // RNE, no NaN inputs
}

__device__ __forceinline__ uint32_t cvt_pk_bf16(float lo, float hi) {
  uint32_t r;
  asm("v_cvt_pk_bf16_f32 %0, %1, %2" : "=v"(r) : "v"(lo), "v"(hi));
  return r;
}

// ---------------- fp32 -> bf16 cast (vectorized, 8 elems/thread) -------------
__device__ __forceinline__ void cast8(const float* __restrict__ s,
                                      u16* __restrict__ d) {
  const float4* p = (const float4*)s;
  float4 a = p[0], b = p[1];
  uint4 o;
  o.x = cvt_pk_bf16(a.x, a.y);
  o.y = cvt_pk_bf16(a.z, a.w);
  o.z = cvt_pk_bf16(b.x, b.y);
  o.w = cvt_pk_bf16(b.z, b.w);
  *(uint4*)d = o;
}

__global__ __launch_bounds__(256) void cast_kernel(const float* __restrict__ s,
                                                   u16* __restrict__ d, int n) {
  int i = (blockIdx.x * 256 + threadIdx.x) * 8;
  if (i >= n) return;
  cast8(s + i, d + i);
}

// 4 weight matrices (1M elems each) -> contiguous bf16 (wq|wk|wv|wo)
__global__ __launch_bounds__(256) void cast4_kernel(const float* __restrict__ s0,
                                                    const float* __restrict__ s1,
                                                    const float* __restrict__ s2,
                                                    const float* __restrict__ s3,
                                                    u16* __restrict__ d) {
  int b = blockIdx.x >> 9;
  int i = ((blockIdx.x & 511) * 256 + threadIdx.x) * 8;
  const float* s = (b == 0) ? s0 : (b == 1) ? s1 : (b == 2) ? s2 : s3;
  cast8(s + i, d + ((size_t)b << 20) + i);
}

// ---------------- 16-MFMA phase cluster (compile-time m-base) ----------------
template <int MB>
__device__ __forceinline__ void mfma16(f32x4 (&acc)[8][4], const bf16x8 (&af)[4],
                                       const bf16x8 (&bfr)[4]) {
  asm volatile("s_waitcnt lgkmcnt(0)" ::: "memory");
  __builtin_amdgcn_sched_barrier(0);
  __builtin_amdgcn_s_setprio(1);
#pragma unroll
  for (int j = 0; j < 4; ++j)
#pragma unroll
    for (int n = 0; n < 4; ++n)
      acc[MB + j][n] = __builtin_amdgcn_mfma_f32_16x16x32_bf16(
          af[j], bfr[n], acc[MB + j][n], 0, 0, 0);
  __builtin_amdgcn_s_setprio(0);
}

// ---------------- 8-phase 256x256 bf16 GEMM with COUNTED vmcnt (T3+T4) -------
// 8 waves (2M x 4N), BK=64, 2 K-tiles per iteration. LDS: 4 half-slots per
// operand ([2 dbuf][2 half] of 128x64). One/two half-tiles staged per phase;
// tile-boundary waits are vmcnt(4) (needed batch retired oldest-first, next
// batch of 4 loads stays in flight). vmcnt(0) only at the final tail.
// Slot-reuse audit: A/B-odd slots staged p1/p2 (last read prev p8); A/B-even
// slots staged p5/p6 (last read p4). scaleq: C cols <1024 *= SOFTMAX_SC.
__global__ __launch_bounds__(512, 2) void gemm8k(const u16* __restrict__ A,
                                                 const u16* __restrict__ B,
                                                 u16* __restrict__ C, int M,
                                                 int N, int K, int scaleq) {
  __shared__ u16 As[4][128 * 64];
  __shared__ u16 Bs[4][128 * 64];
  const int tid = threadIdx.x;
  const int lane = tid & 63;
  const int l15 = lane & 15, lhi = lane >> 4;
  const int wave = tid >> 6;
  const int wm = wave >> 2, wn = wave & 3;
  // XCD-aware bijective swizzle (nwg % 8 == 0 for our grids)
  int bid = blockIdx.y * gridDim.x + blockIdx.x;
  const int cpx = (gridDim.x * gridDim.y) >> 3;
  bid = (bid & 7) * cpx + (bid >> 3);
  const int m0 = (bid / gridDim.x) * 256, n0 = (bid % gridDim.x) * 256;
  const int nt = K >> 6;  // K-tiles of 64 (even)

  // swizzled LDS read offsets within a 128x64 half-slot
  int aoff[2][8], boff[2][4];
#pragma unroll
  for (int ks = 0; ks < 2; ++ks) {
    const int sl = ((ks * 4 + lhi) ^ (l15 & 7)) << 4;
#pragma unroll
    for (int m = 0; m < 8; ++m) aoff[ks][m] = (m * 16 + l15) * 128 + sl;
#pragma unroll
    for (int n = 0; n < 4; ++n)
      boff[ks][n] = ((wn & 1) * 64 + n * 16 + l15) * 128 + sl;
  }

  // stage half h of K-tile T (1024 chunks of 16B; 2 loads/thread)
  auto stA = [&](int T, int h) {
    u16* lb = As[(T & 1) * 2 + h];
#pragma unroll
    for (int i = 0; i < 2; ++i) {
      int c = tid + i * 512;
      int row = c >> 3;
      int scol = ((c & 7) ^ (row & 7)) * 8;
      GL2LDS16(A + (size_t)(m0 + h * 128 + row) * K + T * 64 + scol,
               (char*)lb + c * 16);
    }
  };
  auto stB = [&](int T, int h) {
    u16* lb = Bs[(T & 1) * 2 + h];
#pragma unroll
    for (int i = 0; i < 2; ++i) {
      int c = tid + i * 512;
      int row = c >> 3;
      int scol = ((c & 7) ^ (row & 7)) * 8;
      GL2LDS16(B + (size_t)(n0 + h * 128 + row) * K + T * 64 + scol,
               (char*)lb + c * 16);
    }
  };

  f32x4 acc[8][4] = {};

  // prologue: stage K-tile 0 fully (8 loads/thread)
  stA(0, 0); stA(0, 1); stB(0, 0); stB(0, 1);
  asm volatile("s_waitcnt vmcnt(0)" ::: "memory");
  __builtin_amdgcn_s_barrier();

  for (int i = 0; i < nt / 2; ++i) {
    const int e = 2 * i, o = e + 1;
    const char* Ae = (const char*)As[wm];
    const char* Be = (const char*)Bs[wn >> 1];
    const char* Ao = (const char*)As[2 + wm];
    const char* Bo = (const char*)Bs[2 + (wn >> 1)];
    bf16x8 af[4], bfr[4];
    const bool pre = (e + 2) < nt;

    // p1: stage A-odds; wait evens landed (odds fly); MFMA e ks0 mh0
    stA(o, 0); stA(o, 1);
    asm volatile("s_waitcnt vmcnt(4)" ::: "memory");
    __builtin_amdgcn_s_barrier();
#pragma unroll
    for (int j = 0; j < 4; ++j) af[j] = *(const bf16x8*)(Ae + aoff[0][j]);
#pragma unroll
    for (int n = 0; n < 4; ++n) bfr[n] = *(const bf16x8*)(Be + boff[0][n]);
    mfma16<0>(acc, af, bfr);
    __builtin_amdgcn_s_barrier();
    // p2: MFMA e ks0 mh1; stage B-odds
#pragma unroll
    for (int j = 0; j < 4; ++j) af[j] = *(const bf16x8*)(Ae + aoff[0][4 + j]);
    stB(o, 0); stB(o, 1);
    __builtin_amdgcn_s_barrier();
    mfma16<4>(acc, af, bfr);
    __builtin_amdgcn_s_barrier();
    // p3: MFMA e ks1 mh0
#pragma unroll
    for (int j = 0; j < 4; ++j) af[j] = *(const bf16x8*)(Ae + aoff[1][j]);
#pragma unroll
    for (int n = 0; n < 4; ++n) bfr[n] = *(const bf16x8*)(Be + boff[1][n]);
    __builtin_amdgcn_s_barrier();
    mfma16<0>(acc, af, bfr);
    __builtin_amdgcn_s_barrier();
    // p4: MFMA e ks1 mh1
#pragma unroll
    for (int j = 0; j < 4; ++j) af[j] = *(const bf16x8*)(Ae + aoff[1][4 + j]);
    __builtin_amdgcn_s_barrier();
    mfma16<4>(acc, af, bfr);
    __builtin_amdgcn_s_barrier();
    // p5: stage A-evens(t+2); wait odds landed (evens fly); MFMA o ks0 mh0
    if (pre) {
      stA(e + 2, 0); stA(e + 2, 1);
      asm volatile("s_waitcnt vmcnt(4)" ::: "memory");
    } else {
      asm volatile("s_waitcnt vmcnt(0)" ::: "memory");
    }
    __builtin_amdgcn_s_barrier();
#pragma unroll
    for (int j = 0; j < 4; ++j) af[j] = *(const bf16x8*)(Ao + aoff[0][j]);
#pragma unroll
    for (int n = 0; n < 4; ++n) bfr[n] = *(const bf16x8*)(Bo + boff[0][n]);
    mfma16<0>(acc, af, bfr);
    __builtin_amdgcn_s_barrier();
    // p6: MFMA o ks0 mh1; stage B-evens(t+2)
#pragma unroll
    for (int j = 0; j < 4; ++j) af[j] = *(const bf16x8*)(Ao + aoff[0][4 + j]);
    if (pre) { stB(e + 2, 0); stB(e + 2, 1); }
    __builtin_amdgcn_s_barrier();
    mfma16<4>(acc, af, bfr);
    __builtin_amdgcn_s_barrier();
    // p7: MFMA o ks1 mh0
#pragma unroll
    for (int j = 0; j < 4; ++j) af[j] = *(const bf16x8*)(Ao + aoff[1][j]);
#pragma unroll
    for (int n = 0; n < 4; ++n) bfr[n] = *(const bf16x8*)(Bo + boff[1][n]);
    __builtin_amdgcn_s_barrier();
    mfma16<0>(acc, af, bfr);
    __builtin_amdgcn_s_barrier();
    // p8: MFMA o ks1 mh1
#pragma unroll
    for (int j = 0; j < 4; ++j) af[j] = *(const bf16x8*)(Ao + aoff[1][4 + j]);
    __builtin_amdgcn_s_barrier();
    mfma16<4>(acc, af, bfr);
    __builtin_amdgcn_s_barrier();
  }

  // epilogue: rows m0 + wm*128 + m*16 + lhi*4 + r; cols n0 + wn*64 + n*16 + l15
#pragma unroll
  for (int m = 0; m < 8; ++m) {
    int rbase = m0 + wm * 128 + m * 16 + lhi * 4;
#pragma unroll
    for (int n = 0; n < 4; ++n) {
      int col = n0 + wn * 64 + n * 16 + l15;
      float sc = (scaleq && col < 1024) ? SOFTMAX_SC : 1.0f;
#pragma unroll
      for (int r = 0; r < 4; ++r)
        C[(size_t)(rbase + r) * N + col] = f2bf(acc[m][n][r] * sc);
    }
  }
}

// ---------------- bf16 GEMM, C = A * B^T (m97 128^2 structure, fp32 out) ----
template <typename CT>
__global__ __launch_bounds__(256) void gemm_bt(const u16* __restrict__ A,
                                               const u16* __restrict__ B,
                                               CT* __restrict__ C, int M, int N,
                                               int K) {
  __shared__ u16 As[128 * 32];
  __shared__ u16 Bs[128 * 32];
  const int tid = threadIdx.x;
  const int lane = tid & 63;
  const int l15 = lane & 15, lhi = lane >> 4;
  const int wave = tid >> 6;
  const int wr = (wave >> 1) * 64, wc = (wave & 1) * 64;
  const int m0 = blockIdx.y * 128, n0 = blockIdx.x * 128;

  f32x4 acc[4][4] = {};

  for (int k0 = 0; k0 < K; k0 += 32) {
    __syncthreads();
#pragma unroll
    for (int i = 0; i < 2; ++i) {
      int c = tid + i * 256;           // 16B chunk id, 512 chunks = 128x32 bf16
      int row = c >> 2, slot = c & 3;
      int scol = (slot ^ ((row >> 1) & 3)) * 8;  // inverse-swizzled source col
      GL2LDS16(A + (size_t)(m0 + row) * K + k0 + scol, (char*)As + c * 16);
      GL2LDS16(B + (size_t)(n0 + row) * K + k0 + scol, (char*)Bs + c * 16);
    }
    __syncthreads();
    bf16x8 af[4], bfr[4];
#pragma unroll
    for (int mi = 0; mi < 4; ++mi) {
      int row = wr + mi * 16 + l15;
      int byt = row * 64 + ((lhi ^ ((row >> 1) & 3)) << 4);
      af[mi] = *(const bf16x8*)((const char*)As + byt);
    }
#pragma unroll
    for (int ni = 0; ni < 4; ++ni) {
      int row = wc + ni * 16 + l15;
      int byt = row * 64 + ((lhi ^ ((row >> 1) & 3)) << 4);
      bfr[ni] = *(const bf16x8*)((const char*)Bs + byt);
    }
#pragma unroll
    for (int mi = 0; mi < 4; ++mi)
#pragma unroll
      for (int ni = 0; ni < 4; ++ni)
        acc[mi][ni] = __builtin_amdgcn_mfma_f32_16x16x32_bf16(
            af[mi], bfr[ni], acc[mi][ni], 0, 0, 0);
  }

#pragma unroll
  for (int mi = 0; mi < 4; ++mi) {
    int rbase = m0 + wr + mi * 16 + lhi * 4;
#pragma unroll
    for (int ni = 0; ni < 4; ++ni) {
      int col = n0 + wc + ni * 16 + l15;
#pragma unroll
      for (int r = 0; r < 4; ++r) {
        float v = acc[mi][ni][r];
        if constexpr (sizeof(CT) == 2)
          C[(size_t)(rbase + r) * N + col] = (CT)f2bf(v);
        else
          C[(size_t)(rbase + r) * N + col] = v;
      }
    }
  }
}

// ---------------- V transpose: qkv[4096][3072] V-cols -> vt[1024][4096] -----
__global__ __launch_bounds__(256) void vtrans_kernel(const u16* __restrict__ qkv,
                                                     u16* __restrict__ vt) {
  __shared__ u16 t[64][72];  // +8 pad breaks bank aliasing on column reads
  const int bs = blockIdx.x * 64;  // s tile
  const int be = blockIdx.y * 64;  // e tile (within 1024 V cols)
  const int tid = threadIdx.x;
#pragma unroll
  for (int i = 0; i < 2; ++i) {
    int c = tid + i * 256, row = c >> 3, col = (c & 7) * 8;
    *(u16x8*)&t[row][col] =
        *(const u16x8*)(qkv + (size_t)(bs + row) * 3072 + 2048 + be + col);
  }
  __syncthreads();
#pragma unroll
  for (int i = 0; i < 2; ++i) {
    int c = tid + i * 256, erow = c >> 3, scol = (c & 7) * 8;
    u16x8 o;
#pragma unroll
    for (int j = 0; j < 8; ++j) o[j] = t[scol + j][erow];
    *(u16x8*)(vt + (size_t)(be + erow) * 4096 + bs + scol) = o;
  }
}

// ---------------- causal flash attention --------------------------------------
// 8 waves / 128 q-rows per block (halves K/V traffic vs 4-wave). Swapped-QK^T:
// lane owns ONE q-row (= l15) x 16 kv -> in-lane softmax. Q pre-scaled by
// SOFTMAX_SC in gemm8k epilogue. Paired q-supertiles (bx, 31-bx): 68 tiles/blk.
__global__ __launch_bounds__(512) void attn_kernel(const u16* __restrict__ qkv,
                                                   const u16* __restrict__ vt,
                                                   u16* __restrict__ out) {
  const int h = blockIdx.y;
  const int bx = blockIdx.x;  // 0..15
  const int tid = threadIdx.x;
  const int lane = tid & 63, wave = tid >> 6;  // wave 0..7
  const int l15 = lane & 15, lhi = lane >> 4;

  __shared__ u16 Ks[2][64 * 64];
  __shared__ u16 Vs[2][64 * 64];
  __shared__ u16 Ps[8][16 * 64];
  u16* Pw = Ps[wave];

  // hoisted XOR-swizzled LDS offsets (kb-invariant)
  int koff[2][4];  // [ks][nf]: row = nf*16+l15, 16B col = lhi*16 + ks*64
#pragma unroll
  for (int ks = 0; ks < 2; ++ks)
#pragma unroll
    for (int nf = 0; nf < 4; ++nf) {
      int row = nf * 16 + l15;
      koff[ks][nf] = row * 128 + ((lhi * 16 + ks * 64) ^ ((row & 7) << 4));
    }
  int poff[4];  // P write: row = q = l15, 8B col = nf*32 + lhi*8
#pragma unroll
  for (int nf = 0; nf < 4; ++nf)
    poff[nf] = l15 * 128 + ((nf * 32 + lhi * 8) ^ ((l15 & 7) << 4));

  auto stage = [&](int b, int kb) {
    int c = tid;  // 512 chunks = 64x64 bf16, one per thread
    int row = c >> 3, slot = c & 7;
    int scol = (slot ^ (row & 7)) * 8;  // inverse-swizzled source col
    GL2LDS16(qkv + (size_t)(kb * 64 + row) * 3072 + 1024 + h * 64 + scol,
             (char*)(Ks[b]) + c * 16);
    GL2LDS16(vt + (size_t)(h * 64 + row) * 4096 + kb * 64 + scol,
             (char*)(Vs[b]) + c * 16);
  };

  int cur = 0;
  for (int rep = 0; rep < 2; ++rep) {
    const int qsb = rep ? (31 - bx) : bx;   // 128-row q-supertile
    const int ntile = 2 * qsb + 2;          // kv tiles of 64
    const int q0 = qsb * 128 + wave * 16;
    const u16* Qb = qkv + (size_t)(q0 + l15) * 3072 + h * 64;
    bf16x8 qf0 = *(const bf16x8*)(const void*)(Qb + lhi * 8);
    bf16x8 qf1 = *(const bf16x8*)(const void*)(Qb + 32 + lhi * 8);

    f32x4 oa[4] = {};
    float mrow = -1e30f, lrow = 0.f;  // scalars: this lane's q-row = l15

    // prologue: stage tile 0 and drain (all waves' chunks must land)
    stage(cur, 0);
    asm volatile("s_waitcnt vmcnt(0)" ::: "memory");
    __builtin_amdgcn_s_barrier();

    for (int kb = 0; kb < ntile; ++kb) {
      // issue next tile's loads early; they fly under this tile's compute
      if (kb + 1 < ntile) stage(cur ^ 1, kb + 1);

      // S^T = K Q^T: s[nf][r] = S[kv = kb*64 + nf*16+lhi*4+r][q = q0+l15]
      f32x4 s[4] = {};
#pragma unroll
      for (int ks = 0; ks < 2; ++ks)
#pragma unroll
        for (int nf = 0; nf < 4; ++nf) {
          bf16x8 kf =
              *(const bf16x8*)((const char*)(Ks[cur]) + koff[ks][nf]);
          s[nf] = __builtin_amdgcn_mfma_f32_16x16x32_bf16(kf, ks ? qf1 : qf0,
                                                          s[nf], 0, 0, 0);
        }

      // causal mask (wave-uniform branch; elementwise kv>q inside)
      if (kb * 64 + 63 > q0) {
        const int q = q0 + l15;
#pragma unroll
        for (int nf = 0; nf < 4; ++nf)
#pragma unroll
          for (int r = 0; r < 4; ++r)
            if (kb * 64 + nf * 16 + lhi * 4 + r > q) s[nf][r] = -1e30f;
      }

      // row max: in-lane over 16 kv + 2 shfls across lhi groups
      float pm0 = fmaxf(fmaxf(s[0][0], s[0][1]), fmaxf(s[0][2], s[0][3]));
      float pm1 = fmaxf(fmaxf(s[1][0], s[1][1]), fmaxf(s[1][2], s[1][3]));
      float pm2 = fmaxf(fmaxf(s[2][0], s[2][1]), fmaxf(s[2][2], s[2][3]));
      float pm3 = fmaxf(fmaxf(s[3][0], s[3][1]), fmaxf(s[3][2], s[3][3]));
      float pm = fmaxf(fmaxf(pm0, pm1), fmaxf(pm2, pm3));
      pm = fmaxf(pm, __shfl_xor(pm, 16));
      pm = fmaxf(pm, __shfl_xor(pm, 32));

      // defer-max: rescale only when running max grew by > 8 (2^8 headroom)
      if (__any(pm - mrow > 8.0f)) {
        float mn = fmaxf(mrow, pm);
        float al = EXP2(mrow - mn);
        mrow = mn;
        lrow *= al;
        float alq[4];
#pragma unroll
        for (int r = 0; r < 4; ++r) alq[r] = __shfl(al, lhi * 4 + r, 16);
#pragma unroll
        for (int nf = 0; nf < 4; ++nf)
#pragma unroll
          for (int r = 0; r < 4; ++r) oa[nf][r] *= alq[r];
      }

      // P = exp2(S - m); row sum in-lane + 2 shfls
#pragma unroll
      for (int nf = 0; nf < 4; ++nf)
#pragma unroll
        for (int r = 0; r < 4; ++r) s[nf][r] = EXP2(s[nf][r] - mrow);
      float rs = ((s[0][0] + s[0][1]) + (s[0][2] + s[0][3])) +
                 ((s[1][0] + s[1][1]) + (s[1][2] + s[1][3])) +
                 ((s[2][0] + s[2][1]) + (s[2][2] + s[2][3])) +
                 ((s[3][0] + s[3][1]) + (s[3][2] + s[3][3]));
      rs += __shfl_xor(rs, 16);
      rs += __shfl_xor(rs, 32);
      lrow += rs;

      // P -> LDS: lane's 4 kv values are contiguous -> one b64 write per frag
#pragma unroll
      for (int nf = 0; nf < 4; ++nf) {
        uint2 pk;
        pk.x = cvt_pk_bf16(s[nf][0], s[nf][1]);
        pk.y = cvt_pk_bf16(s[nf][2], s[nf][3]);
        *(uint2*)((char*)Pw + poff[nf]) = pk;
      }

      // P A-fragments (row = q = l15, contiguous kv)
      bf16x8 pf[2];
#pragma unroll
      for (int ks = 0; ks < 2; ++ks)
        pf[ks] = *(const bf16x8*)((const char*)Pw + koff[ks][0]);

      // O += P * V  (B-frag from V^T tile: row = d, contiguous along kv)
#pragma unroll
      for (int ks = 0; ks < 2; ++ks)
#pragma unroll
        for (int nf = 0; nf < 4; ++nf) {
          bf16x8 vf =
              *(const bf16x8*)((const char*)(Vs[cur]) + koff[ks][nf]);
          oa[nf] = __builtin_amdgcn_mfma_f32_16x16x32_bf16(pf[ks], vf, oa[nf],
                                                           0, 0, 0);
        }

      // staged next tile must be complete; barrier also fences buffer reuse
      asm volatile("s_waitcnt vmcnt(0)" ::: "memory");
      __builtin_amdgcn_s_barrier();
      cur ^= 1;
    }

    // epilogue: O / l -> bf16 (l lives in lane l15 = q; broadcast to rows)
    float linv[4];
#pragma unroll
    for (int r = 0; r < 4; ++r)
      linv[r] = 1.0f / __shfl(lrow, lhi * 4 + r, 16);
#pragma unroll
    for (int r = 0; r < 4; ++r) {
      int rowg = q0 + lhi * 4 + r;
#pragma unroll
      for (int nf = 0; nf < 4; ++nf)
        out[(size_t)rowg * 1024 + h * 64 + nf * 16 + l15] =
            f2bf(oa[nf][r] * linv[r]);
    }
  }
}

// -----------------------------------------------------------------------------
extern "C" void kernel_launch(void* const* d_in, const int* in_sizes, int n_in,
                              void* d_out, int out_size, void* d_ws,
                              size_t ws_size, hipStream_t stream) {
  const float* x = (const float*)d_in[0];
  const float* wq = (const float*)d_in[1];
  const float* wk = (const float*)d_in[2];
  const float* wv = (const float*)d_in[3];
  const float* wo = (const float*)d_in[4];

  // workspace layout (bf16), ~48 MB total
  u16* xb = (u16*)d_ws;                      // [4096][1024]  (dead after QKV GEMM)
  u16* wqkv = xb + 4096 * 1024;              // [3072][1024] (wq|wk|wv rows)
  u16* wob = wqkv + 3072 * 1024;             // [1024][1024] (contiguous after wqkv)
  u16* qkv = wob + 1024 * 1024;              // [4096][3072]
  u16* atn = qkv + (size_t)4096 * 3072;      // [4096][1024]
  u16* vt = xb;                              // [1024][4096] V^T, reuses xb

  cast_kernel<<<2048, 256, 0, stream>>>(x, xb, 4096 * 1024);
  cast4_kernel<<<2048, 256, 0, stream>>>(wq, wk, wv, wo, wqkv);

  // QKV projection: [4096][3072] = x_bf16 * wqkv^T (counted-vmcnt 8-phase)
  gemm8k<<<dim3(12, 16), 512, 0, stream>>>(xb, wqkv, qkv, 4096, 3072, 1024, 1);
  // V transpose (xb no longer needed -> vt aliases it)
  vtrans_kernel<<<dim3(64, 16), 256, 0, stream>>>(qkv, vt);
  // causal flash attention per head (8 waves, 128 q-rows, paired supertiles)
  attn_kernel<<<dim3(16, 16), 512, 0, stream>>>(qkv, vt, atn);
  // output projection: fp32 out = attn_bf16 * wo^T
  gemm_bt<float><<<dim3(8, 32), 256, 0, stream>>>(atn, wob, (float*)d_out, 4096,
                                                  1024, 1024);
}

// Round 7
// 219.852 us; speedup vs baseline: 1.9810x; 1.0858x over previous
//
#include <hip/hip_runtime.h>
#include <hip/hip_bf16.h>
#include <stdint.h>

typedef unsigned short u16;
typedef float f32x4 __attribute__((ext_vector_type(4)));
typedef __bf16 bf16x8 __attribute__((ext_vector_type(8)));
typedef u16 u16x8 __attribute__((ext_vector_type(8)));

// async global->LDS, 16B per lane. LDS dest must be wave-uniform base + lane*16.
#define GL2LDS16(g, l)                                                          \
  __builtin_amdgcn_global_load_lds(                                             \
      (const __attribute__((address_space(1))) unsigned int*)(g),               \
      (__attribute__((address_space(3))) unsigned int*)(l), 16, 0, 0)

#if __has_builtin(__builtin_amdgcn_exp2f)
#define EXP2(x) __builtin_amdgcn_exp2f(x)
#else
#define EXP2(x) exp2f(x)
#endif

#define SOFTMAX_SC 0.18033688f  // 0.125 * log2(e)

__device__ __forceinline__ u16 f2bf(float f) {
  uint32_t u = __builtin_bit_cast(uint32_t, f);
  return (u16)((u + 0x7FFFu + ((u >> 16) & 1u)) >> 16);  // RNE, no NaN inputs
}

__device__ __forceinline__ float bf2f(u16 b) {
  return __builtin_bit_cast(float, (uint32_t)b << 16);
}

__device__ __forceinline__ uint32_t cvt_pk_bf16(float lo, float hi) {
  uint32_t r;
  asm("v_cvt_pk_bf16_f32 %0, %1, %2" : "=v"(r) : "v"(lo), "v"(hi));
  return r;
}

// ---------------- fp32 -> bf16 cast (vectorized, 8 elems/thread) -------------
__device__ __forceinline__ void cast8(const float* __restrict__ s,
                                      u16* __restrict__ d) {
  const float4* p = (const float4*)s;
  float4 a = p[0], b = p[1];
  uint4 o;
  o.x = cvt_pk_bf16(a.x, a.y);
  o.y = cvt_pk_bf16(a.z, a.w);
  o.z = cvt_pk_bf16(b.x, b.y);
  o.w = cvt_pk_bf16(b.z, b.w);
  *(uint4*)d = o;
}

__global__ __launch_bounds__(256) void cast_kernel(const float* __restrict__ s,
                                                   u16* __restrict__ d, int n) {
  int i = (blockIdx.x * 256 + threadIdx.x) * 8;
  if (i >= n) return;
  cast8(s + i, d + i);
}

// 4 weight matrices (1M elems each) -> contiguous bf16 (wq|wk|wv|wo)
__global__ __launch_bounds__(256) void cast4_kernel(const float* __restrict__ s0,
                                                    const float* __restrict__ s1,
                                                    const float* __restrict__ s2,
                                                    const float* __restrict__ s3,
                                                    u16* __restrict__ d) {
  int b = blockIdx.x >> 9;
  int i = ((blockIdx.x & 511) * 256 + threadIdx.x) * 8;
  const float* s = (b == 0) ? s0 : (b == 1) ? s1 : (b == 2) ? s2 : s3;
  cast8(s + i, d + ((size_t)b << 20) + i);
}

// ---------------- 16-MFMA phase cluster (compile-time m-base) ----------------
template <int MB>
__device__ __forceinline__ void mfma16(f32x4 (&acc)[8][4], const bf16x8 (&af)[4],
                                       const bf16x8 (&bfr)[4]) {
  asm volatile("s_waitcnt lgkmcnt(0)" ::: "memory");
  __builtin_amdgcn_sched_barrier(0);
  __builtin_amdgcn_s_setprio(1);
#pragma unroll
  for (int j = 0; j < 4; ++j)
#pragma unroll
    for (int n = 0; n < 4; ++n)
      acc[MB + j][n] = __builtin_amdgcn_mfma_f32_16x16x32_bf16(
          af[j], bfr[n], acc[MB + j][n], 0, 0, 0);
  __builtin_amdgcn_s_setprio(0);
}

// ---------------- 8-phase 256x256 bf16 GEMM with COUNTED vmcnt (T3+T4) -------
__global__ __launch_bounds__(512, 2) void gemm8k(const u16* __restrict__ A,
                                                 const u16* __restrict__ B,
                                                 u16* __restrict__ C, int M,
                                                 int N, int K, int scaleq) {
  __shared__ u16 As[4][128 * 64];
  __shared__ u16 Bs[4][128 * 64];
  const int tid = threadIdx.x;
  const int lane = tid & 63;
  const int l15 = lane & 15, lhi = lane >> 4;
  const int wave = tid >> 6;
  const int wm = wave >> 2, wn = wave & 3;
  // XCD-aware bijective swizzle (nwg % 8 == 0 for our grids)
  int bid = blockIdx.y * gridDim.x + blockIdx.x;
  const int cpx = (gridDim.x * gridDim.y) >> 3;
  bid = (bid & 7) * cpx + (bid >> 3);
  const int m0 = (bid / gridDim.x) * 256, n0 = (bid % gridDim.x) * 256;
  const int nt = K >> 6;  // K-tiles of 64 (even)

  // swizzled LDS read offsets within a 128x64 half-slot
  int aoff[2][8], boff[2][4];
#pragma unroll
  for (int ks = 0; ks < 2; ++ks) {
    const int sl = ((ks * 4 + lhi) ^ (l15 & 7)) << 4;
#pragma unroll
    for (int m = 0; m < 8; ++m) aoff[ks][m] = (m * 16 + l15) * 128 + sl;
#pragma unroll
    for (int n = 0; n < 4; ++n)
      boff[ks][n] = ((wn & 1) * 64 + n * 16 + l15) * 128 + sl;
  }

  auto stA = [&](int T, int h) {
    u16* lb = As[(T & 1) * 2 + h];
#pragma unroll
    for (int i = 0; i < 2; ++i) {
      int c = tid + i * 512;
      int row = c >> 3;
      int scol = ((c & 7) ^ (row & 7)) * 8;
      GL2LDS16(A + (size_t)(m0 + h * 128 + row) * K + T * 64 + scol,
               (char*)lb + c * 16);
    }
  };
  auto stB = [&](int T, int h) {
    u16* lb = Bs[(T & 1) * 2 + h];
#pragma unroll
    for (int i = 0; i < 2; ++i) {
      int c = tid + i * 512;
      int row = c >> 3;
      int scol = ((c & 7) ^ (row & 7)) * 8;
      GL2LDS16(B + (size_t)(n0 + h * 128 + row) * K + T * 64 + scol,
               (char*)lb + c * 16);
    }
  };

  f32x4 acc[8][4] = {};

  stA(0, 0); stA(0, 1); stB(0, 0); stB(0, 1);
  asm volatile("s_waitcnt vmcnt(0)" ::: "memory");
  __builtin_amdgcn_s_barrier();

  for (int i = 0; i < nt / 2; ++i) {
    const int e = 2 * i, o = e + 1;
    const char* Ae = (const char*)As[wm];
    const char* Be = (const char*)Bs[wn >> 1];
    const char* Ao = (const char*)As[2 + wm];
    const char* Bo = (const char*)Bs[2 + (wn >> 1)];
    bf16x8 af[4], bfr[4];
    const bool pre = (e + 2) < nt;

    // p1: stage A-odds; wait evens landed (odds fly); MFMA e ks0 mh0
    stA(o, 0); stA(o, 1);
    asm volatile("s_waitcnt vmcnt(4)" ::: "memory");
    __builtin_amdgcn_s_barrier();
#pragma unroll
    for (int j = 0; j < 4; ++j) af[j] = *(const bf16x8*)(Ae + aoff[0][j]);
#pragma unroll
    for (int n = 0; n < 4; ++n) bfr[n] = *(const bf16x8*)(Be + boff[0][n]);
    mfma16<0>(acc, af, bfr);
    __builtin_amdgcn_s_barrier();
    // p2: MFMA e ks0 mh1; stage B-odds
#pragma unroll
    for (int j = 0; j < 4; ++j) af[j] = *(const bf16x8*)(Ae + aoff[0][4 + j]);
    stB(o, 0); stB(o, 1);
    __builtin_amdgcn_s_barrier();
    mfma16<4>(acc, af, bfr);
    __builtin_amdgcn_s_barrier();
    // p3: MFMA e ks1 mh0
#pragma unroll
    for (int j = 0; j < 4; ++j) af[j] = *(const bf16x8*)(Ae + aoff[1][j]);
#pragma unroll
    for (int n = 0; n < 4; ++n) bfr[n] = *(const bf16x8*)(Be + boff[1][n]);
    __builtin_amdgcn_s_barrier();
    mfma16<0>(acc, af, bfr);
    __builtin_amdgcn_s_barrier();
    // p4: MFMA e ks1 mh1
#pragma unroll
    for (int j = 0; j < 4; ++j) af[j] = *(const bf16x8*)(Ae + aoff[1][4 + j]);
    __builtin_amdgcn_s_barrier();
    mfma16<4>(acc, af, bfr);
    __builtin_amdgcn_s_barrier();
    // p5: stage A-evens(t+2); wait odds landed; MFMA o ks0 mh0
    if (pre) {
      stA(e + 2, 0); stA(e + 2, 1);
      asm volatile("s_waitcnt vmcnt(4)" ::: "memory");
    } else {
      asm volatile("s_waitcnt vmcnt(0)" ::: "memory");
    }
    __builtin_amdgcn_s_barrier();
#pragma unroll
    for (int j = 0; j < 4; ++j) af[j] = *(const bf16x8*)(Ao + aoff[0][j]);
#pragma unroll
    for (int n = 0; n < 4; ++n) bfr[n] = *(const bf16x8*)(Bo + boff[0][n]);
    mfma16<0>(acc, af, bfr);
    __builtin_amdgcn_s_barrier();
    // p6: MFMA o ks0 mh1; stage B-evens(t+2)
#pragma unroll
    for (int j = 0; j < 4; ++j) af[j] = *(const bf16x8*)(Ao + aoff[0][4 + j]);
    if (pre) { stB(e + 2, 0); stB(e + 2, 1); }
    __builtin_amdgcn_s_barrier();
    mfma16<4>(acc, af, bfr);
    __builtin_amdgcn_s_barrier();
    // p7: MFMA o ks1 mh0
#pragma unroll
    for (int j = 0; j < 4; ++j) af[j] = *(const bf16x8*)(Ao + aoff[1][j]);
#pragma unroll
    for (int n = 0; n < 4; ++n) bfr[n] = *(const bf16x8*)(Bo + boff[1][n]);
    __builtin_amdgcn_s_barrier();
    mfma16<0>(acc, af, bfr);
    __builtin_amdgcn_s_barrier();
    // p8: MFMA o ks1 mh1
#pragma unroll
    for (int j = 0; j < 4; ++j) af[j] = *(const bf16x8*)(Ao + aoff[1][4 + j]);
    __builtin_amdgcn_s_barrier();
    mfma16<4>(acc, af, bfr);
    __builtin_amdgcn_s_barrier();
  }

#pragma unroll
  for (int m = 0; m < 8; ++m) {
    int rbase = m0 + wm * 128 + m * 16 + lhi * 4;
#pragma unroll
    for (int n = 0; n < 4; ++n) {
      int col = n0 + wn * 64 + n * 16 + l15;
      float sc = (scaleq && col < 1024) ? SOFTMAX_SC : 1.0f;
#pragma unroll
      for (int r = 0; r < 4; ++r)
        C[(size_t)(rbase + r) * N + col] = f2bf(acc[m][n][r] * sc);
    }
  }
}

// ---------------- bf16 GEMM, C = A * B^T (m97 128^2 structure, fp32 out) ----
template <typename CT>
__global__ __launch_bounds__(256) void gemm_bt(const u16* __restrict__ A,
                                               const u16* __restrict__ B,
                                               CT* __restrict__ C, int M, int N,
                                               int K) {
  __shared__ u16 As[128 * 32];
  __shared__ u16 Bs[128 * 32];
  const int tid = threadIdx.x;
  const int lane = tid & 63;
  const int l15 = lane & 15, lhi = lane >> 4;
  const int wave = tid >> 6;
  const int wr = (wave >> 1) * 64, wc = (wave & 1) * 64;
  const int m0 = blockIdx.y * 128, n0 = blockIdx.x * 128;

  f32x4 acc[4][4] = {};

  for (int k0 = 0; k0 < K; k0 += 32) {
    __syncthreads();
#pragma unroll
    for (int i = 0; i < 2; ++i) {
      int c = tid + i * 256;           // 16B chunk id, 512 chunks = 128x32 bf16
      int row = c >> 2, slot = c & 3;
      int scol = (slot ^ ((row >> 1) & 3)) * 8;  // inverse-swizzled source col
      GL2LDS16(A + (size_t)(m0 + row) * K + k0 + scol, (char*)As + c * 16);
      GL2LDS16(B + (size_t)(n0 + row) * K + k0 + scol, (char*)Bs + c * 16);
    }
    __syncthreads();
    bf16x8 af[4], bfr[4];
#pragma unroll
    for (int mi = 0; mi < 4; ++mi) {
      int row = wr + mi * 16 + l15;
      int byt = row * 64 + ((lhi ^ ((row >> 1) & 3)) << 4);
      af[mi] = *(const bf16x8*)((const char*)As + byt);
    }
#pragma unroll
    for (int ni = 0; ni < 4; ++ni) {
      int row = wc + ni * 16 + l15;
      int byt = row * 64 + ((lhi ^ ((row >> 1) & 3)) << 4);
      bfr[ni] = *(const bf16x8*)((const char*)Bs + byt);
    }
#pragma unroll
    for (int mi = 0; mi < 4; ++mi)
#pragma unroll
      for (int ni = 0; ni < 4; ++ni)
        acc[mi][ni] = __builtin_amdgcn_mfma_f32_16x16x32_bf16(
            af[mi], bfr[ni], acc[mi][ni], 0, 0, 0);
  }

#pragma unroll
  for (int mi = 0; mi < 4; ++mi) {
    int rbase = m0 + wr + mi * 16 + lhi * 4;
#pragma unroll
    for (int ni = 0; ni < 4; ++ni) {
      int col = n0 + wc + ni * 16 + l15;
#pragma unroll
      for (int r = 0; r < 4; ++r) {
        float v = acc[mi][ni][r];
        if constexpr (sizeof(CT) == 2)
          C[(size_t)(rbase + r) * N + col] = (CT)f2bf(v);
        else
          C[(size_t)(rbase + r) * N + col] = v;
      }
    }
  }
}

// ---------------- V transpose: qkv[4096][3072] V-cols -> vt[1024][4096] -----
__global__ __launch_bounds__(256) void vtrans_kernel(const u16* __restrict__ qkv,
                                                     u16* __restrict__ vt) {
  __shared__ u16 t[64][72];  // +8 pad breaks bank aliasing on column reads
  const int bs = blockIdx.x * 64;  // s tile
  const int be = blockIdx.y * 64;  // e tile (within 1024 V cols)
  const int tid = threadIdx.x;
#pragma unroll
  for (int i = 0; i < 2; ++i) {
    int c = tid + i * 256, row = c >> 3, col = (c & 7) * 8;
    *(u16x8*)&t[row][col] =
        *(const u16x8*)(qkv + (size_t)(bs + row) * 3072 + 2048 + be + col);
  }
  __syncthreads();
#pragma unroll
  for (int i = 0; i < 2; ++i) {
    int c = tid + i * 256, erow = c >> 3, scol = (c & 7) * 8;
    u16x8 o;
#pragma unroll
    for (int j = 0; j < 8; ++j) o[j] = t[scol + j][erow];
    *(u16x8*)(vt + (size_t)(be + erow) * 4096 + bs + scol) = o;
  }
}

// ---------------- causal flash attention (kv-split halves) -------------------
// 8 waves / 128 q-rows. Swapped-QK^T: lane owns ONE q-row (= l15) x 16 kv.
// Q pre-scaled by SOFTMAX_SC in gemm8k. Paired supertiles (bx, 31-bx).
// blockIdx.z = kv half: supertile qsb has T=2qsb+2 tiles; half0=[0,qsb+1),
// half1=[qsb+1,T) -> every block exactly 33 tiles; 512 blocks = 2/CU.
// Writes normalized partial O (bf16) + per-row (m,l) for the merge kernel.
__global__ __launch_bounds__(512) void attn_kernel(const u16* __restrict__ qkv,
                                                   const u16* __restrict__ vt,
                                                   u16* __restrict__ pout,
                                                   float2* __restrict__ mlb) {
  const int h = blockIdx.y;
  const int bx = blockIdx.x;        // 0..15
  const int half = blockIdx.z;      // 0..1
  const int tid = threadIdx.x;
  const int lane = tid & 63, wave = tid >> 6;  // wave 0..7
  const int l15 = lane & 15, lhi = lane >> 4;

  u16* po = pout + (size_t)half * 4096 * 1024;
  float2* ml = mlb + (size_t)half * 4096 * 16;

  __shared__ u16 Ks[2][64 * 64];
  __shared__ u16 Vs[2][64 * 64];
  __shared__ u16 Ps[8][16 * 64];
  u16* Pw = Ps[wave];

  // hoisted XOR-swizzled LDS offsets (kb-invariant)
  int koff[2][4];  // [ks][nf]: row = nf*16+l15, 16B col = lhi*16 + ks*64
#pragma unroll
  for (int ks = 0; ks < 2; ++ks)
#pragma unroll
    for (int nf = 0; nf < 4; ++nf) {
      int row = nf * 16 + l15;
      koff[ks][nf] = row * 128 + ((lhi * 16 + ks * 64) ^ ((row & 7) << 4));
    }
  int poff[4];  // P write: row = q = l15, 8B col = nf*32 + lhi*8
#pragma unroll
  for (int nf = 0; nf < 4; ++nf)
    poff[nf] = l15 * 128 + ((nf * 32 + lhi * 8) ^ ((l15 & 7) << 4));

  auto stage = [&](int b, int kb) {
    int c = tid;  // 512 chunks = 64x64 bf16, one per thread
    int row = c >> 3, slot = c & 7;
    int scol = (slot ^ (row & 7)) * 8;  // inverse-swizzled source col
    GL2LDS16(qkv + (size_t)(kb * 64 + row) * 3072 + 1024 + h * 64 + scol,
             (char*)(Ks[b]) + c * 16);
    GL2LDS16(vt + (size_t)(h * 64 + row) * 4096 + kb * 64 + scol,
             (char*)(Vs[b]) + c * 16);
  };

  int cur = 0;
  for (int rep = 0; rep < 2; ++rep) {
    const int qsb = rep ? (31 - bx) : bx;   // 128-row q-supertile
    const int kb0 = half * (qsb + 1);       // this half's kv-tile range
    const int kbe = kb0 + qsb + 1;
    const int q0 = qsb * 128 + wave * 16;
    const u16* Qb = qkv + (size_t)(q0 + l15) * 3072 + h * 64;
    bf16x8 qf0 = *(const bf16x8*)(const void*)(Qb + lhi * 8);
    bf16x8 qf1 = *(const bf16x8*)(const void*)(Qb + 32 + lhi * 8);

    f32x4 oa[4] = {};
    float mrow = -1e30f, lrow = 0.f;  // scalars: this lane's q-row = l15

    // prologue: stage first tile and drain
    stage(cur, kb0);
    asm volatile("s_waitcnt vmcnt(0)" ::: "memory");
    __builtin_amdgcn_s_barrier();

    for (int kb = kb0; kb < kbe; ++kb) {
      if (kb + 1 < kbe) stage(cur ^ 1, kb + 1);

      // S^T = K Q^T: s[nf][r] = S[kv = kb*64 + nf*16+lhi*4+r][q = q0+l15]
      f32x4 s[4] = {};
#pragma unroll
      for (int ks = 0; ks < 2; ++ks)
#pragma unroll
        for (int nf = 0; nf < 4; ++nf) {
          bf16x8 kf =
              *(const bf16x8*)((const char*)(Ks[cur]) + koff[ks][nf]);
          s[nf] = __builtin_amdgcn_mfma_f32_16x16x32_bf16(kf, ks ? qf1 : qf0,
                                                          s[nf], 0, 0, 0);
        }

      // causal mask (wave-uniform branch; elementwise kv>q inside)
      if (kb * 64 + 63 > q0) {
        const int q = q0 + l15;
#pragma unroll
        for (int nf = 0; nf < 4; ++nf)
#pragma unroll
          for (int r = 0; r < 4; ++r)
            if (kb * 64 + nf * 16 + lhi * 4 + r > q) s[nf][r] = -1e30f;
      }

      // row max: in-lane over 16 kv + 2 shfls across lhi groups
      float pm0 = fmaxf(fmaxf(s[0][0], s[0][1]), fmaxf(s[0][2], s[0][3]));
      float pm1 = fmaxf(fmaxf(s[1][0], s[1][1]), fmaxf(s[1][2], s[1][3]));
      float pm2 = fmaxf(fmaxf(s[2][0], s[2][1]), fmaxf(s[2][2], s[2][3]));
      float pm3 = fmaxf(fmaxf(s[3][0], s[3][1]), fmaxf(s[3][2], s[3][3]));
      float pm = fmaxf(fmaxf(pm0, pm1), fmaxf(pm2, pm3));
      pm = fmaxf(pm, __shfl_xor(pm, 16));
      pm = fmaxf(pm, __shfl_xor(pm, 32));

      // defer-max: rescale only when running max grew by > 8 (2^8 headroom)
      if (__any(pm - mrow > 8.0f)) {
        float mn = fmaxf(mrow, pm);
        float al = EXP2(mrow - mn);
        mrow = mn;
        lrow *= al;
        float alq[4];
#pragma unroll
        for (int r = 0; r < 4; ++r) alq[r] = __shfl(al, lhi * 4 + r, 16);
#pragma unroll
        for (int nf = 0; nf < 4; ++nf)
#pragma unroll
          for (int r = 0; r < 4; ++r) oa[nf][r] *= alq[r];
      }

      // P = exp2(S - m); row sum in-lane + 2 shfls
#pragma unroll
      for (int nf = 0; nf < 4; ++nf)
#pragma unroll
        for (int r = 0; r < 4; ++r) s[nf][r] = EXP2(s[nf][r] - mrow);
      float rs = ((s[0][0] + s[0][1]) + (s[0][2] + s[0][3])) +
                 ((s[1][0] + s[1][1]) + (s[1][2] + s[1][3])) +
                 ((s[2][0] + s[2][1]) + (s[2][2] + s[2][3])) +
                 ((s[3][0] + s[3][1]) + (s[3][2] + s[3][3]));
      rs += __shfl_xor(rs, 16);
      rs += __shfl_xor(rs, 32);
      lrow += rs;

      // P -> LDS: lane's 4 kv values contiguous -> one b64 write per frag
#pragma unroll
      for (int nf = 0; nf < 4; ++nf) {
        uint2 pk;
        pk.x = cvt_pk_bf16(s[nf][0], s[nf][1]);
        pk.y = cvt_pk_bf16(s[nf][2], s[nf][3]);
        *(uint2*)((char*)Pw + poff[nf]) = pk;
      }

      // P A-fragments (row = q = l15, contiguous kv)
      bf16x8 pf[2];
#pragma unroll
      for (int ks = 0; ks < 2; ++ks)
        pf[ks] = *(const bf16x8*)((const char*)Pw + koff[ks][0]);

      // O += P * V  (B-frag from V^T tile: row = d, contiguous along kv)
#pragma unroll
      for (int ks = 0; ks < 2; ++ks)
#pragma unroll
        for (int nf = 0; nf < 4; ++nf) {
          bf16x8 vf =
              *(const bf16x8*)((const char*)(Vs[cur]) + koff[ks][nf]);
          oa[nf] = __builtin_amdgcn_mfma_f32_16x16x32_bf16(pf[ks], vf, oa[nf],
                                                           0, 0, 0);
        }

      // staged next tile must be complete; barrier also fences buffer reuse
      asm volatile("s_waitcnt vmcnt(0)" ::: "memory");
      __builtin_amdgcn_s_barrier();
      cur ^= 1;
    }

    // epilogue: normalized partial O -> bf16; (m,l) per q-row for merge
    float linv[4];
#pragma unroll
    for (int r = 0; r < 4; ++r)
      linv[r] = 1.0f / __shfl(lrow, lhi * 4 + r, 16);
#pragma unroll
    for (int r = 0; r < 4; ++r) {
      int rowg = q0 + lhi * 4 + r;
#pragma unroll
      for (int nf = 0; nf < 4; ++nf)
        po[(size_t)rowg * 1024 + h * 64 + nf * 16 + l15] =
            f2bf(oa[nf][r] * linv[r]);
    }
    if (lhi == 0) ml[(q0 + l15) * 16 + h] = float2{mrow, lrow};
  }
}

// ---------------- merge the two kv-half partials -----------------------------
__global__ __launch_bounds__(256) void merge_kernel(const u16* __restrict__ po,
                                                    const float2* __restrict__ mlb,
                                                    u16* __restrict__ atn) {
  int base = (blockIdx.x * 256 + threadIdx.x) * 8;
  int row = base >> 10, h = (base & 1023) >> 6;
  float2 a = mlb[row * 16 + h];
  float2 b = mlb[4096 * 16 + row * 16 + h];
  float m = fmaxf(a.x, b.x);
  float w0 = EXP2(a.x - m) * a.y, w1 = EXP2(b.x - m) * b.y;
  float inv = 1.0f / (w0 + w1);
  w0 *= inv; w1 *= inv;
  u16x8 p0 = *(const u16x8*)(po + base);
  u16x8 p1 = *(const u16x8*)(po + 4096 * 1024 + base);
  u16x8 o;
#pragma unroll
  for (int j = 0; j < 8; ++j) o[j] = f2bf(w0 * bf2f(p0[j]) + w1 * bf2f(p1[j]));
  *(u16x8*)(atn + base) = o;
}

// -----------------------------------------------------------------------------
extern "C" void kernel_launch(void* const* d_in, const int* in_sizes, int n_in,
                              void* d_out, int out_size, void* d_ws,
                              size_t ws_size, hipStream_t stream) {
  const float* x = (const float*)d_in[0];
  const float* wq = (const float*)d_in[1];
  const float* wk = (const float*)d_in[2];
  const float* wv = (const float*)d_in[3];
  const float* wo = (const float*)d_in[4];

  // workspace layout (bf16), ~48 MB total
  u16* xb = (u16*)d_ws;                      // [4096][1024]  (dead after QKV GEMM)
  u16* wqkv = xb + 4096 * 1024;              // [3072][1024] (dead after QKV GEMM)
  u16* wob = wqkv + 3072 * 1024;             // [1024][1024]
  u16* qkv = wob + 1024 * 1024;              // [4096][3072]
  u16* atn = qkv + (size_t)4096 * 3072;      // [4096][1024]
  u16* vt = xb;                              // [1024][4096] V^T, reuses xb
  float2* mlb = (float2*)wqkv;               // 2 x [4096][16] (m,l), reuses wqkv
  u16* pout = (u16*)d_out;                   // 2 x [4096][1024] bf16 partials
                                             // (d_out is scratch until wo-GEMM)

  cast_kernel<<<2048, 256, 0, stream>>>(x, xb, 4096 * 1024);
  cast4_kernel<<<2048, 256, 0, stream>>>(wq, wk, wv, wo, wqkv);

  // QKV projection: [4096][3072] = x_bf16 * wqkv^T (counted-vmcnt 8-phase)
  gemm8k<<<dim3(12, 16), 512, 0, stream>>>(xb, wqkv, qkv, 4096, 3072, 1024, 1);
  // V transpose (xb no longer needed -> vt aliases it)
  vtrans_kernel<<<dim3(64, 16), 256, 0, stream>>>(qkv, vt);
  // causal flash attention, kv-split halves (512 uniform blocks, 2/CU)
  attn_kernel<<<dim3(16, 16, 2), 512, 0, stream>>>(qkv, vt, pout, mlb);
  // merge partials -> atn
  merge_kernel<<<2048, 256, 0, stream>>>(pout, mlb, atn);
  // output projection: fp32 out = attn_bf16 * wo^T
  gemm_bt<float><<<dim3(8, 32), 256, 0, stream>>>(atn, wob, (float*)d_out, 4096,
                                                  1024, 1024);
}

// Round 8
// 216.616 us; speedup vs baseline: 2.0106x; 1.0149x over previous
//
#include <hip/hip_runtime.h>
#include <hip/hip_bf16.h>
#include <stdint.h>

typedef unsigned short u16;
typedef float f32x4 __attribute__((ext_vector_type(4)));
typedef __bf16 bf16x8 __attribute__((ext_vector_type(8)));
typedef u16 u16x8 __attribute__((ext_vector_type(8)));

// async global->LDS, 16B per lane. LDS dest must be wave-uniform base + lane*16.
#define GL2LDS16(g, l)                                                          \
  __builtin_amdgcn_global_load_lds(                                             \
      (const __attribute__((address_space(1))) unsigned int*)(g),               \
      (__attribute__((address_space(3))) unsigned int*)(l), 16, 0, 0)

#if __has_builtin(__builtin_amdgcn_exp2f)
#define EXP2(x) __builtin_amdgcn_exp2f(x)
#else
#define EXP2(x) exp2f(x)
#endif

#define SOFTMAX_SC 0.18033688f  // 0.125 * log2(e)

__device__ __forceinline__ u16 f2bf(float f) {
  uint32_t u = __builtin_bit_cast(uint32_t, f);
  return (u16)((u + 0x7FFFu + ((u >> 16) & 1u)) >> 16);  // RNE, no NaN inputs
}

__device__ __forceinline__ float bf2f(u16 b) {
  return __builtin_bit_cast(float, (uint32_t)b << 16);
}

__device__ __forceinline__ uint32_t cvt_pk_bf16(float lo, float hi) {
  uint32_t r;
  asm("v_cvt_pk_bf16_f32 %0, %1, %2" : "=v"(r) : "v"(lo), "v"(hi));
  return r;
}

// ---------------- fp32 -> bf16 casts (x + 4 weights, one launch) -------------
__device__ __forceinline__ void cast8(const float* __restrict__ s,
                                      u16* __restrict__ d) {
  const float4* p = (const float4*)s;
  float4 a = p[0], b = p[1];
  uint4 o;
  o.x = cvt_pk_bf16(a.x, a.y);
  o.y = cvt_pk_bf16(a.z, a.w);
  o.z = cvt_pk_bf16(b.x, b.y);
  o.w = cvt_pk_bf16(b.z, b.w);
  *(uint4*)d = o;
}

__global__ __launch_bounds__(256) void castall_kernel(
    const float* __restrict__ x, const float* __restrict__ wq,
    const float* __restrict__ wk, const float* __restrict__ wv,
    const float* __restrict__ wo, u16* __restrict__ xb,
    u16* __restrict__ wqkv) {
  int b = blockIdx.x;
  if (b < 2048) {
    int i = (b * 256 + threadIdx.x) * 8;
    cast8(x + i, xb + i);
  } else {
    b -= 2048;
    int w = b >> 9;
    int i = ((b & 511) * 256 + threadIdx.x) * 8;
    const float* s = (w == 0) ? wq : (w == 1) ? wk : (w == 2) ? wv : wo;
    cast8(s + i, wqkv + ((size_t)w << 20) + i);
  }
}

// ---------------- 16-MFMA phase cluster (compile-time m-base) ----------------
template <int MB>
__device__ __forceinline__ void mfma16(f32x4 (&acc)[8][4], const bf16x8 (&af)[4],
                                       const bf16x8 (&bfr)[4]) {
  asm volatile("s_waitcnt lgkmcnt(0)" ::: "memory");
  __builtin_amdgcn_sched_barrier(0);
  __builtin_amdgcn_s_setprio(1);
#pragma unroll
  for (int j = 0; j < 4; ++j)
#pragma unroll
    for (int n = 0; n < 4; ++n)
      acc[MB + j][n] = __builtin_amdgcn_mfma_f32_16x16x32_bf16(
          af[j], bfr[n], acc[MB + j][n], 0, 0, 0);
  __builtin_amdgcn_s_setprio(0);
}

// ---------------- 8-phase 256x256 QKV GEMM with COUNTED vmcnt ----------------
// C = A * B^T (M=4096, N=3072, K=1024). Planar output: cols<1024 -> qb (scaled
// by SOFTMAX_SC), cols 1024..2047 -> kb, cols>=2048 -> vt TRANSPOSED
// ([1024][4096], lane's 4 acc rows contiguous -> one 8B store per fragment).
__global__ __launch_bounds__(512, 2) void gemm8k(const u16* __restrict__ A,
                                                 const u16* __restrict__ B,
                                                 u16* __restrict__ qb,
                                                 u16* __restrict__ kb,
                                                 u16* __restrict__ vt) {
  const int K = 1024;
  __shared__ u16 As[4][128 * 64];
  __shared__ u16 Bs[4][128 * 64];
  const int tid = threadIdx.x;
  const int lane = tid & 63;
  const int l15 = lane & 15, lhi = lane >> 4;
  const int wave = tid >> 6;
  const int wm = wave >> 2, wn = wave & 3;
  // XCD-aware bijective swizzle (nwg = 192, % 8 == 0)
  int bid = blockIdx.y * gridDim.x + blockIdx.x;
  const int cpx = (gridDim.x * gridDim.y) >> 3;
  bid = (bid & 7) * cpx + (bid >> 3);
  const int m0 = (bid / gridDim.x) * 256, n0 = (bid % gridDim.x) * 256;
  const int nt = K >> 6;  // 16 K-tiles of 64

  int aoff[2][8], boff[2][4];
#pragma unroll
  for (int ks = 0; ks < 2; ++ks) {
    const int sl = ((ks * 4 + lhi) ^ (l15 & 7)) << 4;
#pragma unroll
    for (int m = 0; m < 8; ++m) aoff[ks][m] = (m * 16 + l15) * 128 + sl;
#pragma unroll
    for (int n = 0; n < 4; ++n)
      boff[ks][n] = ((wn & 1) * 64 + n * 16 + l15) * 128 + sl;
  }

  auto stA = [&](int T, int h) {
    u16* lb = As[(T & 1) * 2 + h];
#pragma unroll
    for (int i = 0; i < 2; ++i) {
      int c = tid + i * 512;
      int row = c >> 3;
      int scol = ((c & 7) ^ (row & 7)) * 8;
      GL2LDS16(A + (size_t)(m0 + h * 128 + row) * K + T * 64 + scol,
               (char*)lb + c * 16);
    }
  };
  auto stB = [&](int T, int h) {
    u16* lb = Bs[(T & 1) * 2 + h];
#pragma unroll
    for (int i = 0; i < 2; ++i) {
      int c = tid + i * 512;
      int row = c >> 3;
      int scol = ((c & 7) ^ (row & 7)) * 8;
      GL2LDS16(B + (size_t)(n0 + h * 128 + row) * K + T * 64 + scol,
               (char*)lb + c * 16);
    }
  };

  f32x4 acc[8][4] = {};

  stA(0, 0); stA(0, 1); stB(0, 0); stB(0, 1);
  asm volatile("s_waitcnt vmcnt(0)" ::: "memory");
  __builtin_amdgcn_s_barrier();

  for (int i = 0; i < nt / 2; ++i) {
    const int e = 2 * i, o = e + 1;
    const char* Ae = (const char*)As[wm];
    const char* Be = (const char*)Bs[wn >> 1];
    const char* Ao = (const char*)As[2 + wm];
    const char* Bo = (const char*)Bs[2 + (wn >> 1)];
    bf16x8 af[4], bfr[4];
    const bool pre = (e + 2) < nt;

    // p1: stage A-odds; wait evens landed (odds fly); MFMA e ks0 mh0
    stA(o, 0); stA(o, 1);
    asm volatile("s_waitcnt vmcnt(4)" ::: "memory");
    __builtin_amdgcn_s_barrier();
#pragma unroll
    for (int j = 0; j < 4; ++j) af[j] = *(const bf16x8*)(Ae + aoff[0][j]);
#pragma unroll
    for (int n = 0; n < 4; ++n) bfr[n] = *(const bf16x8*)(Be + boff[0][n]);
    mfma16<0>(acc, af, bfr);
    __builtin_amdgcn_s_barrier();
    // p2: MFMA e ks0 mh1; stage B-odds
#pragma unroll
    for (int j = 0; j < 4; ++j) af[j] = *(const bf16x8*)(Ae + aoff[0][4 + j]);
    stB(o, 0); stB(o, 1);
    __builtin_amdgcn_s_barrier();
    mfma16<4>(acc, af, bfr);
    __builtin_amdgcn_s_barrier();
    // p3: MFMA e ks1 mh0
#pragma unroll
    for (int j = 0; j < 4; ++j) af[j] = *(const bf16x8*)(Ae + aoff[1][j]);
#pragma unroll
    for (int n = 0; n < 4; ++n) bfr[n] = *(const bf16x8*)(Be + boff[1][n]);
    __builtin_amdgcn_s_barrier();
    mfma16<0>(acc, af, bfr);
    __builtin_amdgcn_s_barrier();
    // p4: MFMA e ks1 mh1
#pragma unroll
    for (int j = 0; j < 4; ++j) af[j] = *(const bf16x8*)(Ae + aoff[1][4 + j]);
    __builtin_amdgcn_s_barrier();
    mfma16<4>(acc, af, bfr);
    __builtin_amdgcn_s_barrier();
    // p5: stage A-evens(t+2); wait odds landed; MFMA o ks0 mh0
    if (pre) {
      stA(e + 2, 0); stA(e + 2, 1);
      asm volatile("s_waitcnt vmcnt(4)" ::: "memory");
    } else {
      asm volatile("s_waitcnt vmcnt(0)" ::: "memory");
    }
    __builtin_amdgcn_s_barrier();
#pragma unroll
    for (int j = 0; j < 4; ++j) af[j] = *(const bf16x8*)(Ao + aoff[0][j]);
#pragma unroll
    for (int n = 0; n < 4; ++n) bfr[n] = *(const bf16x8*)(Bo + boff[0][n]);
    mfma16<0>(acc, af, bfr);
    __builtin_amdgcn_s_barrier();
    // p6: MFMA o ks0 mh1; stage B-evens(t+2)
#pragma unroll
    for (int j = 0; j < 4; ++j) af[j] = *(const bf16x8*)(Ao + aoff[0][4 + j]);
    if (pre) { stB(e + 2, 0); stB(e + 2, 1); }
    __builtin_amdgcn_s_barrier();
    mfma16<4>(acc, af, bfr);
    __builtin_amdgcn_s_barrier();
    // p7: MFMA o ks1 mh0
#pragma unroll
    for (int j = 0; j < 4; ++j) af[j] = *(const bf16x8*)(Ao + aoff[1][j]);
#pragma unroll
    for (int n = 0; n < 4; ++n) bfr[n] = *(const bf16x8*)(Bo + boff[1][n]);
    __builtin_amdgcn_s_barrier();
    mfma16<0>(acc, af, bfr);
    __builtin_amdgcn_s_barrier();
    // p8: MFMA o ks1 mh1
#pragma unroll
    for (int j = 0; j < 4; ++j) af[j] = *(const bf16x8*)(Ao + aoff[1][4 + j]);
    __builtin_amdgcn_s_barrier();
    mfma16<4>(acc, af, bfr);
    __builtin_amdgcn_s_barrier();
  }

  // planar epilogue
#pragma unroll
  for (int m = 0; m < 8; ++m) {
    int rbase = m0 + wm * 128 + m * 16 + lhi * 4;
#pragma unroll
    for (int n = 0; n < 4; ++n) {
      int col = n0 + wn * 64 + n * 16 + l15;
      if (col >= 2048) {  // V: write transposed into vt[1024][4096]
        uint2 pk;
        pk.x = cvt_pk_bf16(acc[m][n][0], acc[m][n][1]);
        pk.y = cvt_pk_bf16(acc[m][n][2], acc[m][n][3]);
        *(uint2*)(vt + (size_t)(col - 2048) * 4096 + rbase) = pk;
      } else {
        u16* dst = (col < 1024) ? qb : kb;
        int cc = col & 1023;
        float sc = (col < 1024) ? SOFTMAX_SC : 1.0f;
#pragma unroll
        for (int r = 0; r < 4; ++r)
          dst[(size_t)(rbase + r) * 1024 + cc] = f2bf(acc[m][n][r] * sc);
      }
    }
  }
}

// ---------------- 2-phase counted-dbuf 128x128 GEMM, fp32 out (wo proj) ----
__global__ __launch_bounds__(256) void gemm2p(const u16* __restrict__ A,
                                              const u16* __restrict__ B,
                                              float* __restrict__ C, int M,
                                              int N, int K) {
  __shared__ u16 As[2][128 * 64];
  __shared__ u16 Bs[2][128 * 64];
  const int tid = threadIdx.x;
  const int lane = tid & 63;
  const int l15 = lane & 15, lhi = lane >> 4;
  const int wave = tid >> 6;
  const int wr = (wave >> 1) * 64, wc = (wave & 1) * 64;
  const int m0 = blockIdx.y * 128, n0 = blockIdx.x * 128;
  const int nt = K >> 6;

  int aoff[2][4], boff[2][4];
#pragma unroll
  for (int ks = 0; ks < 2; ++ks) {
    const int sl = ((ks * 4 + lhi) ^ (l15 & 7)) << 4;
#pragma unroll
    for (int mi = 0; mi < 4; ++mi)
      aoff[ks][mi] = (wr + mi * 16 + l15) * 128 + sl;
#pragma unroll
    for (int ni = 0; ni < 4; ++ni)
      boff[ks][ni] = (wc + ni * 16 + l15) * 128 + sl;
  }

  auto stage = [&](int b, int t) {
#pragma unroll
    for (int i = 0; i < 4; ++i) {
      int c = tid + i * 256;
      int row = c >> 3;
      int scol = ((c & 7) ^ (row & 7)) * 8;
      GL2LDS16(A + (size_t)(m0 + row) * K + t * 64 + scol,
               (char*)(As[b]) + c * 16);
      GL2LDS16(B + (size_t)(n0 + row) * K + t * 64 + scol,
               (char*)(Bs[b]) + c * 16);
    }
  };

  f32x4 acc[4][4] = {};

  stage(0, 0);
  asm volatile("s_waitcnt vmcnt(0)" ::: "memory");
  __builtin_amdgcn_s_barrier();

  int cur = 0;
  for (int t = 0; t < nt; ++t) {
    if (t + 1 < nt) stage(cur ^ 1, t + 1);
    const char* Ab = (const char*)(As[cur]);
    const char* Bb = (const char*)(Bs[cur]);
#pragma unroll
    for (int ks = 0; ks < 2; ++ks) {
      bf16x8 af[4], bfr[4];
#pragma unroll
      for (int mi = 0; mi < 4; ++mi)
        af[mi] = *(const bf16x8*)(Ab + aoff[ks][mi]);
#pragma unroll
      for (int ni = 0; ni < 4; ++ni)
        bfr[ni] = *(const bf16x8*)(Bb + boff[ks][ni]);
#pragma unroll
      for (int mi = 0; mi < 4; ++mi)
#pragma unroll
        for (int ni = 0; ni < 4; ++ni)
          acc[mi][ni] = __builtin_amdgcn_mfma_f32_16x16x32_bf16(
              af[mi], bfr[ni], acc[mi][ni], 0, 0, 0);
    }
    asm volatile("s_waitcnt vmcnt(0)" ::: "memory");
    __builtin_amdgcn_s_barrier();
    cur ^= 1;
  }

#pragma unroll
  for (int mi = 0; mi < 4; ++mi) {
    int rbase = m0 + wr + mi * 16 + lhi * 4;
#pragma unroll
    for (int ni = 0; ni < 4; ++ni) {
      int col = n0 + wc + ni * 16 + l15;
#pragma unroll
      for (int r = 0; r < 4; ++r)
        C[(size_t)(rbase + r) * N + col] = acc[mi][ni][r];
    }
  }
}

// ---------------- causal flash attention (3-way kv-split) --------------------
// 8 waves / 128 q-rows. Swapped-QK^T: lane owns ONE q-row (= l15) x 16 kv.
// Q pre-scaled in gemm8k. Paired supertiles (bx, 31-bx). blockIdx.z = third:
// kv tiles [z*T/3, (z+1)*T/3) per supertile -> 768 blocks = 3/CU (LDS 48KB).
// Writes normalized partial O (bf16) + per-row (m,l) for the merge kernel.
__global__ __launch_bounds__(512) void attn_kernel(
    const u16* __restrict__ qb, const u16* __restrict__ kbuf,
    const u16* __restrict__ vt, u16* __restrict__ p0, u16* __restrict__ p12,
    float2* __restrict__ mlb) {
  const int h = blockIdx.y;
  const int bx = blockIdx.x;   // 0..15
  const int z = blockIdx.z;    // 0..2
  const int tid = threadIdx.x;
  const int lane = tid & 63, wave = tid >> 6;  // wave 0..7
  const int l15 = lane & 15, lhi = lane >> 4;

  u16* po = (z == 0) ? p0 : p12 + (size_t)(z - 1) * 4096 * 1024;
  float2* ml = mlb + (size_t)z * 4096 * 16;

  __shared__ u16 Ks[2][64 * 64];
  __shared__ u16 Vs[2][64 * 64];
  __shared__ u16 Ps[8][16 * 64];
  u16* Pw = Ps[wave];

  int koff[2][4];  // [ks][nf]: row = nf*16+l15, 16B col = lhi*16 + ks*64
#pragma unroll
  for (int ks = 0; ks < 2; ++ks)
#pragma unroll
    for (int nf = 0; nf < 4; ++nf) {
      int row = nf * 16 + l15;
      koff[ks][nf] = row * 128 + ((lhi * 16 + ks * 64) ^ ((row & 7) << 4));
    }
  int poff[4];  // P write: row = q = l15, 8B col = nf*32 + lhi*8
#pragma unroll
  for (int nf = 0; nf < 4; ++nf)
    poff[nf] = l15 * 128 + ((nf * 32 + lhi * 8) ^ ((l15 & 7) << 4));

  auto stage = [&](int b, int kb) {
    int c = tid;  // 512 chunks = 64x64 bf16, one per thread
    int row = c >> 3, slot = c & 7;
    int scol = (slot ^ (row & 7)) * 8;  // inverse-swizzled source col
    GL2LDS16(kbuf + (size_t)(kb * 64 + row) * 1024 + h * 64 + scol,
             (char*)(Ks[b]) + c * 16);
    GL2LDS16(vt + (size_t)(h * 64 + row) * 4096 + kb * 64 + scol,
             (char*)(Vs[b]) + c * 16);
  };

  int cur = 0;
  for (int rep = 0; rep < 2; ++rep) {
    const int qsb = rep ? (31 - bx) : bx;   // 128-row q-supertile
    const int T = 2 * qsb + 2;              // causal kv tiles of 64
    const int kb0 = (z * T) / 3;
    const int kbe = ((z + 1) * T) / 3;
    const int q0 = qsb * 128 + wave * 16;

    if (kb0 >= kbe) {  // empty third: weight-0 sentinel, skip O
      if (lhi == 0) ml[(q0 + l15) * 16 + h] = float2{-1e30f, 0.f};
      continue;
    }

    const u16* Qb = qb + (size_t)(q0 + l15) * 1024 + h * 64;
    bf16x8 qf0 = *(const bf16x8*)(const void*)(Qb + lhi * 8);
    bf16x8 qf1 = *(const bf16x8*)(const void*)(Qb + 32 + lhi * 8);

    f32x4 oa[4] = {};
    float mrow = -1e30f, lrow = 0.f;  // scalars: this lane's q-row

    stage(cur, kb0);
    asm volatile("s_waitcnt vmcnt(0)" ::: "memory");
    __builtin_amdgcn_s_barrier();

    for (int kb = kb0; kb < kbe; ++kb) {
      if (kb + 1 < kbe) stage(cur ^ 1, kb + 1);

      // S^T = K Q^T: s[nf][r] = S[kv = kb*64 + nf*16+lhi*4+r][q = q0+l15]
      f32x4 s[4] = {};
#pragma unroll
      for (int ks = 0; ks < 2; ++ks)
#pragma unroll
        for (int nf = 0; nf < 4; ++nf) {
          bf16x8 kf = *(const bf16x8*)((const char*)(Ks[cur]) + koff[ks][nf]);
          s[nf] = __builtin_amdgcn_mfma_f32_16x16x32_bf16(kf, ks ? qf1 : qf0,
                                                          s[nf], 0, 0, 0);
        }

      // causal mask (wave-uniform branch; elementwise kv>q inside)
      if (kb * 64 + 63 > q0) {
        const int q = q0 + l15;
#pragma unroll
        for (int nf = 0; nf < 4; ++nf)
#pragma unroll
          for (int r = 0; r < 4; ++r)
            if (kb * 64 + nf * 16 + lhi * 4 + r > q) s[nf][r] = -1e30f;
      }

      // row max: in-lane over 16 kv + 2 shfls across lhi groups
      float pm0 = fmaxf(fmaxf(s[0][0], s[0][1]), fmaxf(s[0][2], s[0][3]));
      float pm1 = fmaxf(fmaxf(s[1][0], s[1][1]), fmaxf(s[1][2], s[1][3]));
      float pm2 = fmaxf(fmaxf(s[2][0], s[2][1]), fmaxf(s[2][2], s[2][3]));
      float pm3 = fmaxf(fmaxf(s[3][0], s[3][1]), fmaxf(s[3][2], s[3][3]));
      float pm = fmaxf(fmaxf(pm0, pm1), fmaxf(pm2, pm3));
      pm = fmaxf(pm, __shfl_xor(pm, 16));
      pm = fmaxf(pm, __shfl_xor(pm, 32));

      // defer-max: rescale only when running max grew by > 8 (2^8 headroom)
      if (__any(pm - mrow > 8.0f)) {
        float mn = fmaxf(mrow, pm);
        float al = EXP2(mrow - mn);
        mrow = mn;
        lrow *= al;
        float alq[4];
#pragma unroll
        for (int r = 0; r < 4; ++r) alq[r] = __shfl(al, lhi * 4 + r, 16);
#pragma unroll
        for (int nf = 0; nf < 4; ++nf)
#pragma unroll
          for (int r = 0; r < 4; ++r) oa[nf][r] *= alq[r];
      }

      // P = exp2(S - m); row sum in-lane + 2 shfls
#pragma unroll
      for (int nf = 0; nf < 4; ++nf)
#pragma unroll
        for (int r = 0; r < 4; ++r) s[nf][r] = EXP2(s[nf][r] - mrow);
      float rs = ((s[0][0] + s[0][1]) + (s[0][2] + s[0][3])) +
                 ((s[1][0] + s[1][1]) + (s[1][2] + s[1][3])) +
                 ((s[2][0] + s[2][1]) + (s[2][2] + s[2][3])) +
                 ((s[3][0] + s[3][1]) + (s[3][2] + s[3][3]));
      rs += __shfl_xor(rs, 16);
      rs += __shfl_xor(rs, 32);
      lrow += rs;

      // P -> LDS: lane's 4 kv values contiguous -> one b64 write per frag
#pragma unroll
      for (int nf = 0; nf < 4; ++nf) {
        uint2 pk;
        pk.x = cvt_pk_bf16(s[nf][0], s[nf][1]);
        pk.y = cvt_pk_bf16(s[nf][2], s[nf][3]);
        *(uint2*)((char*)Pw + poff[nf]) = pk;
      }

      // P A-fragments (row = q = l15, contiguous kv)
      bf16x8 pf[2];
#pragma unroll
      for (int ks = 0; ks < 2; ++ks)
        pf[ks] = *(const bf16x8*)((const char*)Pw + koff[ks][0]);

      // O += P * V  (B-frag from V^T tile: row = d, contiguous along kv)
#pragma unroll
      for (int ks = 0; ks < 2; ++ks)
#pragma unroll
        for (int nf = 0; nf < 4; ++nf) {
          bf16x8 vf = *(const bf16x8*)((const char*)(Vs[cur]) + koff[ks][nf]);
          oa[nf] = __builtin_amdgcn_mfma_f32_16x16x32_bf16(pf[ks], vf, oa[nf],
                                                           0, 0, 0);
        }

      asm volatile("s_waitcnt vmcnt(0)" ::: "memory");
      __builtin_amdgcn_s_barrier();
      cur ^= 1;
    }

    // epilogue: normalized partial O -> bf16; (m,l) per q-row for merge
    float linv[4];
#pragma unroll
    for (int r = 0; r < 4; ++r) {
      float lr = __shfl(lrow, lhi * 4 + r, 16);
      linv[r] = (lr > 0.f) ? 1.0f / lr : 0.f;
    }
#pragma unroll
    for (int r = 0; r < 4; ++r) {
      int rowg = q0 + lhi * 4 + r;
#pragma unroll
      for (int nf = 0; nf < 4; ++nf)
        po[(size_t)rowg * 1024 + h * 64 + nf * 16 + l15] =
            f2bf(oa[nf][r] * linv[r]);
    }
    if (lhi == 0) ml[(q0 + l15) * 16 + h] = float2{mrow, lrow};
  }
}

// ---------------- merge the three kv-third partials (p0 in-place) ------------
__global__ __launch_bounds__(256) void merge_kernel(u16* __restrict__ p0,
                                                    const u16* __restrict__ p12,
                                                    const float2* __restrict__ mlb,
                                                    int dummy) {
  int base = (blockIdx.x * 256 + threadIdx.x) * 8;
  int row = base >> 10, h = (base & 1023) >> 6;
  float2 a = mlb[row * 16 + h];
  float2 b = mlb[4096 * 16 + row * 16 + h];
  float2 c = mlb[2 * 4096 * 16 + row * 16 + h];
  float m = fmaxf(fmaxf(a.x, b.x), c.x);
  float w0 = EXP2(a.x - m) * a.y;
  float w1 = EXP2(b.x - m) * b.y;
  float w2 = EXP2(c.x - m) * c.y;
  float inv = 1.0f / (w0 + w1 + w2);
  w0 *= inv; w1 *= inv; w2 *= inv;
  u16x8 q0 = *(const u16x8*)(p0 + base);
  u16x8 q1 = *(const u16x8*)(p12 + base);
  u16x8 q2 = *(const u16x8*)(p12 + 4096 * 1024 + base);
  u16x8 o;
#pragma unroll
  for (int j = 0; j < 8; ++j)
    o[j] = f2bf(w0 * bf2f(q0[j]) + w1 * bf2f(q1[j]) + w2 * bf2f(q2[j]));
  *(u16x8*)(p0 + base) = o;
}

// -----------------------------------------------------------------------------
extern "C" void kernel_launch(void* const* d_in, const int* in_sizes, int n_in,
                              void* d_out, int out_size, void* d_ws,
                              size_t ws_size, hipStream_t stream) {
  const float* x = (const float*)d_in[0];
  const float* wq = (const float*)d_in[1];
  const float* wk = (const float*)d_in[2];
  const float* wv = (const float*)d_in[3];
  const float* wo = (const float*)d_in[4];

  // workspace layout (bf16 elements), ~50 MB
  u16* xb = (u16*)d_ws;                      // [4096][1024]
  u16* wqkv = xb + 4096 * 1024;              // [3072][1024] (dead after gemm8k)
  u16* wob = wqkv + 3072 * 1024;             // [1024][1024]
  u16* qb = wob + 1024 * 1024;               // [4096][1024] Q (pre-scaled)
  u16* kbuf = qb + 4096 * 1024;              // [4096][1024] K
  u16* vt = kbuf + 4096 * 1024;              // [1024][4096] V^T (planar)
  u16* atn = vt + 4096 * 1024;               // [4096][1024] merged attn out
  float2* mlb = (float2*)wqkv;               // 3 x [4096][16] (m,l)
  u16* p12 = (u16*)d_out;                    // partials z=1,2 (d_out scratch)

  castall_kernel<<<4096, 256, 0, stream>>>(x, wq, wk, wv, wo, xb, wqkv);

  // QKV projection -> planar Q | K | V^T (V transposed in epilogue)
  gemm8k<<<dim3(12, 16), 512, 0, stream>>>(xb, wqkv, qb, kbuf, vt);
  // causal flash attention, 3-way kv-split (768 blocks = 3/CU)
  attn_kernel<<<dim3(16, 16, 3), 512, 0, stream>>>(qb, kbuf, vt, atn, p12, mlb);
  // merge partials (in-place into atn)
  merge_kernel<<<2048, 256, 0, stream>>>(atn, p12, mlb, 0);
  // output projection: fp32 out = attn_bf16 * wo^T (2-phase counted dbuf)
  gemm2p<<<dim3(8, 32), 256, 0, stream>>>(atn, wob, (float*)d_out, 4096, 1024,
                                          1024);
}

// Round 9
// 207.916 us; speedup vs baseline: 2.0947x; 1.0418x over previous
//
#include <hip/hip_runtime.h>
#include <hip/hip_bf16.h>
#include <stdint.h>

typedef unsigned short u16;
typedef float f32x4 __attribute__((ext_vector_type(4)));
typedef __bf16 bf16x8 __attribute__((ext_vector_type(8)));
typedef u16 u16x8 __attribute__((ext_vector_type(8)));

// async global->LDS, 16B per lane. LDS dest must be wave-uniform base + lane*16.
#define GL2LDS16(g, l)                                                          \
  __builtin_amdgcn_global_load_lds(                                             \
      (const __attribute__((address_space(1))) unsigned int*)(g),               \
      (__attribute__((address_space(3))) unsigned int*)(l), 16, 0, 0)

#if __has_builtin(__builtin_amdgcn_exp2f)
#define EXP2(x) __builtin_amdgcn_exp2f(x)
#else
#define EXP2(x) exp2f(x)
#endif

#define SOFTMAX_SC 0.18033688f  // 0.125 * log2(e)

__device__ __forceinline__ u16 f2bf(float f) {
  uint32_t u = __builtin_bit_cast(uint32_t, f);
  return (u16)((u + 0x7FFFu + ((u >> 16) & 1u)) >> 16);  // RNE, no NaN inputs
}

__device__ __forceinline__ float bf2f(u16 b) {
  return __builtin_bit_cast(float, (uint32_t)b << 16);
}

__device__ __forceinline__ uint32_t cvt_pk_bf16(float lo, float hi) {
  uint32_t r;
  asm("v_cvt_pk_bf16_f32 %0, %1, %2" : "=v"(r) : "v"(lo), "v"(hi));
  return r;
}

// ---------------- fp32 -> bf16 casts (x + 4 weights, one launch) -------------
__device__ __forceinline__ void cast8(const float* __restrict__ s,
                                      u16* __restrict__ d) {
  const float4* p = (const float4*)s;
  float4 a = p[0], b = p[1];
  uint4 o;
  o.x = cvt_pk_bf16(a.x, a.y);
  o.y = cvt_pk_bf16(a.z, a.w);
  o.z = cvt_pk_bf16(b.x, b.y);
  o.w = cvt_pk_bf16(b.z, b.w);
  *(uint4*)d = o;
}

__global__ __launch_bounds__(256) void castall_kernel(
    const float* __restrict__ x, const float* __restrict__ wq,
    const float* __restrict__ wk, const float* __restrict__ wv,
    const float* __restrict__ wo, u16* __restrict__ xb,
    u16* __restrict__ wqkv) {
  int b = blockIdx.x;
  if (b < 2048) {
    int i = (b * 256 + threadIdx.x) * 8;
    cast8(x + i, xb + i);
  } else {
    b -= 2048;
    int w = b >> 9;
    int i = ((b & 511) * 256 + threadIdx.x) * 8;
    const float* s = (w == 0) ? wq : (w == 1) ? wk : (w == 2) ? wv : wo;
    cast8(s + i, wqkv + ((size_t)w << 20) + i);
  }
}

// ---------------- 16-MFMA phase cluster (compile-time m-base) ----------------
template <int MB>
__device__ __forceinline__ void mfma16(f32x4 (&acc)[8][4], const bf16x8 (&af)[4],
                                       const bf16x8 (&bfr)[4]) {
  asm volatile("s_waitcnt lgkmcnt(0)" ::: "memory");
  __builtin_amdgcn_sched_barrier(0);
  __builtin_amdgcn_s_setprio(1);
#pragma unroll
  for (int j = 0; j < 4; ++j)
#pragma unroll
    for (int n = 0; n < 4; ++n)
      acc[MB + j][n] = __builtin_amdgcn_mfma_f32_16x16x32_bf16(
          af[j], bfr[n], acc[MB + j][n], 0, 0, 0);
  __builtin_amdgcn_s_setprio(0);
}

// ---------------- 8-phase 256x256 QKV GEMM with COUNTED vmcnt ----------------
// C = A * B^T (M=4096, N=3072, K=1024). Planar output: cols<1024 -> qb (scaled
// by SOFTMAX_SC), cols 1024..2047 -> kb, cols>=2048 -> vt TRANSPOSED.
__global__ __launch_bounds__(512, 2) void gemm8k(const u16* __restrict__ A,
                                                 const u16* __restrict__ B,
                                                 u16* __restrict__ qb,
                                                 u16* __restrict__ kb,
                                                 u16* __restrict__ vt) {
  const int K = 1024;
  __shared__ u16 As[4][128 * 64];
  __shared__ u16 Bs[4][128 * 64];
  const int tid = threadIdx.x;
  const int lane = tid & 63;
  const int l15 = lane & 15, lhi = lane >> 4;
  const int wave = tid >> 6;
  const int wm = wave >> 2, wn = wave & 3;
  int bid = blockIdx.y * gridDim.x + blockIdx.x;
  const int cpx = (gridDim.x * gridDim.y) >> 3;
  bid = (bid & 7) * cpx + (bid >> 3);
  const int m0 = (bid / gridDim.x) * 256, n0 = (bid % gridDim.x) * 256;
  const int nt = K >> 6;  // 16 K-tiles of 64

  int aoff[2][8], boff[2][4];
#pragma unroll
  for (int ks = 0; ks < 2; ++ks) {
    const int sl = ((ks * 4 + lhi) ^ (l15 & 7)) << 4;
#pragma unroll
    for (int m = 0; m < 8; ++m) aoff[ks][m] = (m * 16 + l15) * 128 + sl;
#pragma unroll
    for (int n = 0; n < 4; ++n)
      boff[ks][n] = ((wn & 1) * 64 + n * 16 + l15) * 128 + sl;
  }

  auto stA = [&](int T, int h) {
    u16* lb = As[(T & 1) * 2 + h];
#pragma unroll
    for (int i = 0; i < 2; ++i) {
      int c = tid + i * 512;
      int row = c >> 3;
      int scol = ((c & 7) ^ (row & 7)) * 8;
      GL2LDS16(A + (size_t)(m0 + h * 128 + row) * K + T * 64 + scol,
               (char*)lb + c * 16);
    }
  };
  auto stB = [&](int T, int h) {
    u16* lb = Bs[(T & 1) * 2 + h];
#pragma unroll
    for (int i = 0; i < 2; ++i) {
      int c = tid + i * 512;
      int row = c >> 3;
      int scol = ((c & 7) ^ (row & 7)) * 8;
      GL2LDS16(B + (size_t)(n0 + h * 128 + row) * K + T * 64 + scol,
               (char*)lb + c * 16);
    }
  };

  f32x4 acc[8][4] = {};

  stA(0, 0); stA(0, 1); stB(0, 0); stB(0, 1);
  asm volatile("s_waitcnt vmcnt(0)" ::: "memory");
  __builtin_amdgcn_s_barrier();

  for (int i = 0; i < nt / 2; ++i) {
    const int e = 2 * i, o = e + 1;
    const char* Ae = (const char*)As[wm];
    const char* Be = (const char*)Bs[wn >> 1];
    const char* Ao = (const char*)As[2 + wm];
    const char* Bo = (const char*)Bs[2 + (wn >> 1)];
    bf16x8 af[4], bfr[4];
    const bool pre = (e + 2) < nt;

    // p1: stage A-odds; wait evens landed (odds fly); MFMA e ks0 mh0
    stA(o, 0); stA(o, 1);
    asm volatile("s_waitcnt vmcnt(4)" ::: "memory");
    __builtin_amdgcn_s_barrier();
#pragma unroll
    for (int j = 0; j < 4; ++j) af[j] = *(const bf16x8*)(Ae + aoff[0][j]);
#pragma unroll
    for (int n = 0; n < 4; ++n) bfr[n] = *(const bf16x8*)(Be + boff[0][n]);
    mfma16<0>(acc, af, bfr);
    __builtin_amdgcn_s_barrier();
    // p2: MFMA e ks0 mh1; stage B-odds
#pragma unroll
    for (int j = 0; j < 4; ++j) af[j] = *(const bf16x8*)(Ae + aoff[0][4 + j]);
    stB(o, 0); stB(o, 1);
    __builtin_amdgcn_s_barrier();
    mfma16<4>(acc, af, bfr);
    __builtin_amdgcn_s_barrier();
    // p3: MFMA e ks1 mh0
#pragma unroll
    for (int j = 0; j < 4; ++j) af[j] = *(const bf16x8*)(Ae + aoff[1][j]);
#pragma unroll
    for (int n = 0; n < 4; ++n) bfr[n] = *(const bf16x8*)(Be + boff[1][n]);
    __builtin_amdgcn_s_barrier();
    mfma16<0>(acc, af, bfr);
    __builtin_amdgcn_s_barrier();
    // p4: MFMA e ks1 mh1
#pragma unroll
    for (int j = 0; j < 4; ++j) af[j] = *(const bf16x8*)(Ae + aoff[1][4 + j]);
    __builtin_amdgcn_s_barrier();
    mfma16<4>(acc, af, bfr);
    __builtin_amdgcn_s_barrier();
    // p5: stage A-evens(t+2); wait odds landed; MFMA o ks0 mh0
    if (pre) {
      stA(e + 2, 0); stA(e + 2, 1);
      asm volatile("s_waitcnt vmcnt(4)" ::: "memory");
    } else {
      asm volatile("s_waitcnt vmcnt(0)" ::: "memory");
    }
    __builtin_amdgcn_s_barrier();
#pragma unroll
    for (int j = 0; j < 4; ++j) af[j] = *(const bf16x8*)(Ao + aoff[0][j]);
#pragma unroll
    for (int n = 0; n < 4; ++n) bfr[n] = *(const bf16x8*)(Bo + boff[0][n]);
    mfma16<0>(acc, af, bfr);
    __builtin_amdgcn_s_barrier();
    // p6: MFMA o ks0 mh1; stage B-evens(t+2)
#pragma unroll
    for (int j = 0; j < 4; ++j) af[j] = *(const bf16x8*)(Ao + aoff[0][4 + j]);
    if (pre) { stB(e + 2, 0); stB(e + 2, 1); }
    __builtin_amdgcn_s_barrier();
    mfma16<4>(acc, af, bfr);
    __builtin_amdgcn_s_barrier();
    // p7: MFMA o ks1 mh0
#pragma unroll
    for (int j = 0; j < 4; ++j) af[j] = *(const bf16x8*)(Ao + aoff[1][j]);
#pragma unroll
    for (int n = 0; n < 4; ++n) bfr[n] = *(const bf16x8*)(Bo + boff[1][n]);
    __builtin_amdgcn_s_barrier();
    mfma16<0>(acc, af, bfr);
    __builtin_amdgcn_s_barrier();
    // p8: MFMA o ks1 mh1
#pragma unroll
    for (int j = 0; j < 4; ++j) af[j] = *(const bf16x8*)(Ao + aoff[1][4 + j]);
    __builtin_amdgcn_s_barrier();
    mfma16<4>(acc, af, bfr);
    __builtin_amdgcn_s_barrier();
  }

  // planar epilogue
#pragma unroll
  for (int m = 0; m < 8; ++m) {
    int rbase = m0 + wm * 128 + m * 16 + lhi * 4;
#pragma unroll
    for (int n = 0; n < 4; ++n) {
      int col = n0 + wn * 64 + n * 16 + l15;
      if (col >= 2048) {  // V: write transposed into vt[1024][4096]
        uint2 pk;
        pk.x = cvt_pk_bf16(acc[m][n][0], acc[m][n][1]);
        pk.y = cvt_pk_bf16(acc[m][n][2], acc[m][n][3]);
        *(uint2*)(vt + (size_t)(col - 2048) * 4096 + rbase) = pk;
      } else {
        u16* dst = (col < 1024) ? qb : kb;
        int cc = col & 1023;
        float sc = (col < 1024) ? SOFTMAX_SC : 1.0f;
#pragma unroll
        for (int r = 0; r < 4; ++r)
          dst[(size_t)(rbase + r) * 1024 + cc] = f2bf(acc[m][n][r] * sc);
      }
    }
  }
}

// ---------------- depth-2 prefetch 128x128 GEMM, fp32 out (wo proj) ---------
// 512 thr = 8 waves (2M x 4N, 64x32 out each), BK=64, 3 LDS buffers, counted
// vmcnt(4): tile t+2 staged while waiting only for t+1 (true T4, no drain0).
__global__ __launch_bounds__(512) void gemm2p(const u16* __restrict__ A,
                                              const u16* __restrict__ B,
                                              float* __restrict__ C, int M,
                                              int N, int K) {
  __shared__ u16 As[3][128 * 64];
  __shared__ u16 Bs[3][128 * 64];
  const int tid = threadIdx.x;
  const int lane = tid & 63;
  const int l15 = lane & 15, lhi = lane >> 4;
  const int wave = tid >> 6;
  const int wm = wave >> 2, wn = wave & 3;
  int bid = blockIdx.y * gridDim.x + blockIdx.x;
  const int cpx = (gridDim.x * gridDim.y) >> 3;
  bid = (bid & 7) * cpx + (bid >> 3);
  const int m0 = (bid / gridDim.x) * 128, n0 = (bid % gridDim.x) * 128;
  const int nt = K >> 6;

  int aoff[2][4], boff[2][2];
#pragma unroll
  for (int ks = 0; ks < 2; ++ks) {
    const int sl = ((ks * 4 + lhi) ^ (l15 & 7)) << 4;
#pragma unroll
    for (int mi = 0; mi < 4; ++mi)
      aoff[ks][mi] = (wm * 64 + mi * 16 + l15) * 128 + sl;
#pragma unroll
    for (int ni = 0; ni < 2; ++ni)
      boff[ks][ni] = (wn * 32 + ni * 16 + l15) * 128 + sl;
  }

  auto stage = [&](int b, int t) {
#pragma unroll
    for (int i = 0; i < 2; ++i) {
      int c = tid + i * 512;
      int row = c >> 3;
      int scol = ((c & 7) ^ (row & 7)) * 8;
      GL2LDS16(A + (size_t)(m0 + row) * K + t * 64 + scol,
               (char*)(As[b]) + c * 16);
      GL2LDS16(B + (size_t)(n0 + row) * K + t * 64 + scol,
               (char*)(Bs[b]) + c * 16);
    }
  };

  f32x4 acc[4][2] = {};

  stage(0, 0);
  if (nt > 1) stage(1, 1);
  if (nt > 1) asm volatile("s_waitcnt vmcnt(4)" ::: "memory");
  else asm volatile("s_waitcnt vmcnt(0)" ::: "memory");
  __builtin_amdgcn_s_barrier();

  for (int t = 0; t < nt; ++t) {
    if (t + 2 < nt) stage((t + 2) % 3, t + 2);
    const char* Ab = (const char*)(As[t % 3]);
    const char* Bb = (const char*)(Bs[t % 3]);
#pragma unroll
    for (int ks = 0; ks < 2; ++ks) {
      bf16x8 af[4], bfr[2];
#pragma unroll
      for (int mi = 0; mi < 4; ++mi)
        af[mi] = *(const bf16x8*)(Ab + aoff[ks][mi]);
#pragma unroll
      for (int ni = 0; ni < 2; ++ni)
        bfr[ni] = *(const bf16x8*)(Bb + boff[ks][ni]);
      __builtin_amdgcn_s_setprio(1);
#pragma unroll
      for (int mi = 0; mi < 4; ++mi)
#pragma unroll
        for (int ni = 0; ni < 2; ++ni)
          acc[mi][ni] = __builtin_amdgcn_mfma_f32_16x16x32_bf16(
              af[mi], bfr[ni], acc[mi][ni], 0, 0, 0);
      __builtin_amdgcn_s_setprio(0);
    }
    if (t + 1 < nt) {
      if (t + 2 < nt) asm volatile("s_waitcnt vmcnt(4)" ::: "memory");
      else asm volatile("s_waitcnt vmcnt(0)" ::: "memory");
      __builtin_amdgcn_s_barrier();
    }
  }

#pragma unroll
  for (int mi = 0; mi < 4; ++mi) {
    int rbase = m0 + wm * 64 + mi * 16 + lhi * 4;
#pragma unroll
    for (int ni = 0; ni < 2; ++ni) {
      int col = n0 + wn * 32 + ni * 16 + l15;
#pragma unroll
      for (int r = 0; r < 4; ++r)
        C[(size_t)(rbase + r) * N + col] = acc[mi][ni][r];
    }
  }
}

// ---------------- causal flash attention (2-way kv-split, T15 pipeline) ------
// 8 waves / 128 q-rows. Swapped-QK^T: lane owns ONE q-row (= l15) x 16 kv.
// Q pre-scaled in gemm8k. Paired supertiles (bx, 31-bx); blockIdx.z = kv half.
// T15: softmax(t-1)+PV(t-1) overlap QK^T(t) -> 3 LDS buffers (A: Ks[c] read,
// Vs[cp] read, stage writes cn; c,cp,cn distinct mod 3).
__global__ __launch_bounds__(512) void attn_kernel(
    const u16* __restrict__ qb, const u16* __restrict__ kbuf,
    const u16* __restrict__ vt, u16* __restrict__ p0, u16* __restrict__ p1g,
    float2* __restrict__ mlb) {
  const int h = blockIdx.y;
  const int bx = blockIdx.x;    // 0..15
  const int half = blockIdx.z;  // 0..1
  const int tid = threadIdx.x;
  const int lane = tid & 63, wave = tid >> 6;  // wave 0..7
  const int l15 = lane & 15, lhi = lane >> 4;

  u16* po = half ? p1g : p0;
  float2* ml = mlb + (size_t)half * 4096 * 16;

  __shared__ u16 Ks[3][64 * 64];
  __shared__ u16 Vs[3][64 * 64];
  __shared__ u16 Ps[8][16 * 64];
  u16* Pw = Ps[wave];

  int koff[2][4];  // [ks][nf]: row = nf*16+l15, 16B col = lhi*16 + ks*64
#pragma unroll
  for (int ks = 0; ks < 2; ++ks)
#pragma unroll
    for (int nf = 0; nf < 4; ++nf) {
      int row = nf * 16 + l15;
      koff[ks][nf] = row * 128 + ((lhi * 16 + ks * 64) ^ ((row & 7) << 4));
    }
  int poff[4];  // P write: row = q = l15, 8B col = nf*32 + lhi*8
#pragma unroll
  for (int nf = 0; nf < 4; ++nf)
    poff[nf] = l15 * 128 + ((nf * 32 + lhi * 8) ^ ((l15 & 7) << 4));

  auto stage = [&](int b, int kb) {
    int c = tid;  // 512 chunks = 64x64 bf16, one per thread
    int row = c >> 3, slot = c & 7;
    int scol = (slot ^ (row & 7)) * 8;
    GL2LDS16(kbuf + (size_t)(kb * 64 + row) * 1024 + h * 64 + scol,
             (char*)(Ks[b]) + c * 16);
    GL2LDS16(vt + (size_t)(h * 64 + row) * 4096 + kb * 64 + scol,
             (char*)(Vs[b]) + c * 16);
  };

  for (int rep = 0; rep < 2; ++rep) {
    const int qsb = rep ? (31 - bx) : bx;   // 128-row q-supertile
    const int kb0 = half * (qsb + 1);       // this half's kv-tile range
    const int kbe = kb0 + qsb + 1;          // length qsb+1 >= 1
    const int q0 = qsb * 128 + wave * 16;
    const u16* Qb = qb + (size_t)(q0 + l15) * 1024 + h * 64;
    bf16x8 qf0 = *(const bf16x8*)(const void*)(Qb + lhi * 8);
    bf16x8 qf1 = *(const bf16x8*)(const void*)(Qb + 32 + lhi * 8);

    f32x4 oa[4] = {};
    float mrow = -1e30f, lrow = 0.f;
    f32x4 sp[4];

    auto qkt = [&](int buf, f32x4 (&s)[4]) {
      __builtin_amdgcn_s_setprio(1);
#pragma unroll
      for (int ks = 0; ks < 2; ++ks)
#pragma unroll
        for (int nf = 0; nf < 4; ++nf) {
          bf16x8 kf = *(const bf16x8*)((const char*)(Ks[buf]) + koff[ks][nf]);
          s[nf] = __builtin_amdgcn_mfma_f32_16x16x32_bf16(kf, ks ? qf1 : qf0,
                                                          s[nf], 0, 0, 0);
        }
      __builtin_amdgcn_s_setprio(0);
    };

    // softmax of tile t (scores in sp) + PV from Vs[vbuf]
    auto smax_pv = [&](int t, int vbuf) {
      if (t * 64 + 63 > q0) {  // causal mask (wave-uniform branch)
        const int q = q0 + l15;
#pragma unroll
        for (int nf = 0; nf < 4; ++nf)
#pragma unroll
          for (int r = 0; r < 4; ++r)
            if (t * 64 + nf * 16 + lhi * 4 + r > q) sp[nf][r] = -1e30f;
      }
      float pm0 = fmaxf(fmaxf(sp[0][0], sp[0][1]), fmaxf(sp[0][2], sp[0][3]));
      float pm1 = fmaxf(fmaxf(sp[1][0], sp[1][1]), fmaxf(sp[1][2], sp[1][3]));
      float pm2 = fmaxf(fmaxf(sp[2][0], sp[2][1]), fmaxf(sp[2][2], sp[2][3]));
      float pm3 = fmaxf(fmaxf(sp[3][0], sp[3][1]), fmaxf(sp[3][2], sp[3][3]));
      float pm = fmaxf(fmaxf(pm0, pm1), fmaxf(pm2, pm3));
      pm = fmaxf(pm, __shfl_xor(pm, 16));
      pm = fmaxf(pm, __shfl_xor(pm, 32));

      if (__any(pm - mrow > 8.0f)) {  // defer-max (2^8 headroom)
        float mn = fmaxf(mrow, pm);
        float al = EXP2(mrow - mn);
        mrow = mn;
        lrow *= al;
        float alq[4];
#pragma unroll
        for (int r = 0; r < 4; ++r) alq[r] = __shfl(al, lhi * 4 + r, 16);
#pragma unroll
        for (int nf = 0; nf < 4; ++nf)
#pragma unroll
          for (int r = 0; r < 4; ++r) oa[nf][r] *= alq[r];
      }

#pragma unroll
      for (int nf = 0; nf < 4; ++nf)
#pragma unroll
        for (int r = 0; r < 4; ++r) sp[nf][r] = EXP2(sp[nf][r] - mrow);
      float rs = ((sp[0][0] + sp[0][1]) + (sp[0][2] + sp[0][3])) +
                 ((sp[1][0] + sp[1][1]) + (sp[1][2] + sp[1][3])) +
                 ((sp[2][0] + sp[2][1]) + (sp[2][2] + sp[2][3])) +
                 ((sp[3][0] + sp[3][1]) + (sp[3][2] + sp[3][3]));
      rs += __shfl_xor(rs, 16);
      rs += __shfl_xor(rs, 32);
      lrow += rs;

#pragma unroll
      for (int nf = 0; nf < 4; ++nf) {
        uint2 pk;
        pk.x = cvt_pk_bf16(sp[nf][0], sp[nf][1]);
        pk.y = cvt_pk_bf16(sp[nf][2], sp[nf][3]);
        *(uint2*)((char*)Pw + poff[nf]) = pk;
      }
      bf16x8 pf[2];
#pragma unroll
      for (int ks = 0; ks < 2; ++ks)
        pf[ks] = *(const bf16x8*)((const char*)Pw + koff[ks][0]);

      __builtin_amdgcn_s_setprio(1);
#pragma unroll
      for (int ks = 0; ks < 2; ++ks)
#pragma unroll
        for (int nf = 0; nf < 4; ++nf) {
          bf16x8 vf = *(const bf16x8*)((const char*)(Vs[vbuf]) + koff[ks][nf]);
          oa[nf] = __builtin_amdgcn_mfma_f32_16x16x32_bf16(pf[ks], vf, oa[nf],
                                                           0, 0, 0);
        }
      __builtin_amdgcn_s_setprio(0);
    };

    // prologue: tile kb0 staged + its QK^T peeled
    stage(0, kb0);
    asm volatile("s_waitcnt vmcnt(0)" ::: "memory");
    __builtin_amdgcn_s_barrier();
    if (kb0 + 1 < kbe) stage(1, kb0 + 1);
#pragma unroll
    for (int nf = 0; nf < 4; ++nf) sp[nf] = f32x4{0.f, 0.f, 0.f, 0.f};
    qkt(0, sp);
    asm volatile("s_waitcnt vmcnt(0)" ::: "memory");
    __builtin_amdgcn_s_barrier();

    // pipelined main loop: QK^T(t) || softmax(t-1)+PV(t-1)
    for (int t = kb0 + 1; t < kbe; ++t) {
      const int c = (t - kb0) % 3;       // tile t (K read)
      const int cp = (t - kb0 + 2) % 3;  // tile t-1 (V read)
      const int cn = (t - kb0 + 1) % 3;  // tile t+1 (stage target)
      if (t + 1 < kbe) stage(cn, t + 1);
      f32x4 sn[4] = {};
      qkt(c, sn);
      smax_pv(t - 1, cp);
      asm volatile("s_waitcnt vmcnt(0)" ::: "memory");
      __builtin_amdgcn_s_barrier();
#pragma unroll
      for (int nf = 0; nf < 4; ++nf) sp[nf] = sn[nf];
    }
    // drain last tile
    smax_pv(kbe - 1, (kbe - 1 - kb0) % 3);

    // epilogue: normalized partial O -> bf16; (m,l) per q-row for merge
    float linv[4];
#pragma unroll
    for (int r = 0; r < 4; ++r) {
      float lr = __shfl(lrow, lhi * 4 + r, 16);
      linv[r] = (lr > 0.f) ? 1.0f / lr : 0.f;
    }
#pragma unroll
    for (int r = 0; r < 4; ++r) {
      int rowg = q0 + lhi * 4 + r;
#pragma unroll
      for (int nf = 0; nf < 4; ++nf)
        po[(size_t)rowg * 1024 + h * 64 + nf * 16 + l15] =
            f2bf(oa[nf][r] * linv[r]);
    }
    if (lhi == 0) ml[(q0 + l15) * 16 + h] = float2{mrow, lrow};
  }
}

// ---------------- merge the two kv-half partials (p0 in-place) ---------------
__global__ __launch_bounds__(256) void merge_kernel(u16* __restrict__ p0,
                                                    const u16* __restrict__ p1,
                                                    const float2* __restrict__ mlb) {
  int base = (blockIdx.x * 256 + threadIdx.x) * 8;
  int row = base >> 10, h = (base & 1023) >> 6;
  float2 a = mlb[row * 16 + h];
  float2 b = mlb[4096 * 16 + row * 16 + h];
  float m = fmaxf(a.x, b.x);
  float w0 = EXP2(a.x - m) * a.y, w1 = EXP2(b.x - m) * b.y;
  float inv = 1.0f / (w0 + w1);
  w0 *= inv; w1 *= inv;
  u16x8 q0 = *(const u16x8*)(p0 + base);
  u16x8 q1 = *(const u16x8*)(p1 + base);
  u16x8 o;
#pragma unroll
  for (int j = 0; j < 8; ++j) o[j] = f2bf(w0 * bf2f(q0[j]) + w1 * bf2f(q1[j]));
  *(u16x8*)(p0 + base) = o;
}

// -----------------------------------------------------------------------------
extern "C" void kernel_launch(void* const* d_in, const int* in_sizes, int n_in,
                              void* d_out, int out_size, void* d_ws,
                              size_t ws_size, hipStream_t stream) {
  const float* x = (const float*)d_in[0];
  const float* wq = (const float*)d_in[1];
  const float* wk = (const float*)d_in[2];
  const float* wv = (const float*)d_in[3];
  const float* wo = (const float*)d_in[4];

  // workspace layout (bf16 elements), ~50 MB
  u16* xb = (u16*)d_ws;                      // [4096][1024]
  u16* wqkv = xb + 4096 * 1024;              // [3072][1024] (dead after gemm8k)
  u16* wob = wqkv + 3072 * 1024;             // [1024][1024]
  u16* qb = wob + 1024 * 1024;               // [4096][1024] Q (pre-scaled)
  u16* kbuf = qb + 4096 * 1024;              // [4096][1024] K
  u16* vt = kbuf + 4096 * 1024;              // [1024][4096] V^T (planar)
  u16* atn = vt + 4096 * 1024;               // [4096][1024] half0 partial/merged
  float2* mlb = (float2*)wqkv;               // 2 x [4096][16] (m,l)
  u16* p1 = (u16*)d_out;                     // half1 partial (d_out scratch)

  castall_kernel<<<4096, 256, 0, stream>>>(x, wq, wk, wv, wo, xb, wqkv);

  // QKV projection -> planar Q | K | V^T (V transposed in epilogue)
  gemm8k<<<dim3(12, 16), 512, 0, stream>>>(xb, wqkv, qb, kbuf, vt);
  // causal flash attention, 2-way kv-split, T15 softmax/PV || QK^T pipeline
  attn_kernel<<<dim3(16, 16, 2), 512, 0, stream>>>(qb, kbuf, vt, atn, p1, mlb);
  // merge partials (in-place into atn)
  merge_kernel<<<2048, 256, 0, stream>>>(atn, p1, mlb);
  // output projection: fp32 out = attn_bf16 * wo^T (depth-2 counted prefetch)
  gemm2p<<<dim3(8, 32), 512, 0, stream>>>(atn, wob, (float*)d_out, 4096, 1024,
                                          1024);
}

// Round 10
// 206.278 us; speedup vs baseline: 2.1114x; 1.0079x over previous
//
#include <hip/hip_runtime.h>
#include <hip/hip_bf16.h>
#include <stdint.h>

typedef unsigned short u16;
typedef float f32x4 __attribute__((ext_vector_type(4)));
typedef __bf16 bf16x8 __attribute__((ext_vector_type(8)));
typedef u16 u16x8 __attribute__((ext_vector_type(8)));

// async global->LDS, 16B per lane. LDS dest must be wave-uniform base + lane*16.
#define GL2LDS16(g, l)                                                          \
  __builtin_amdgcn_global_load_lds(                                             \
      (const __attribute__((address_space(1))) unsigned int*)(g),               \
      (__attribute__((address_space(3))) unsigned int*)(l), 16, 0, 0)

#if __has_builtin(__builtin_amdgcn_exp2f)
#define EXP2(x) __builtin_amdgcn_exp2f(x)
#else
#define EXP2(x) exp2f(x)
#endif

#define SOFTMAX_SC 0.18033688f  // 0.125 * log2(e)

__device__ __forceinline__ u16 f2bf(float f) {
  uint32_t u = __builtin_bit_cast(uint32_t, f);
  return (u16)((u + 0x7FFFu + ((u >> 16) & 1u)) >> 16);  // RNE, no NaN inputs
}

__device__ __forceinline__ float bf2f(u16 b) {
  return __builtin_bit_cast(float, (uint32_t)b << 16);
}

__device__ __forceinline__ uint32_t cvt_pk_bf16(float lo, float hi) {
  uint32_t r;
  asm("v_cvt_pk_bf16_f32 %0, %1, %2" : "=v"(r) : "v"(lo), "v"(hi));
  return r;
}

// ---------------- fp32 -> bf16 casts (x + 4 weights, one launch) -------------
__device__ __forceinline__ void cast8(const float* __restrict__ s,
                                      u16* __restrict__ d) {
  const float4* p = (const float4*)s;
  float4 a = p[0], b = p[1];
  uint4 o;
  o.x = cvt_pk_bf16(a.x, a.y);
  o.y = cvt_pk_bf16(a.z, a.w);
  o.z = cvt_pk_bf16(b.x, b.y);
  o.w = cvt_pk_bf16(b.z, b.w);
  *(uint4*)d = o;
}

__global__ __launch_bounds__(256) void castall_kernel(
    const float* __restrict__ x, const float* __restrict__ wq,
    const float* __restrict__ wk, const float* __restrict__ wv,
    const float* __restrict__ wo, u16* __restrict__ xb,
    u16* __restrict__ wqkv) {
  int b = blockIdx.x;
  if (b < 2048) {
    int i = (b * 256 + threadIdx.x) * 8;
    cast8(x + i, xb + i);
  } else {
    b -= 2048;
    int w = b >> 9;
    int i = ((b & 511) * 256 + threadIdx.x) * 8;
    const float* s = (w == 0) ? wq : (w == 1) ? wk : (w == 2) ? wv : wo;
    cast8(s + i, wqkv + ((size_t)w << 20) + i);
  }
}

// ---------------- 16-MFMA phase cluster (compile-time m-base) ----------------
template <int MB>
__device__ __forceinline__ void mfma16(f32x4 (&acc)[8][4], const bf16x8 (&af)[4],
                                       const bf16x8 (&bfr)[4]) {
  asm volatile("s_waitcnt lgkmcnt(0)" ::: "memory");
  __builtin_amdgcn_sched_barrier(0);
  __builtin_amdgcn_s_setprio(1);
#pragma unroll
  for (int j = 0; j < 4; ++j)
#pragma unroll
    for (int n = 0; n < 4; ++n)
      acc[MB + j][n] = __builtin_amdgcn_mfma_f32_16x16x32_bf16(
          af[j], bfr[n], acc[MB + j][n], 0, 0, 0);
  __builtin_amdgcn_s_setprio(0);
}

// ---------------- 8-phase 256x256 QKV GEMM with COUNTED vmcnt ----------------
// C = A * B^T (M=4096, N=3072, K=1024). Planar output: cols<1024 -> qb (scaled
// by SOFTMAX_SC), cols 1024..2047 -> kb, cols>=2048 -> vt TRANSPOSED.
__global__ __launch_bounds__(512, 2) void gemm8k(const u16* __restrict__ A,
                                                 const u16* __restrict__ B,
                                                 u16* __restrict__ qb,
                                                 u16* __restrict__ kb,
                                                 u16* __restrict__ vt) {
  const int K = 1024;
  __shared__ u16 As[4][128 * 64];
  __shared__ u16 Bs[4][128 * 64];
  const int tid = threadIdx.x;
  const int lane = tid & 63;
  const int l15 = lane & 15, lhi = lane >> 4;
  const int wave = tid >> 6;
  const int wm = wave >> 2, wn = wave & 3;
  int bid = blockIdx.y * gridDim.x + blockIdx.x;
  const int cpx = (gridDim.x * gridDim.y) >> 3;
  bid = (bid & 7) * cpx + (bid >> 3);
  const int m0 = (bid / gridDim.x) * 256, n0 = (bid % gridDim.x) * 256;
  const int nt = K >> 6;  // 16 K-tiles of 64

  int aoff[2][8], boff[2][4];
#pragma unroll
  for (int ks = 0; ks < 2; ++ks) {
    const int sl = ((ks * 4 + lhi) ^ (l15 & 7)) << 4;
#pragma unroll
    for (int m = 0; m < 8; ++m) aoff[ks][m] = (m * 16 + l15) * 128 + sl;
#pragma unroll
    for (int n = 0; n < 4; ++n)
      boff[ks][n] = ((wn & 1) * 64 + n * 16 + l15) * 128 + sl;
  }

  auto stA = [&](int T, int h) {
    u16* lb = As[(T & 1) * 2 + h];
#pragma unroll
    for (int i = 0; i < 2; ++i) {
      int c = tid + i * 512;
      int row = c >> 3;
      int scol = ((c & 7) ^ (row & 7)) * 8;
      GL2LDS16(A + (size_t)(m0 + h * 128 + row) * K + T * 64 + scol,
               (char*)lb + c * 16);
    }
  };
  auto stB = [&](int T, int h) {
    u16* lb = Bs[(T & 1) * 2 + h];
#pragma unroll
    for (int i = 0; i < 2; ++i) {
      int c = tid + i * 512;
      int row = c >> 3;
      int scol = ((c & 7) ^ (row & 7)) * 8;
      GL2LDS16(B + (size_t)(n0 + h * 128 + row) * K + T * 64 + scol,
               (char*)lb + c * 16);
    }
  };

  f32x4 acc[8][4] = {};

  stA(0, 0); stA(0, 1); stB(0, 0); stB(0, 1);
  asm volatile("s_waitcnt vmcnt(0)" ::: "memory");
  __builtin_amdgcn_s_barrier();

  for (int i = 0; i < nt / 2; ++i) {
    const int e = 2 * i, o = e + 1;
    const char* Ae = (const char*)As[wm];
    const char* Be = (const char*)Bs[wn >> 1];
    const char* Ao = (const char*)As[2 + wm];
    const char* Bo = (const char*)Bs[2 + (wn >> 1)];
    bf16x8 af[4], bfr[4];
    const bool pre = (e + 2) < nt;

    // p1: stage A-odds; wait evens landed (odds fly); MFMA e ks0 mh0
    stA(o, 0); stA(o, 1);
    asm volatile("s_waitcnt vmcnt(4)" ::: "memory");
    __builtin_amdgcn_s_barrier();
#pragma unroll
    for (int j = 0; j < 4; ++j) af[j] = *(const bf16x8*)(Ae + aoff[0][j]);
#pragma unroll
    for (int n = 0; n < 4; ++n) bfr[n] = *(const bf16x8*)(Be + boff[0][n]);
    mfma16<0>(acc, af, bfr);
    __builtin_amdgcn_s_barrier();
    // p2: MFMA e ks0 mh1; stage B-odds
#pragma unroll
    for (int j = 0; j < 4; ++j) af[j] = *(const bf16x8*)(Ae + aoff[0][4 + j]);
    stB(o, 0); stB(o, 1);
    __builtin_amdgcn_s_barrier();
    mfma16<4>(acc, af, bfr);
    __builtin_amdgcn_s_barrier();
    // p3: MFMA e ks1 mh0
#pragma unroll
    for (int j = 0; j < 4; ++j) af[j] = *(const bf16x8*)(Ae + aoff[1][j]);
#pragma unroll
    for (int n = 0; n < 4; ++n) bfr[n] = *(const bf16x8*)(Be + boff[1][n]);
    __builtin_amdgcn_s_barrier();
    mfma16<0>(acc, af, bfr);
    __builtin_amdgcn_s_barrier();
    // p4: MFMA e ks1 mh1
#pragma unroll
    for (int j = 0; j < 4; ++j) af[j] = *(const bf16x8*)(Ae + aoff[1][4 + j]);
    __builtin_amdgcn_s_barrier();
    mfma16<4>(acc, af, bfr);
    __builtin_amdgcn_s_barrier();
    // p5: stage A-evens(t+2); wait odds landed; MFMA o ks0 mh0
    if (pre) {
      stA(e + 2, 0); stA(e + 2, 1);
      asm volatile("s_waitcnt vmcnt(4)" ::: "memory");
    } else {
      asm volatile("s_waitcnt vmcnt(0)" ::: "memory");
    }
    __builtin_amdgcn_s_barrier();
#pragma unroll
    for (int j = 0; j < 4; ++j) af[j] = *(const bf16x8*)(Ao + aoff[0][j]);
#pragma unroll
    for (int n = 0; n < 4; ++n) bfr[n] = *(const bf16x8*)(Bo + boff[0][n]);
    mfma16<0>(acc, af, bfr);
    __builtin_amdgcn_s_barrier();
    // p6: MFMA o ks0 mh1; stage B-evens(t+2)
#pragma unroll
    for (int j = 0; j < 4; ++j) af[j] = *(const bf16x8*)(Ao + aoff[0][4 + j]);
    if (pre) { stB(e + 2, 0); stB(e + 2, 1); }
    __builtin_amdgcn_s_barrier();
    mfma16<4>(acc, af, bfr);
    __builtin_amdgcn_s_barrier();
    // p7: MFMA o ks1 mh0
#pragma unroll
    for (int j = 0; j < 4; ++j) af[j] = *(const bf16x8*)(Ao + aoff[1][j]);
#pragma unroll
    for (int n = 0; n < 4; ++n) bfr[n] = *(const bf16x8*)(Bo + boff[1][n]);
    __builtin_amdgcn_s_barrier();
    mfma16<0>(acc, af, bfr);
    __builtin_amdgcn_s_barrier();
    // p8: MFMA o ks1 mh1
#pragma unroll
    for (int j = 0; j < 4; ++j) af[j] = *(const bf16x8*)(Ao + aoff[1][4 + j]);
    __builtin_amdgcn_s_barrier();
    mfma16<4>(acc, af, bfr);
    __builtin_amdgcn_s_barrier();
  }

  // planar epilogue
#pragma unroll
  for (int m = 0; m < 8; ++m) {
    int rbase = m0 + wm * 128 + m * 16 + lhi * 4;
#pragma unroll
    for (int n = 0; n < 4; ++n) {
      int col = n0 + wn * 64 + n * 16 + l15;
      if (col >= 2048) {  // V: write transposed into vt[1024][4096]
        uint2 pk;
        pk.x = cvt_pk_bf16(acc[m][n][0], acc[m][n][1]);
        pk.y = cvt_pk_bf16(acc[m][n][2], acc[m][n][3]);
        *(uint2*)(vt + (size_t)(col - 2048) * 4096 + rbase) = pk;
      } else {
        u16* dst = (col < 1024) ? qb : kb;
        int cc = col & 1023;
        float sc = (col < 1024) ? SOFTMAX_SC : 1.0f;
#pragma unroll
        for (int r = 0; r < 4; ++r)
          dst[(size_t)(rbase + r) * 1024 + cc] = f2bf(acc[m][n][r] * sc);
      }
    }
  }
}

// ---------------- depth-2 prefetch 128x128 GEMM, fp32 out (wo proj) ---------
__global__ __launch_bounds__(512) void gemm2p(const u16* __restrict__ A,
                                              const u16* __restrict__ B,
                                              float* __restrict__ C, int M,
                                              int N, int K) {
  __shared__ u16 As[3][128 * 64];
  __shared__ u16 Bs[3][128 * 64];
  const int tid = threadIdx.x;
  const int lane = tid & 63;
  const int l15 = lane & 15, lhi = lane >> 4;
  const int wave = tid >> 6;
  const int wm = wave >> 2, wn = wave & 3;
  int bid = blockIdx.y * gridDim.x + blockIdx.x;
  const int cpx = (gridDim.x * gridDim.y) >> 3;
  bid = (bid & 7) * cpx + (bid >> 3);
  const int m0 = (bid / gridDim.x) * 128, n0 = (bid % gridDim.x) * 128;
  const int nt = K >> 6;

  int aoff[2][4], boff[2][2];
#pragma unroll
  for (int ks = 0; ks < 2; ++ks) {
    const int sl = ((ks * 4 + lhi) ^ (l15 & 7)) << 4;
#pragma unroll
    for (int mi = 0; mi < 4; ++mi)
      aoff[ks][mi] = (wm * 64 + mi * 16 + l15) * 128 + sl;
#pragma unroll
    for (int ni = 0; ni < 2; ++ni)
      boff[ks][ni] = (wn * 32 + ni * 16 + l15) * 128 + sl;
  }

  auto stage = [&](int b, int t) {
#pragma unroll
    for (int i = 0; i < 2; ++i) {
      int c = tid + i * 512;
      int row = c >> 3;
      int scol = ((c & 7) ^ (row & 7)) * 8;
      GL2LDS16(A + (size_t)(m0 + row) * K + t * 64 + scol,
               (char*)(As[b]) + c * 16);
      GL2LDS16(B + (size_t)(n0 + row) * K + t * 64 + scol,
               (char*)(Bs[b]) + c * 16);
    }
  };

  f32x4 acc[4][2] = {};

  stage(0, 0);
  if (nt > 1) stage(1, 1);
  if (nt > 1) asm volatile("s_waitcnt vmcnt(4)" ::: "memory");
  else asm volatile("s_waitcnt vmcnt(0)" ::: "memory");
  __builtin_amdgcn_s_barrier();

  for (int t = 0; t < nt; ++t) {
    if (t + 2 < nt) stage((t + 2) % 3, t + 2);
    const char* Ab = (const char*)(As[t % 3]);
    const char* Bb = (const char*)(Bs[t % 3]);
#pragma unroll
    for (int ks = 0; ks < 2; ++ks) {
      bf16x8 af[4], bfr[2];
#pragma unroll
      for (int mi = 0; mi < 4; ++mi)
        af[mi] = *(const bf16x8*)(Ab + aoff[ks][mi]);
#pragma unroll
      for (int ni = 0; ni < 2; ++ni)
        bfr[ni] = *(const bf16x8*)(Bb + boff[ks][ni]);
      __builtin_amdgcn_s_setprio(1);
#pragma unroll
      for (int mi = 0; mi < 4; ++mi)
#pragma unroll
        for (int ni = 0; ni < 2; ++ni)
          acc[mi][ni] = __builtin_amdgcn_mfma_f32_16x16x32_bf16(
              af[mi], bfr[ni], acc[mi][ni], 0, 0, 0);
      __builtin_amdgcn_s_setprio(0);
    }
    if (t + 1 < nt) {
      if (t + 2 < nt) asm volatile("s_waitcnt vmcnt(4)" ::: "memory");
      else asm volatile("s_waitcnt vmcnt(0)" ::: "memory");
      __builtin_amdgcn_s_barrier();
    }
  }

#pragma unroll
  for (int mi = 0; mi < 4; ++mi) {
    int rbase = m0 + wm * 64 + mi * 16 + lhi * 4;
#pragma unroll
    for (int ni = 0; ni < 2; ++ni) {
      int col = n0 + wn * 32 + ni * 16 + l15;
#pragma unroll
      for (int r = 0; r < 4; ++r)
        C[(size_t)(rbase + r) * N + col] = acc[mi][ni][r];
    }
  }
}

// ---------------- causal flash attention (2-way kv-split, T15 pipeline) ------
// 1D grid, head-locality XCD decode: XCD x (= bid & 7 round-robin, m157) gets
// exactly heads {2x, 2x+1} -> 64 blocks/XCD = residency capacity; 2 heads'
// K/V = 4 MB = one XCD's L2 -> K/V re-reads become L2 hits.
// 8 waves / 128 q-rows, swapped-QK^T, paired supertiles (bx, 31-bx), kv-half z.
__global__ __launch_bounds__(512) void attn_kernel(
    const u16* __restrict__ qb, const u16* __restrict__ kbuf,
    const u16* __restrict__ vt, u16* __restrict__ p0, u16* __restrict__ p1g,
    float2* __restrict__ mlb) {
  const int bid = blockIdx.x;            // 0..511
  const int xcd = bid & 7;
  const int slot = bid >> 3;             // 0..63
  const int h = 2 * xcd + (slot >> 5);   // heads 2x, 2x+1 on XCD x
  const int idx = slot & 31;
  const int bx = idx & 15;               // 0..15
  const int half = idx >> 4;             // 0..1
  const int tid = threadIdx.x;
  const int lane = tid & 63, wave = tid >> 6;  // wave 0..7
  const int l15 = lane & 15, lhi = lane >> 4;

  u16* po = half ? p1g : p0;
  float2* ml = mlb + (size_t)half * 4096 * 16;

  __shared__ u16 Ks[3][64 * 64];
  __shared__ u16 Vs[3][64 * 64];
  __shared__ u16 Ps[8][16 * 64];
  u16* Pw = Ps[wave];

  int koff[2][4];  // [ks][nf]: row = nf*16+l15, 16B col = lhi*16 + ks*64
#pragma unroll
  for (int ks = 0; ks < 2; ++ks)
#pragma unroll
    for (int nf = 0; nf < 4; ++nf) {
      int row = nf * 16 + l15;
      koff[ks][nf] = row * 128 + ((lhi * 16 + ks * 64) ^ ((row & 7) << 4));
    }
  int poff[4];  // P write: row = q = l15, 8B col = nf*32 + lhi*8
#pragma unroll
  for (int nf = 0; nf < 4; ++nf)
    poff[nf] = l15 * 128 + ((nf * 32 + lhi * 8) ^ ((l15 & 7) << 4));

  auto stage = [&](int b, int kb) {
    int c = tid;  // 512 chunks = 64x64 bf16, one per thread
    int row = c >> 3, slot2 = c & 7;
    int scol = (slot2 ^ (row & 7)) * 8;
    GL2LDS16(kbuf + (size_t)(kb * 64 + row) * 1024 + h * 64 + scol,
             (char*)(Ks[b]) + c * 16);
    GL2LDS16(vt + (size_t)(h * 64 + row) * 4096 + kb * 64 + scol,
             (char*)(Vs[b]) + c * 16);
  };

  for (int rep = 0; rep < 2; ++rep) {
    const int qsb = rep ? (31 - bx) : bx;   // 128-row q-supertile
    const int kb0 = half * (qsb + 1);       // this half's kv-tile range
    const int kbe = kb0 + qsb + 1;          // length qsb+1 >= 1
    const int q0 = qsb * 128 + wave * 16;
    const u16* Qb = qb + (size_t)(q0 + l15) * 1024 + h * 64;
    bf16x8 qf0 = *(const bf16x8*)(const void*)(Qb + lhi * 8);
    bf16x8 qf1 = *(const bf16x8*)(const void*)(Qb + 32 + lhi * 8);

    f32x4 oa[4] = {};
    float mrow = -1e30f, lrow = 0.f;
    f32x4 sp[4];

    auto qkt = [&](int buf, f32x4 (&s)[4]) {
      __builtin_amdgcn_s_setprio(1);
#pragma unroll
      for (int ks = 0; ks < 2; ++ks)
#pragma unroll
        for (int nf = 0; nf < 4; ++nf) {
          bf16x8 kf = *(const bf16x8*)((const char*)(Ks[buf]) + koff[ks][nf]);
          s[nf] = __builtin_amdgcn_mfma_f32_16x16x32_bf16(kf, ks ? qf1 : qf0,
                                                          s[nf], 0, 0, 0);
        }
      __builtin_amdgcn_s_setprio(0);
    };

    // softmax of tile t (scores in sp) + PV from Vs[vbuf]
    auto smax_pv = [&](int t, int vbuf) {
      if (t * 64 + 63 > q0) {  // causal mask (wave-uniform branch)
        const int q = q0 + l15;
#pragma unroll
        for (int nf = 0; nf < 4; ++nf)
#pragma unroll
          for (int r = 0; r < 4; ++r)
            if (t * 64 + nf * 16 + lhi * 4 + r > q) sp[nf][r] = -1e30f;
      }
      float pm0 = fmaxf(fmaxf(sp[0][0], sp[0][1]), fmaxf(sp[0][2], sp[0][3]));
      float pm1 = fmaxf(fmaxf(sp[1][0], sp[1][1]), fmaxf(sp[1][2], sp[1][3]));
      float pm2 = fmaxf(fmaxf(sp[2][0], sp[2][1]), fmaxf(sp[2][2], sp[2][3]));
      float pm3 = fmaxf(fmaxf(sp[3][0], sp[3][1]), fmaxf(sp[3][2], sp[3][3]));
      float pm = fmaxf(fmaxf(pm0, pm1), fmaxf(pm2, pm3));
      pm = fmaxf(pm, __shfl_xor(pm, 16));
      pm = fmaxf(pm, __shfl_xor(pm, 32));

      if (__any(pm - mrow > 8.0f)) {  // defer-max (2^8 headroom)
        float mn = fmaxf(mrow, pm);
        float al = EXP2(mrow - mn);
        mrow = mn;
        lrow *= al;
        float alq[4];
#pragma unroll
        for (int r = 0; r < 4; ++r) alq[r] = __shfl(al, lhi * 4 + r, 16);
#pragma unroll
        for (int nf = 0; nf < 4; ++nf)
#pragma unroll
          for (int r = 0; r < 4; ++r) oa[nf][r] *= alq[r];
      }

#pragma unroll
      for (int nf = 0; nf < 4; ++nf)
#pragma unroll
        for (int r = 0; r < 4; ++r) sp[nf][r] = EXP2(sp[nf][r] - mrow);
      float rs = ((sp[0][0] + sp[0][1]) + (sp[0][2] + sp[0][3])) +
                 ((sp[1][0] + sp[1][1]) + (sp[1][2] + sp[1][3])) +
                 ((sp[2][0] + sp[2][1]) + (sp[2][2] + sp[2][3])) +
                 ((sp[3][0] + sp[3][1]) + (sp[3][2] + sp[3][3]));
      rs += __shfl_xor(rs, 16);
      rs += __shfl_xor(rs, 32);
      lrow += rs;

#pragma unroll
      for (int nf = 0; nf < 4; ++nf) {
        uint2 pk;
        pk.x = cvt_pk_bf16(sp[nf][0], sp[nf][1]);
        pk.y = cvt_pk_bf16(sp[nf][2], sp[nf][3]);
        *(uint2*)((char*)Pw + poff[nf]) = pk;
      }
      bf16x8 pf[2];
#pragma unroll
      for (int ks = 0; ks < 2; ++ks)
        pf[ks] = *(const bf16x8*)((const char*)Pw + koff[ks][0]);

      __builtin_amdgcn_s_setprio(1);
#pragma unroll
      for (int ks = 0; ks < 2; ++ks)
#pragma unroll
        for (int nf = 0; nf < 4; ++nf) {
          bf16x8 vf = *(const bf16x8*)((const char*)(Vs[vbuf]) + koff[ks][nf]);
          oa[nf] = __builtin_amdgcn_mfma_f32_16x16x32_bf16(pf[ks], vf, oa[nf],
                                                           0, 0, 0);
        }
      __builtin_amdgcn_s_setprio(0);
    };

    // prologue: tile kb0 staged + its QK^T peeled
    stage(0, kb0);
    asm volatile("s_waitcnt vmcnt(0)" ::: "memory");
    __builtin_amdgcn_s_barrier();
    if (kb0 + 1 < kbe) stage(1, kb0 + 1);
#pragma unroll
    for (int nf = 0; nf < 4; ++nf) sp[nf] = f32x4{0.f, 0.f, 0.f, 0.f};
    qkt(0, sp);
    asm volatile("s_waitcnt vmcnt(0)" ::: "memory");
    __builtin_amdgcn_s_barrier();

    // pipelined main loop: QK^T(t) || softmax(t-1)+PV(t-1)
    for (int t = kb0 + 1; t < kbe; ++t) {
      const int c = (t - kb0) % 3;       // tile t (K read)
      const int cp = (t - kb0 + 2) % 3;  // tile t-1 (V read)
      const int cn = (t - kb0 + 1) % 3;  // tile t+1 (stage target)
      if (t + 1 < kbe) stage(cn, t + 1);
      f32x4 sn[4] = {};
      qkt(c, sn);
      smax_pv(t - 1, cp);
      asm volatile("s_waitcnt vmcnt(0)" ::: "memory");
      __builtin_amdgcn_s_barrier();
#pragma unroll
      for (int nf = 0; nf < 4; ++nf) sp[nf] = sn[nf];
    }
    // drain last tile
    smax_pv(kbe - 1, (kbe - 1 - kb0) % 3);

    // epilogue: normalized partial O -> bf16; (m,l) per q-row for merge
    float linv[4];
#pragma unroll
    for (int r = 0; r < 4; ++r) {
      float lr = __shfl(lrow, lhi * 4 + r, 16);
      linv[r] = (lr > 0.f) ? 1.0f / lr : 0.f;
    }
#pragma unroll
    for (int r = 0; r < 4; ++r) {
      int rowg = q0 + lhi * 4 + r;
#pragma unroll
      for (int nf = 0; nf < 4; ++nf)
        po[(size_t)rowg * 1024 + h * 64 + nf * 16 + l15] =
            f2bf(oa[nf][r] * linv[r]);
    }
    if (lhi == 0) ml[(q0 + l15) * 16 + h] = float2{mrow, lrow};
  }
}

// ---------------- merge the two kv-half partials (p0 in-place) ---------------
__global__ __launch_bounds__(256) void merge_kernel(u16* __restrict__ p0,
                                                    const u16* __restrict__ p1,
                                                    const float2* __restrict__ mlb) {
  int base = (blockIdx.x * 256 + threadIdx.x) * 8;
  int row = base >> 10, h = (base & 1023) >> 6;
  float2 a = mlb[row * 16 + h];
  float2 b = mlb[4096 * 16 + row * 16 + h];
  float m = fmaxf(a.x, b.x);
  float w0 = EXP2(a.x - m) * a.y, w1 = EXP2(b.x - m) * b.y;
  float inv = 1.0f / (w0 + w1);
  w0 *= inv; w1 *= inv;
  u16x8 q0 = *(const u16x8*)(p0 + base);
  u16x8 q1 = *(const u16x8*)(p1 + base);
  u16x8 o;
#pragma unroll
  for (int j = 0; j < 8; ++j) o[j] = f2bf(w0 * bf2f(q0[j]) + w1 * bf2f(q1[j]));
  *(u16x8*)(p0 + base) = o;
}

// -----------------------------------------------------------------------------
extern "C" void kernel_launch(void* const* d_in, const int* in_sizes, int n_in,
                              void* d_out, int out_size, void* d_ws,
                              size_t ws_size, hipStream_t stream) {
  const float* x = (const float*)d_in[0];
  const float* wq = (const float*)d_in[1];
  const float* wk = (const float*)d_in[2];
  const float* wv = (const float*)d_in[3];
  const float* wo = (const float*)d_in[4];

  // workspace layout (bf16 elements), ~50 MB
  u16* xb = (u16*)d_ws;                      // [4096][1024]
  u16* wqkv = xb + 4096 * 1024;              // [3072][1024] (dead after gemm8k)
  u16* wob = wqkv + 3072 * 1024;             // [1024][1024]
  u16* qb = wob + 1024 * 1024;               // [4096][1024] Q (pre-scaled)
  u16* kbuf = qb + 4096 * 1024;              // [4096][1024] K
  u16* vt = kbuf + 4096 * 1024;              // [1024][4096] V^T (planar)
  u16* atn = vt + 4096 * 1024;               // [4096][1024] half0 partial/merged
  float2* mlb = (float2*)wqkv;               // 2 x [4096][16] (m,l)
  u16* p1 = (u16*)d_out;                     // half1 partial (d_out scratch)

  castall_kernel<<<4096, 256, 0, stream>>>(x, wq, wk, wv, wo, xb, wqkv);

  // QKV projection -> planar Q | K | V^T (V transposed in epilogue)
  gemm8k<<<dim3(12, 16), 512, 0, stream>>>(xb, wqkv, qb, kbuf, vt);
  // causal flash attention, 2-way kv-split, head-locality XCD decode (1D grid)
  attn_kernel<<<512, 512, 0, stream>>>(qb, kbuf, vt, atn, p1, mlb);
  // merge partials (in-place into atn)
  merge_kernel<<<2048, 256, 0, stream>>>(atn, p1, mlb);
  // output projection: fp32 out = attn_bf16 * wo^T (depth-2 counted prefetch)
  gemm2p<<<dim3(8, 32), 512, 0, stream>>>(atn, wob, (float*)d_out, 4096, 1024,
                                          1024);
}